// Round 1
// baseline (1635.448 us; speedup 1.0000x reference)
//
#include <hip/hip_runtime.h>
#include <hip/hip_bf16.h>
#include <cstdio>

// ---------------------------------------------------------------------------
// FocusPolicy pipeline, MI355X. All fp32 math; stem activations staged bf16.
// Stages:
//  K1 stem conv 7x7/s2 (3->64) + BN partial sums      -> stem(bf16), partials
//  K2 BN finalize (mean/var -> scale/shift)           -> stats
//  K3 BN apply + relu + maxpool3/2p1                  -> f   (16,64,128,128)
//  K4 grid_sample (+-5 deg) x2                        -> xt1, xt2
//  K5 roialign (11 jobs) -> concat                    -> h   (16,704,23,23)
//  K6 conv1 3x3 (704->64) + bias (LDS-tiled GEMM)     -> c1  (16,64,21,21)
//  K7 BN1 stats                                       -> stats1
//  K8 BN apply + relu + maxpool2/2                    -> p1  (16,64,10,10)
//  K9 conv2 3x3 (64->32) + bias + relu                -> c2  (16,32,8,8)
//  K10 fc1 (2048->128) + relu                         -> fo  (16,128)
//  K11 head (128->12) + tanh                          -> d_out (16,12)
// ---------------------------------------------------------------------------

#define C5 0.9961946980917455f
#define S5 0.08715574274765817f

// ======================= K1: stem conv + BN partials =======================
// grid 8192 = n(16) * oh(256) * owt(2); block 256 = g(8 oc-groups) x q(32)
// each thread: 4 positions (q + 32j) x 8 oc
__global__ __launch_bounds__(256) void k_stem(const float* __restrict__ x,
                                              const float* __restrict__ w,
                                              __hip_bfloat16* __restrict__ out,
                                              float* __restrict__ partial) {
    __shared__ float wlds[147 * 68];   // [kk][oc], stride 68 (16B-aligned rows)
    __shared__ float ilds[7 * 783];    // [kh][iwl(261)][ci(3)]
    const int bx = blockIdx.x;
    const int owt = bx & 1;
    const int oh = (bx >> 1) & 255;
    const int n = bx >> 9;
    const int tid = threadIdx.x;

    for (int e = tid; e < 9408; e += 256) {          // stem_w [oc][147]
        int oc = e / 147, kk = e - oc * 147;
        wlds[kk * 68 + oc] = w[e];
    }
    const int ihb = oh * 2 - 3;
    const int iwb = owt * 256 - 3;
    for (int e = tid; e < 5481; e += 256) {
        int r = e / 783, cc = e - r * 783;
        int ih = ihb + r;
        int iwl = cc / 3, ci = cc - iwl * 3;
        int iw = iwb + iwl;
        float v = 0.f;
        if ((unsigned)ih < 512u && (unsigned)iw < 512u)
            v = x[((n * 512 + ih) * 512 + iw) * 3 + ci];
        ilds[e] = v;
    }
    __syncthreads();

    const int g = tid >> 5, q = tid & 31;
    float acc[32];
#pragma unroll
    for (int i = 0; i < 32; i++) acc[i] = 0.f;

    for (int ci = 0; ci < 3; ci++)
        for (int kh = 0; kh < 7; kh++) {
#pragma unroll
            for (int kw = 0; kw < 7; kw++) {
                const int kk = ci * 49 + kh * 7 + kw;
                const float4 w0 = *(const float4*)&wlds[kk * 68 + g * 8];
                const float4 w1 = *(const float4*)&wlds[kk * 68 + g * 8 + 4];
#pragma unroll
                for (int j = 0; j < 4; j++) {
                    float v = ilds[kh * 783 + ((q + 32 * j) * 2 + kw) * 3 + ci];
                    acc[j * 8 + 0] += v * w0.x; acc[j * 8 + 1] += v * w0.y;
                    acc[j * 8 + 2] += v * w0.z; acc[j * 8 + 3] += v * w0.w;
                    acc[j * 8 + 4] += v * w1.x; acc[j * 8 + 5] += v * w1.y;
                    acc[j * 8 + 6] += v * w1.z; acc[j * 8 + 7] += v * w1.w;
                }
            }
        }

    const int owb = owt * 128;
#pragma unroll
    for (int i = 0; i < 8; i++) {
        const int oc = g * 8 + i;
        float s = 0.f, ss = 0.f;
#pragma unroll
        for (int j = 0; j < 4; j++) {
            float v = acc[j * 8 + i];
            s += v; ss += v * v;
            out[((n * 64 + oc) * 256 + oh) * 256 + owb + q + 32 * j] = __float2bfloat16(v);
        }
#pragma unroll
        for (int off = 16; off; off >>= 1) {      // reduce over q (32 lanes)
            s += __shfl_xor(s, off, 64);
            ss += __shfl_xor(ss, off, 64);
        }
        if (q == 0) {
            partial[bx * 128 + oc * 2 + 0] = s;
            partial[bx * 128 + oc * 2 + 1] = ss;
        }
    }
}

// ======================= K2 / K7: BN finalize ==============================
__global__ __launch_bounds__(256) void k_bnstats(const float* __restrict__ partial,
                                                 int nblk,
                                                 const float* __restrict__ gamma,
                                                 const float* __restrict__ beta,
                                                 float* __restrict__ stats,
                                                 float inv_n) {
    const int c = blockIdx.x;        // 64 channels
    const int tid = threadIdx.x;
    float s = 0.f, ss = 0.f;
    for (int b = tid; b < nblk; b += 256) {
        s  += partial[b * 128 + c * 2 + 0];
        ss += partial[b * 128 + c * 2 + 1];
    }
    __shared__ float sh[8], sh2[8];
#pragma unroll
    for (int off = 32; off; off >>= 1) {
        s += __shfl_xor(s, off, 64);
        ss += __shfl_xor(ss, off, 64);
    }
    if ((tid & 63) == 0) { sh[tid >> 6] = s; sh2[tid >> 6] = ss; }
    __syncthreads();
    if (tid == 0) {
        s = sh[0] + sh[1] + sh[2] + sh[3];
        ss = sh2[0] + sh2[1] + sh2[2] + sh2[3];
        float m = s * inv_n;
        float var = ss * inv_n - m * m;
        float a = gamma[c] * rsqrtf(var + 1e-5f);
        stats[c] = a;
        stats[64 + c] = beta[c] - m * a;
    }
}

__global__ __launch_bounds__(256) void k_bn1stats(const float* __restrict__ c1,
                                                  const float* __restrict__ gamma,
                                                  const float* __restrict__ beta,
                                                  float* __restrict__ stats1) {
    const int c = blockIdx.x;
    const int tid = threadIdx.x;
    float s = 0.f, ss = 0.f;
    for (int e = tid; e < 7056; e += 256) {      // 16 n x 441 pos
        int n = e / 441, p = e - n * 441;
        float v = c1[(n * 64 + c) * 441 + p];
        s += v; ss += v * v;
    }
    __shared__ float sh[8], sh2[8];
#pragma unroll
    for (int off = 32; off; off >>= 1) {
        s += __shfl_xor(s, off, 64);
        ss += __shfl_xor(ss, off, 64);
    }
    if ((tid & 63) == 0) { sh[tid >> 6] = s; sh2[tid >> 6] = ss; }
    __syncthreads();
    if (tid == 0) {
        s = sh[0] + sh[1] + sh[2] + sh[3];
        ss = sh2[0] + sh2[1] + sh2[2] + sh2[3];
        const float inv_n = 1.f / 7056.f;
        float m = s * inv_n;
        float var = ss * inv_n - m * m;
        float a = gamma[c] * rsqrtf(var + 1e-5f);
        stats1[c] = a;
        stats1[64 + c] = beta[c] - m * a;
    }
}

// =============== K3: BN apply + relu + maxpool 3x3/s2/p1 ===================
__global__ __launch_bounds__(256) void k_bnpool(const __hip_bfloat16* __restrict__ sin_,
                                                const float* __restrict__ stats,
                                                float* __restrict__ f) {
    const int t = blockIdx.x * 256 + threadIdx.x;   // 16*64*128*128 exact
    const int pw = t & 127;
    const int ph = (t >> 7) & 127;
    const int c = (t >> 14) & 63;
    const float a = stats[c], b = stats[64 + c];
    const __hip_bfloat16* base = sin_ + (size_t)(t >> 14) * 65536;
    const int r0 = ph * 2 - 1, c0 = pw * 2 - 1;
    float m = -1e30f;
#pragma unroll
    for (int dr = 0; dr < 3; dr++) {
        int r = r0 + dr;
        if ((unsigned)r >= 256u) continue;
#pragma unroll
        for (int dc = 0; dc < 3; dc++) {
            int cc = c0 + dc;
            if ((unsigned)cc >= 256u) continue;
            float v = __bfloat162float(base[r * 256 + cc]);
            m = fmaxf(m, a * v + b);
        }
    }
    f[t] = fmaxf(m, 0.f);
}

// ======================= K4: grid_sample (rotation) ========================
__device__ __forceinline__ float gs_gather(const float* img, float yy, float xx, float wt) {
    bool valid = (xx >= 0.f) & (xx < 128.f) & (yy >= 0.f) & (yy < 128.f);
    int xi = (int)fminf(fmaxf(xx, 0.f), 127.f);
    int yi = (int)fminf(fmaxf(yy, 0.f), 127.f);
    return valid ? img[yi * 128 + xi] * wt : 0.f;
}

__global__ __launch_bounds__(256) void k_gridsample(const float* __restrict__ f,
                                                    float* __restrict__ xt,
                                                    float ct, float st) {
    const int t = blockIdx.x * 256 + threadIdx.x;   // 16*64*128*128 exact
    const int w = t & 127;
    const int h = (t >> 7) & 127;
    const float* img = f + ((size_t)(t >> 14) << 14);
    float gx = (2 * w + 1) * (1.f / 128.f) - 1.f;
    float gy = (2 * h + 1) * (1.f / 128.f) - 1.f;
    float g0 = ct * gx + st * gy;
    float g1 = -st * gx + ct * gy;
    float ix = ((g0 + 1.f) * 128.f - 1.f) * 0.5f;
    float iy = ((g1 + 1.f) * 128.f - 1.f) * 0.5f;
    float x0 = floorf(ix), y0 = floorf(iy);
    float lx = ix - x0, ly = iy - y0;
    float wa = (1.f - lx) * (1.f - ly);
    float wb = (1.f - lx) * ly;
    float wc = lx * (1.f - ly);
    float wd = lx * ly;
    float sum = gs_gather(img, y0,       x0,       wa)
              + gs_gather(img, y0 + 1.f, x0,       wb)
              + gs_gather(img, y0,       x0 + 1.f, wc)
              + gs_gather(img, y0 + 1.f, x0 + 1.f, wd);
    xt[t] = sum;
}

// ======================= K5: roialign into concat h ========================
// grid 704 = n(16) * job(11) * cg(4); block 256. 16 ch x 23x23 per block.
__global__ __launch_bounds__(256) void k_roialign(const float* __restrict__ f,
                                                  const float* __restrict__ xt1,
                                                  const float* __restrict__ xt2,
                                                  const float* __restrict__ box,
                                                  float* __restrict__ h) {
    const int bx = blockIdx.x;
    const int cg = bx & 3;
    const int job = (bx >> 2) % 11;
    const int n = bx / 44;
    int j, cbase;
    const float* src;
    if (job < 7)      { j = job;     cbase = job * 64;            src = f;   }
    else if (job < 9) { j = job - 7; cbase = 448 + (job - 7) * 64; src = xt1; }
    else              { j = job - 9; cbase = 576 + (job - 9) * 64; src = xt2; }
    const float* bp = box + n * 28 + j * 4;
    const float x1 = bp[0] * 0.25f, y1 = bp[1] * 0.25f;
    const float x2 = bp[2] * 0.25f, y2 = bp[3] * 0.25f;
    const float bw = fmaxf(x2 - x1, 1.f) * (1.f / 23.f);
    const float bh = fmaxf(y2 - y1, 1.f) * (1.f / 23.f);

    for (int idx = threadIdx.x; idx < 16 * 529; idx += 256) {
        const int cl = idx / 529;
        const int pp = idx - cl * 529;
        const int ph = pp / 23, pw = pp - ph * 23;
        const float* img = src + (size_t)(n * 64 + cg * 16 + cl) * 16384;
        float sum = 0.f;
#pragma unroll
        for (int r1 = 0; r1 < 2; r1++) {
            const float yv = y1 + (ph + r1 * 0.5f + 0.25f) * bh;
#pragma unroll
            for (int r2 = 0; r2 < 2; r2++) {
                const float xv = x1 + (pw + r2 * 0.5f + 0.25f) * bw;
                if (yv < -1.f || yv > 128.f || xv < -1.f || xv > 128.f) continue;
                float y = fminf(fmaxf(yv, 0.f), 127.f);
                float x = fminf(fmaxf(xv, 0.f), 127.f);
                float y0f = floorf(y), x0f = floorf(x);
                int y0 = (int)y0f, x0 = (int)x0f;
                int y1i = min(y0 + 1, 127), x1i = min(x0 + 1, 127);
                float ly = y - y0f, lx = x - x0f;
                float hy = 1.f - ly, hx = 1.f - lx;
                sum += img[y0 * 128 + x0]  * hy * hx + img[y0 * 128 + x1i]  * hy * lx
                     + img[y1i * 128 + x0] * ly * hx + img[y1i * 128 + x1i] * ly * lx;
            }
        }
        h[((n * 704 + cbase + cg * 16 + cl) * 23 + ph) * 23 + pw] = sum * 0.25f;
    }
}

// =================== K6: conv1 3x3 (704->64) + bias ========================
// implicit GEMM: 64 oc x 64 pos tile, K = 704*9 chunked by 11 ci (99 kk).
// grid 112 = n(16) * posTile(7); block 256 = to(16 oc-quads) x tp(16 pos-quads)
__global__ __launch_bounds__(256) void k_conv1(const float* __restrict__ hbuf,
                                               const float* __restrict__ w1,
                                               const float* __restrict__ b1,
                                               float* __restrict__ c1) {
    __shared__ float As[99 * 68];   // [kk][oc] stride 68
    __shared__ float Bs[99 * 64];   // [kk][pos]
    const int bx = blockIdx.x;
    const int pt = bx % 7;
    const int n = bx / 7;
    const int posBase = pt * 64;
    const int tid = threadIdx.x;
    const int to = tid & 15, tp = tid >> 4;
    float acc[16];
#pragma unroll
    for (int i = 0; i < 16; i++) acc[i] = 0.f;

    for (int chunk = 0; chunk < 64; chunk++) {
        const int ci0 = chunk * 11;
        for (int e = tid; e < 6336; e += 256) {   // A: 99 kk x 64 oc
            int oc = e / 99, kkl = e - oc * 99;
            As[kkl * 68 + oc] = w1[oc * 6336 + ci0 * 9 + kkl];
        }
        for (int e = tid; e < 6336; e += 256) {   // B: gathered im2col
            int kkl = e >> 6, pos = e & 63;
            int ci = ci0 + kkl / 9;
            int tap = kkl % 9;
            int kh = tap / 3, kw = tap - kh * 3;
            int p = posBase + pos;
            float v = 0.f;
            if (p < 441) {
                int ph = p / 21, pw = p - ph * 21;
                v = hbuf[((n * 704 + ci) * 23 + ph + kh) * 23 + pw + kw];
            }
            Bs[kkl * 64 + pos] = v;
        }
        __syncthreads();
#pragma unroll 3
        for (int kkl = 0; kkl < 99; kkl++) {
            const float4 a4 = *(const float4*)&As[kkl * 68 + to * 4];
            const float4 b4 = *(const float4*)&Bs[kkl * 64 + tp * 4];
            acc[0]  += a4.x * b4.x; acc[1]  += a4.x * b4.y; acc[2]  += a4.x * b4.z; acc[3]  += a4.x * b4.w;
            acc[4]  += a4.y * b4.x; acc[5]  += a4.y * b4.y; acc[6]  += a4.y * b4.z; acc[7]  += a4.y * b4.w;
            acc[8]  += a4.z * b4.x; acc[9]  += a4.z * b4.y; acc[10] += a4.z * b4.z; acc[11] += a4.z * b4.w;
            acc[12] += a4.w * b4.x; acc[13] += a4.w * b4.y; acc[14] += a4.w * b4.z; acc[15] += a4.w * b4.w;
        }
        __syncthreads();
    }
#pragma unroll
    for (int i = 0; i < 4; i++) {
        const int oc = to * 4 + i;
        const float bias = b1[oc];
#pragma unroll
        for (int jj = 0; jj < 4; jj++) {
            const int p = posBase + tp * 4 + jj;
            if (p < 441)
                c1[(n * 64 + oc) * 441 + p] = acc[i * 4 + jj] + bias;
        }
    }
}

// ================ K8: BN1 apply + relu + maxpool 2x2/s2 ====================
__global__ __launch_bounds__(256) void k_bnpool2(const float* __restrict__ c1,
                                                 const float* __restrict__ stats1,
                                                 float* __restrict__ p1) {
    const int t = blockIdx.x * 256 + threadIdx.x;   // 16*64*100 = 102400 exact
    const int pw = t % 10;
    const int ph = (t / 10) % 10;
    const int c = (t / 100) % 64;
    const int n = t / 6400;
    const float a = stats1[c], b = stats1[64 + c];
    const float* base = c1 + (size_t)(n * 64 + c) * 441;
    const int r = ph * 2, cc = pw * 2;
    float v0 = a * base[r * 21 + cc] + b;
    float v1 = a * base[r * 21 + cc + 1] + b;
    float v2 = a * base[(r + 1) * 21 + cc] + b;
    float v3 = a * base[(r + 1) * 21 + cc + 1] + b;
    p1[t] = fmaxf(fmaxf(fmaxf(v0, v1), fmaxf(v2, v3)), 0.f);
}

// ================ K9: conv2 3x3 (64->32) + bias + relu =====================
__global__ __launch_bounds__(256) void k_conv2(const float* __restrict__ p1,
                                               const float* __restrict__ w2,
                                               const float* __restrict__ b2,
                                               float* __restrict__ c2) {
    const int t = blockIdx.x * 256 + threadIdx.x;   // 16*32*64 = 32768 exact
    const int pw = t & 7;
    const int ph = (t >> 3) & 7;
    const int oc = (t >> 6) & 31;
    const int n = t >> 11;
    float s = b2[oc];
    for (int ci = 0; ci < 64; ci++) {
        const float* ib = p1 + (size_t)(n * 64 + ci) * 100;
        const float* wb = w2 + (size_t)(oc * 64 + ci) * 9;
#pragma unroll
        for (int kh = 0; kh < 3; kh++)
#pragma unroll
            for (int kw = 0; kw < 3; kw++)
                s += ib[(ph + kh) * 10 + pw + kw] * wb[kh * 3 + kw];
    }
    c2[t] = fmaxf(s, 0.f);
}

// ======================= K10: fc1 + relu ===================================
__global__ __launch_bounds__(64) void k_fc1(const float* __restrict__ c2,
                                            const float* __restrict__ fw,
                                            const float* __restrict__ fb,
                                            float* __restrict__ fo) {
    const int bx = blockIdx.x;         // n*128 + oc
    const int oc = bx & 127, n = bx >> 7;
    const int lane = threadIdx.x;
    const float* a = c2 + (size_t)n * 2048;
    const float* w = fw + (size_t)oc * 2048;
    float s = 0.f;
    for (int k = lane; k < 2048; k += 64) s += a[k] * w[k];
#pragma unroll
    for (int off = 32; off; off >>= 1) s += __shfl_xor(s, off, 64);
    if (lane == 0) fo[n * 128 + oc] = fmaxf(s + fb[oc], 0.f);
}

// ======================= K11: head + tanh ==================================
__global__ __launch_bounds__(64) void k_head(const float* __restrict__ fo,
                                             const float* __restrict__ hw,
                                             const float* __restrict__ hb,
                                             float* __restrict__ out) {
    const int bx = blockIdx.x;         // n*12 + oc
    const int oc = bx % 12, n = bx / 12;
    const int lane = threadIdx.x;
    float s = 0.f;
    for (int k = lane; k < 128; k += 64) s += fo[n * 128 + k] * hw[oc * 128 + k];
#pragma unroll
    for (int off = 32; off; off >>= 1) s += __shfl_xor(s, off, 64);
    if (lane == 0) out[bx] = tanhf(s + hb[oc]);
}

// ===========================================================================
extern "C" void kernel_launch(void* const* d_in, const int* in_sizes, int n_in,
                              void* d_out, int out_size, void* d_ws, size_t ws_size,
                              hipStream_t stream) {
    const float* x       = (const float*)d_in[0];
    const float* box     = (const float*)d_in[1];
    const float* stem_w  = (const float*)d_in[2];
    const float* stem_g  = (const float*)d_in[3];
    const float* stem_b  = (const float*)d_in[4];
    const float* conv1_w = (const float*)d_in[5];
    const float* conv1_b = (const float*)d_in[6];
    const float* bn1_g   = (const float*)d_in[7];
    const float* bn1_b   = (const float*)d_in[8];
    const float* conv2_w = (const float*)d_in[9];
    const float* conv2_b = (const float*)d_in[10];
    const float* fc1_w   = (const float*)d_in[11];
    const float* fc1_b   = (const float*)d_in[12];
    const float* head_w  = (const float*)d_in[13];
    const float* head_b  = (const float*)d_in[14];
    float* out = (float*)d_out;
    float* w = (float*)d_ws;

    const size_t F_SZ = 16777216;                         // 16*64*128*128
    float* f   = w;                                       // fp32
    __hip_bfloat16* stem = (__hip_bfloat16*)(w + F_SZ);   // bf16, 2*F_SZ floats
    float* xt1 = w + F_SZ;                                // aliases stem (dead after K3)
    float* xt2 = w + 2 * F_SZ;
    float* hbuf = w + 3 * F_SZ;                           // 16*704*529 = 5958656
    float* c1   = hbuf + 5958656;                         // 451584
    float* p1   = c1 + 451584;                            // 102400
    float* c2   = p1 + 102400;                            // 32768
    float* fo   = c2 + 32768;                             // 2048
    float* partial = fo + 2048;                           // 8192*128 = 1048576
    float* stats   = partial + 1048576;                   // 128
    float* stats1  = stats + 128;                         // 128
    const size_t need = (size_t)(3 * F_SZ + 5958656 + 451584 + 102400 + 32768
                                 + 2048 + 1048576 + 256) * 4;
    fprintf(stderr, "[FocusPolicy] ws_size=%zu need=%zu\n", ws_size, need);

    k_stem<<<8192, 256, 0, stream>>>(x, stem_w, stem, partial);
    k_bnstats<<<64, 256, 0, stream>>>(partial, 8192, stem_g, stem_b, stats,
                                      1.f / 1048576.f);
    k_bnpool<<<65536, 256, 0, stream>>>(stem, stats, f);
    k_gridsample<<<65536, 256, 0, stream>>>(f, xt1, C5, S5);   // theta1 (a=-5deg)
    k_gridsample<<<65536, 256, 0, stream>>>(f, xt2, C5, -S5);  // theta2 (a=+5deg)
    k_roialign<<<704, 256, 0, stream>>>(f, xt1, xt2, box, hbuf);
    k_conv1<<<112, 256, 0, stream>>>(hbuf, conv1_w, conv1_b, c1);
    k_bn1stats<<<64, 256, 0, stream>>>(c1, bn1_g, bn1_b, stats1);
    k_bnpool2<<<400, 256, 0, stream>>>(c1, stats1, p1);
    k_conv2<<<128, 256, 0, stream>>>(p1, conv2_w, conv2_b, c2);
    k_fc1<<<2048, 64, 0, stream>>>(c2, fc1_w, fc1_b, fo);
    k_head<<<192, 64, 0, stream>>>(fo, head_w, head_b, out);
}

// Round 2
// 962.595 us; speedup vs baseline: 1.6990x; 1.6990x over previous
//
#include <hip/hip_runtime.h>
#include <hip/hip_bf16.h>

// ---------------------------------------------------------------------------
// FocusPolicy pipeline, MI355X.
//  K0 convert conv1_w -> bf16                         -> w1b
//  K1 stem conv 7x7/s2 (3->64) + BN partial sums      -> stem(bf16), partials
//  K2 BN finalize (mean/var -> scale/shift)           -> stats
//  K3 BN apply + relu + maxpool3/2p1                  -> f   (16,64,128,128)
//  K4 grid_sample (+-5 deg) x2                        -> xt1, xt2
//  K5 roialign (11 jobs) -> concat (bf16)             -> h   (16,704,23,23)
//  K6 conv1 3x3 (704->64) MFMA bf16, split-K=3        -> c1p (3,16,64,544)
//  K6b reduce split-K + bias                          -> c1  (16,64,21,21)
//  K7 BN1 stats                                       -> stats1
//  K8 BN apply + relu + maxpool2/2                    -> p1  (16,64,10,10)
//  K9 conv2 3x3 (64->32) + bias + relu                -> c2  (16,32,8,8)
//  K10 fc1 (2048->128) + relu                         -> fo  (16,128)
//  K11 head (128->12) + tanh                          -> d_out (16,12)
// ---------------------------------------------------------------------------

#define C5 0.9961946980917455f
#define S5 0.08715574274765817f

typedef __attribute__((ext_vector_type(8))) short short8;
typedef __attribute__((ext_vector_type(4))) float f32x4;

// ======================= K0: conv1 weights -> bf16 =========================
__global__ __launch_bounds__(256) void k_cvtw1(const float* __restrict__ w1,
                                               __hip_bfloat16* __restrict__ w1b) {
    const int t = blockIdx.x * 256 + threadIdx.x;   // 64*6336 = 405504 exact
    w1b[t] = __float2bfloat16(w1[t]);
}

// ======================= K1: stem conv + BN partials =======================
// grid 8192 = n(16) * oh(256) * owt(2); block 256 = g(8 oc-groups) x q(32)
__global__ __launch_bounds__(256) void k_stem(const float* __restrict__ x,
                                              const float* __restrict__ w,
                                              __hip_bfloat16* __restrict__ out,
                                              float* __restrict__ partial) {
    __shared__ float wlds[147 * 68];   // [kk][oc], stride 68
    __shared__ float ilds[7 * 783];    // [kh][iwl(261)][ci(3)]
    const int bx = blockIdx.x;
    const int owt = bx & 1;
    const int oh = (bx >> 1) & 255;
    const int n = bx >> 9;
    const int tid = threadIdx.x;

    for (int e = tid; e < 9408; e += 256) {          // stem_w [oc][147]
        int oc = e / 147, kk = e - oc * 147;
        wlds[kk * 68 + oc] = w[e];
    }
    const int ihb = oh * 2 - 3;
    const int iwb = owt * 256 - 3;
    for (int e = tid; e < 5481; e += 256) {
        int r = e / 783, cc = e - r * 783;
        int ih = ihb + r;
        int iwl = cc / 3, ci = cc - iwl * 3;
        int iw = iwb + iwl;
        float v = 0.f;
        if ((unsigned)ih < 512u && (unsigned)iw < 512u)
            v = x[((n * 512 + ih) * 512 + iw) * 3 + ci];
        ilds[e] = v;
    }
    __syncthreads();

    const int g = tid >> 5, q = tid & 31;
    float acc[32];
#pragma unroll
    for (int i = 0; i < 32; i++) acc[i] = 0.f;

    for (int ci = 0; ci < 3; ci++)
        for (int kh = 0; kh < 7; kh++) {
#pragma unroll
            for (int kw = 0; kw < 7; kw++) {
                const int kk = ci * 49 + kh * 7 + kw;
                const float4 w0 = *(const float4*)&wlds[kk * 68 + g * 8];
                const float4 w1 = *(const float4*)&wlds[kk * 68 + g * 8 + 4];
#pragma unroll
                for (int j = 0; j < 4; j++) {
                    float v = ilds[kh * 783 + ((q + 32 * j) * 2 + kw) * 3 + ci];
                    acc[j * 8 + 0] += v * w0.x; acc[j * 8 + 1] += v * w0.y;
                    acc[j * 8 + 2] += v * w0.z; acc[j * 8 + 3] += v * w0.w;
                    acc[j * 8 + 4] += v * w1.x; acc[j * 8 + 5] += v * w1.y;
                    acc[j * 8 + 6] += v * w1.z; acc[j * 8 + 7] += v * w1.w;
                }
            }
        }

    const int owb = owt * 128;
#pragma unroll
    for (int i = 0; i < 8; i++) {
        const int oc = g * 8 + i;
        float s = 0.f, ss = 0.f;
#pragma unroll
        for (int j = 0; j < 4; j++) {
            float v = acc[j * 8 + i];
            s += v; ss += v * v;
            out[((n * 64 + oc) * 256 + oh) * 256 + owb + q + 32 * j] = __float2bfloat16(v);
        }
#pragma unroll
        for (int off = 16; off; off >>= 1) {
            s += __shfl_xor(s, off, 64);
            ss += __shfl_xor(ss, off, 64);
        }
        if (q == 0) {
            partial[bx * 128 + oc * 2 + 0] = s;
            partial[bx * 128 + oc * 2 + 1] = ss;
        }
    }
}

// ======================= K2: BN finalize ===================================
__global__ __launch_bounds__(256) void k_bnstats(const float* __restrict__ partial,
                                                 int nblk,
                                                 const float* __restrict__ gamma,
                                                 const float* __restrict__ beta,
                                                 float* __restrict__ stats,
                                                 float inv_n) {
    const int c = blockIdx.x;
    const int tid = threadIdx.x;
    float s = 0.f, ss = 0.f;
    for (int b = tid; b < nblk; b += 256) {
        s  += partial[b * 128 + c * 2 + 0];
        ss += partial[b * 128 + c * 2 + 1];
    }
    __shared__ float sh[8], sh2[8];
#pragma unroll
    for (int off = 32; off; off >>= 1) {
        s += __shfl_xor(s, off, 64);
        ss += __shfl_xor(ss, off, 64);
    }
    if ((tid & 63) == 0) { sh[tid >> 6] = s; sh2[tid >> 6] = ss; }
    __syncthreads();
    if (tid == 0) {
        s = sh[0] + sh[1] + sh[2] + sh[3];
        ss = sh2[0] + sh2[1] + sh2[2] + sh2[3];
        float m = s * inv_n;
        float var = ss * inv_n - m * m;
        float a = gamma[c] * rsqrtf(var + 1e-5f);
        stats[c] = a;
        stats[64 + c] = beta[c] - m * a;
    }
}

__global__ __launch_bounds__(256) void k_bn1stats(const float* __restrict__ c1,
                                                  const float* __restrict__ gamma,
                                                  const float* __restrict__ beta,
                                                  float* __restrict__ stats1) {
    const int c = blockIdx.x;
    const int tid = threadIdx.x;
    float s = 0.f, ss = 0.f;
    for (int e = tid; e < 7056; e += 256) {
        int n = e / 441, p = e - n * 441;
        float v = c1[(n * 64 + c) * 441 + p];
        s += v; ss += v * v;
    }
    __shared__ float sh[8], sh2[8];
#pragma unroll
    for (int off = 32; off; off >>= 1) {
        s += __shfl_xor(s, off, 64);
        ss += __shfl_xor(ss, off, 64);
    }
    if ((tid & 63) == 0) { sh[tid >> 6] = s; sh2[tid >> 6] = ss; }
    __syncthreads();
    if (tid == 0) {
        s = sh[0] + sh[1] + sh[2] + sh[3];
        ss = sh2[0] + sh2[1] + sh2[2] + sh2[3];
        const float inv_n = 1.f / 7056.f;
        float m = s * inv_n;
        float var = ss * inv_n - m * m;
        float a = gamma[c] * rsqrtf(var + 1e-5f);
        stats1[c] = a;
        stats1[64 + c] = beta[c] - m * a;
    }
}

// =============== K3: BN apply + relu + maxpool 3x3/s2/p1 ===================
__global__ __launch_bounds__(256) void k_bnpool(const __hip_bfloat16* __restrict__ sin_,
                                                const float* __restrict__ stats,
                                                float* __restrict__ f) {
    const int t = blockIdx.x * 256 + threadIdx.x;   // 16*64*128*128 exact
    const int pw = t & 127;
    const int ph = (t >> 7) & 127;
    const int c = (t >> 14) & 63;
    const float a = stats[c], b = stats[64 + c];
    const __hip_bfloat16* base = sin_ + (size_t)(t >> 14) * 65536;
    const int r0 = ph * 2 - 1, c0 = pw * 2 - 1;
    float m = -1e30f;
#pragma unroll
    for (int dr = 0; dr < 3; dr++) {
        int r = r0 + dr;
        if ((unsigned)r >= 256u) continue;
#pragma unroll
        for (int dc = 0; dc < 3; dc++) {
            int cc = c0 + dc;
            if ((unsigned)cc >= 256u) continue;
            float v = __bfloat162float(base[r * 256 + cc]);
            m = fmaxf(m, a * v + b);
        }
    }
    f[t] = fmaxf(m, 0.f);
}

// ======================= K4: grid_sample (rotation) ========================
__device__ __forceinline__ float gs_gather(const float* img, float yy, float xx, float wt) {
    bool valid = (xx >= 0.f) & (xx < 128.f) & (yy >= 0.f) & (yy < 128.f);
    int xi = (int)fminf(fmaxf(xx, 0.f), 127.f);
    int yi = (int)fminf(fmaxf(yy, 0.f), 127.f);
    return valid ? img[yi * 128 + xi] * wt : 0.f;
}

__global__ __launch_bounds__(256) void k_gridsample(const float* __restrict__ f,
                                                    float* __restrict__ xt,
                                                    float ct, float st) {
    const int t = blockIdx.x * 256 + threadIdx.x;
    const int w = t & 127;
    const int h = (t >> 7) & 127;
    const float* img = f + ((size_t)(t >> 14) << 14);
    float gx = (2 * w + 1) * (1.f / 128.f) - 1.f;
    float gy = (2 * h + 1) * (1.f / 128.f) - 1.f;
    float g0 = ct * gx + st * gy;
    float g1 = -st * gx + ct * gy;
    float ix = ((g0 + 1.f) * 128.f - 1.f) * 0.5f;
    float iy = ((g1 + 1.f) * 128.f - 1.f) * 0.5f;
    float x0 = floorf(ix), y0 = floorf(iy);
    float lx = ix - x0, ly = iy - y0;
    float wa = (1.f - lx) * (1.f - ly);
    float wb = (1.f - lx) * ly;
    float wc = lx * (1.f - ly);
    float wd = lx * ly;
    float sum = gs_gather(img, y0,       x0,       wa)
              + gs_gather(img, y0 + 1.f, x0,       wb)
              + gs_gather(img, y0,       x0 + 1.f, wc)
              + gs_gather(img, y0 + 1.f, x0 + 1.f, wd);
    xt[t] = sum;
}

// ======================= K5: roialign into concat h (bf16) =================
__global__ __launch_bounds__(256) void k_roialign(const float* __restrict__ f,
                                                  const float* __restrict__ xt1,
                                                  const float* __restrict__ xt2,
                                                  const float* __restrict__ box,
                                                  __hip_bfloat16* __restrict__ h) {
    const int bx = blockIdx.x;
    const int cg = bx & 3;
    const int job = (bx >> 2) % 11;
    const int n = bx / 44;
    int j, cbase;
    const float* src;
    if (job < 7)      { j = job;     cbase = job * 64;             src = f;   }
    else if (job < 9) { j = job - 7; cbase = 448 + (job - 7) * 64; src = xt1; }
    else              { j = job - 9; cbase = 576 + (job - 9) * 64; src = xt2; }
    const float* bp = box + n * 28 + j * 4;
    const float x1 = bp[0] * 0.25f, y1 = bp[1] * 0.25f;
    const float x2 = bp[2] * 0.25f, y2 = bp[3] * 0.25f;
    const float bw = fmaxf(x2 - x1, 1.f) * (1.f / 23.f);
    const float bh = fmaxf(y2 - y1, 1.f) * (1.f / 23.f);

    for (int idx = threadIdx.x; idx < 16 * 529; idx += 256) {
        const int cl = idx / 529;
        const int pp = idx - cl * 529;
        const int ph = pp / 23, pw = pp - ph * 23;
        const float* img = src + (size_t)(n * 64 + cg * 16 + cl) * 16384;
        float sum = 0.f;
#pragma unroll
        for (int r1 = 0; r1 < 2; r1++) {
            const float yv = y1 + (ph + r1 * 0.5f + 0.25f) * bh;
#pragma unroll
            for (int r2 = 0; r2 < 2; r2++) {
                const float xv = x1 + (pw + r2 * 0.5f + 0.25f) * bw;
                if (yv < -1.f || yv > 128.f || xv < -1.f || xv > 128.f) continue;
                float y = fminf(fmaxf(yv, 0.f), 127.f);
                float x = fminf(fmaxf(xv, 0.f), 127.f);
                float y0f = floorf(y), x0f = floorf(x);
                int y0 = (int)y0f, x0 = (int)x0f;
                int y1i = min(y0 + 1, 127), x1i = min(x0 + 1, 127);
                float ly = y - y0f, lx = x - x0f;
                float hy = 1.f - ly, hx = 1.f - lx;
                sum += img[y0 * 128 + x0]  * hy * hx + img[y0 * 128 + x1i]  * hy * lx
                     + img[y1i * 128 + x0] * ly * hx + img[y1i * 128 + x1i] * ly * lx;
            }
        }
        h[(size_t)(n * 704 + cbase + cg * 16 + cl) * 529 + pp] =
            __float2bfloat16(sum * 0.25f);
    }
}

// =================== K6: conv1 MFMA bf16, split-K=3 ========================
// GEMM over padded 23x23 grid: D[oc=64][p529(544)] per (s,n).
// grid 816 = s(3) x n(16) x ptile(17); block 256 = 4 waves, wave w -> oc w*16..+15
__global__ __launch_bounds__(256) void k_conv1m(const ushort* __restrict__ hb,
                                                const ushort* __restrict__ w1b,
                                                float* __restrict__ c1p) {
    __shared__ __align__(16) ushort Bs[2][32][40];   // [panel][pos][kk], stride 40
    const int bx = blockIdx.x;
    const int pt = bx % 17;
    const int n  = (bx / 17) & 15;
    const int s  = bx / 272;
    const int tid = threadIdx.x;
    const int w = tid >> 6, lane = tid & 63;
    const int quad = lane >> 4, m = lane & 15;
    const int kbase = s * 2112;                      // 2112 = 33*64
    const int posb = pt * 32;
    const size_t hb_n = (size_t)n * 704 * 529;
    f32x4 acc0 = {0.f, 0.f, 0.f, 0.f};
    f32x4 acc1 = {0.f, 0.f, 0.f, 0.f};
    const ushort* wrow = w1b + (size_t)(w * 16 + m) * 6336;

    for (int it = 0; it < 33; it++) {
        const int k0 = kbase + it * 64;
        __syncthreads();
        for (int e = tid; e < 2048; e += 256) {      // B-stage: [k][pos] -> Bs[pos][kk]
            int panel = e >> 10, kk = (e >> 5) & 31, pos = e & 31;
            int k = k0 + panel * 32 + kk;
            int ci = k / 9, tap = k - ci * 9;
            int kh = tap / 3, kw = tap - kh * 3;
            Bs[panel][pos][kk] =
                hb[hb_n + (size_t)ci * 529 + kh * 23 + kw + posb + pos];
        }
        __syncthreads();
        const short8 a0  = *(const short8*)(wrow + k0 + quad * 8);
        const short8 a1  = *(const short8*)(wrow + k0 + 32 + quad * 8);
        const short8 b00 = *(const short8*)&Bs[0][m][quad * 8];
        const short8 b01 = *(const short8*)&Bs[0][16 + m][quad * 8];
        const short8 b10 = *(const short8*)&Bs[1][m][quad * 8];
        const short8 b11 = *(const short8*)&Bs[1][16 + m][quad * 8];
        acc0 = __builtin_amdgcn_mfma_f32_16x16x32_bf16(a0, b00, acc0, 0, 0, 0);
        acc1 = __builtin_amdgcn_mfma_f32_16x16x32_bf16(a0, b01, acc1, 0, 0, 0);
        acc0 = __builtin_amdgcn_mfma_f32_16x16x32_bf16(a1, b10, acc0, 0, 0, 0);
        acc1 = __builtin_amdgcn_mfma_f32_16x16x32_bf16(a1, b11, acc1, 0, 0, 0);
    }
    float* outp = c1p + ((size_t)(s * 16 + n) * 64) * 544;
#pragma unroll
    for (int r = 0; r < 4; r++) {
        const int oc = w * 16 + quad * 4 + r;
        outp[(size_t)oc * 544 + posb + m]      = acc0[r];
        outp[(size_t)oc * 544 + posb + 16 + m] = acc1[r];
    }
}

// =================== K6b: split-K reduce + bias ============================
__global__ __launch_bounds__(256) void k_c1red(const float* __restrict__ c1p,
                                               const float* __restrict__ b1,
                                               float* __restrict__ c1) {
    const int t = blockIdx.x * 256 + threadIdx.x;   // 451584 exact
    const int p = t % 441;
    const int oc = (t / 441) % 64;
    const int n = t / 28224;
    const int ph = p / 21, pw = p - ph * 21;
    const int p529 = ph * 23 + pw;
    const size_t base = ((size_t)n * 64 + oc) * 544 + p529;
    const size_t sstr = (size_t)16 * 64 * 544;
    c1[t] = c1p[base] + c1p[base + sstr] + c1p[base + 2 * sstr] + b1[oc];
}

// ================ K8: BN1 apply + relu + maxpool 2x2/s2 ====================
__global__ __launch_bounds__(256) void k_bnpool2(const float* __restrict__ c1,
                                                 const float* __restrict__ stats1,
                                                 float* __restrict__ p1) {
    const int t = blockIdx.x * 256 + threadIdx.x;   // 102400 exact
    const int pw = t % 10;
    const int ph = (t / 10) % 10;
    const int c = (t / 100) % 64;
    const int n = t / 6400;
    const float a = stats1[c], b = stats1[64 + c];
    const float* base = c1 + (size_t)(n * 64 + c) * 441;
    const int r = ph * 2, cc = pw * 2;
    float v0 = a * base[r * 21 + cc] + b;
    float v1 = a * base[r * 21 + cc + 1] + b;
    float v2 = a * base[(r + 1) * 21 + cc] + b;
    float v3 = a * base[(r + 1) * 21 + cc + 1] + b;
    p1[t] = fmaxf(fmaxf(fmaxf(v0, v1), fmaxf(v2, v3)), 0.f);
}

// ================ K9: conv2 3x3 (64->32) + bias + relu =====================
__global__ __launch_bounds__(256) void k_conv2(const float* __restrict__ p1,
                                               const float* __restrict__ w2,
                                               const float* __restrict__ b2,
                                               float* __restrict__ c2) {
    const int t = blockIdx.x * 256 + threadIdx.x;   // 32768 exact
    const int pw = t & 7;
    const int ph = (t >> 3) & 7;
    const int oc = (t >> 6) & 31;
    const int n = t >> 11;
    float s = b2[oc];
    for (int ci = 0; ci < 64; ci++) {
        const float* ib = p1 + (size_t)(n * 64 + ci) * 100;
        const float* wb = w2 + (size_t)(oc * 64 + ci) * 9;
#pragma unroll
        for (int kh = 0; kh < 3; kh++)
#pragma unroll
            for (int kw = 0; kw < 3; kw++)
                s += ib[(ph + kh) * 10 + pw + kw] * wb[kh * 3 + kw];
    }
    c2[t] = fmaxf(s, 0.f);
}

// ======================= K10: fc1 + relu ===================================
__global__ __launch_bounds__(64) void k_fc1(const float* __restrict__ c2,
                                            const float* __restrict__ fw,
                                            const float* __restrict__ fb,
                                            float* __restrict__ fo) {
    const int bx = blockIdx.x;
    const int oc = bx & 127, n = bx >> 7;
    const int lane = threadIdx.x;
    const float* a = c2 + (size_t)n * 2048;
    const float* w = fw + (size_t)oc * 2048;
    float s = 0.f;
    for (int k = lane; k < 2048; k += 64) s += a[k] * w[k];
#pragma unroll
    for (int off = 32; off; off >>= 1) s += __shfl_xor(s, off, 64);
    if (lane == 0) fo[n * 128 + oc] = fmaxf(s + fb[oc], 0.f);
}

// ======================= K11: head + tanh ==================================
__global__ __launch_bounds__(64) void k_head(const float* __restrict__ fo,
                                             const float* __restrict__ hw,
                                             const float* __restrict__ hb,
                                             float* __restrict__ out) {
    const int bx = blockIdx.x;
    const int oc = bx % 12, n = bx / 12;
    const int lane = threadIdx.x;
    float s = 0.f;
    for (int k = lane; k < 128; k += 64) s += fo[n * 128 + k] * hw[oc * 128 + k];
#pragma unroll
    for (int off = 32; off; off >>= 1) s += __shfl_xor(s, off, 64);
    if (lane == 0) out[bx] = tanhf(s + hb[oc]);
}

// ===========================================================================
extern "C" void kernel_launch(void* const* d_in, const int* in_sizes, int n_in,
                              void* d_out, int out_size, void* d_ws, size_t ws_size,
                              hipStream_t stream) {
    const float* x       = (const float*)d_in[0];
    const float* box     = (const float*)d_in[1];
    const float* stem_w  = (const float*)d_in[2];
    const float* stem_g  = (const float*)d_in[3];
    const float* stem_b  = (const float*)d_in[4];
    const float* conv1_w = (const float*)d_in[5];
    const float* conv1_b = (const float*)d_in[6];
    const float* bn1_g   = (const float*)d_in[7];
    const float* bn1_b   = (const float*)d_in[8];
    const float* conv2_w = (const float*)d_in[9];
    const float* conv2_b = (const float*)d_in[10];
    const float* fc1_w   = (const float*)d_in[11];
    const float* fc1_b   = (const float*)d_in[12];
    const float* head_w  = (const float*)d_in[13];
    const float* head_b  = (const float*)d_in[14];
    float* out = (float*)d_out;
    float* w = (float*)d_ws;

    const size_t F_SZ = 16777216;                         // 16*64*128*128
    float* f   = w;                                       // fp32
    __hip_bfloat16* stem = (__hip_bfloat16*)(w + F_SZ);   // bf16, spans 2*F_SZ floats
    float* xt1 = w + F_SZ;                                // aliases stem (dead after K3)
    float* xt2 = w + 2 * F_SZ;
    float* base3 = w + 3 * F_SZ;
    __hip_bfloat16* hbuf = (__hip_bfloat16*)base3;        // 5958656 els (+pad) = 2979392 floats
    float* c1   = base3 + 2979392;                        // 451584
    float* c1p  = c1 + 451584;                            // 3*16*64*544 = 1671168
    float* p1   = c1p + 1671168;                          // 102400
    float* c2   = p1 + 102400;                            // 32768
    float* fo   = c2 + 32768;                             // 2048
    float* partial = fo + 2048;                           // 8192*128 = 1048576
    float* stats   = partial + 1048576;                   // 128
    float* stats1  = stats + 128;                         // 128
    __hip_bfloat16* w1b = (__hip_bfloat16*)(stats1 + 128); // 405504 els = 202752 floats
    // total = 3*F_SZ + 6,490,944 floats = 227.3 MB (< round-1's 231.7 MB, which fit)

    k_cvtw1<<<1584, 256, 0, stream>>>(conv1_w, w1b);
    k_stem<<<8192, 256, 0, stream>>>(x, stem_w, stem, partial);
    k_bnstats<<<64, 256, 0, stream>>>(partial, 8192, stem_g, stem_b, stats,
                                      1.f / 1048576.f);
    k_bnpool<<<65536, 256, 0, stream>>>(stem, stats, f);
    k_gridsample<<<65536, 256, 0, stream>>>(f, xt1, C5, S5);   // theta1 (a=-5deg)
    k_gridsample<<<65536, 256, 0, stream>>>(f, xt2, C5, -S5);  // theta2 (a=+5deg)
    k_roialign<<<704, 256, 0, stream>>>(f, xt1, xt2, box, hbuf);
    k_conv1m<<<816, 256, 0, stream>>>((const ushort*)hbuf, (const ushort*)w1b, c1p);
    k_c1red<<<1764, 256, 0, stream>>>(c1p, conv1_b, c1);
    k_bn1stats<<<64, 256, 0, stream>>>(c1, bn1_g, bn1_b, stats1);
    k_bnpool2<<<400, 256, 0, stream>>>(c1, stats1, p1);
    k_conv2<<<128, 256, 0, stream>>>(p1, conv2_w, conv2_b, c2);
    k_fc1<<<2048, 64, 0, stream>>>(c2, fc1_w, fc1_b, fo);
    k_head<<<192, 64, 0, stream>>>(fo, head_w, head_b, out);
}

// Round 4
// 825.593 us; speedup vs baseline: 1.9809x; 1.1659x over previous
//
#include <hip/hip_runtime.h>
#include <hip/hip_bf16.h>

// ---------------------------------------------------------------------------
// FocusPolicy pipeline, MI355X.
//  K0a convert conv1_w -> bf16                        -> w1b
//  K0b reorder+convert stem_w -> bf16 K=192           -> w2b  (k = kh*24+kw*3+ci)
//  K1 stem conv 7x7/s2 MFMA bf16 + BN partials        -> stem(bf16), partials
//  K2 BN finalize                                     -> stats
//  K3 BN apply + relu + maxpool3/2p1                  -> f   (16,64,128,128)
//  K4 grid_sample (+-5 deg), both in one pass         -> xt1, xt2
//  K5 roialign (11 jobs) -> concat (bf16)             -> h   (16,704,23,23)
//  K6 conv1 3x3 (704->64) MFMA bf16, split-K=3        -> c1p
//  K6b reduce split-K + bias                          -> c1  (16,64,21,21)
//  K7 BN1 stats;  K8 BN+relu+maxpool2/2;  K9 conv2;  K10 fc1;  K11 head
// ---------------------------------------------------------------------------

#define C5 0.9961946980917455f
#define S5 0.08715574274765817f

typedef __attribute__((ext_vector_type(8))) short short8;
typedef __attribute__((ext_vector_type(4))) float f32x4;

__device__ __forceinline__ ushort f2bf_bits(float v) {
    __hip_bfloat16 b = __float2bfloat16(v);
    ushort u;
    __builtin_memcpy(&u, &b, 2);
    return u;
}

// ======================= K0a: conv1 weights -> bf16 ========================
__global__ __launch_bounds__(256) void k_cvtw1(const float* __restrict__ w1,
                                               __hip_bfloat16* __restrict__ w1b) {
    const int t = blockIdx.x * 256 + threadIdx.x;   // 64*6336 = 405504 exact
    w1b[t] = __float2bfloat16(w1[t]);
}

// ============ K0b: stem weights -> bf16, k-order kh*24+kw*3+ci =============
__global__ __launch_bounds__(256) void k_cvtw2(const float* __restrict__ sw,
                                               __hip_bfloat16* __restrict__ w2b) {
    const int e = blockIdx.x * 256 + threadIdx.x;   // 64*192 = 12288 exact
    const int oc = e / 192, k = e - oc * 192;
    const int kh = k / 24, t = k - kh * 24;
    float v = 0.f;
    if (t < 21) {
        int kw = t / 3, ci = t - kw * 3;
        v = sw[oc * 147 + ci * 49 + kh * 7 + kw];
    }
    w2b[e] = __float2bfloat16(v);
}

// =================== K1: stem conv MFMA + BN partials ======================
// grid 8192 = n(16) x oh(256) x pt(2); block 256 = 4 waves.
// Tile: M=64 oc, N=128 positions (posb=pt*128, wave w -> pos w*32..+31), K=192.
__global__ __launch_bounds__(256) void k_stem(const float* __restrict__ x,
                                              const ushort* __restrict__ w2b,
                                              __hip_bfloat16* __restrict__ out,
                                              float* __restrict__ partial) {
    __shared__ ushort raw[7][792];                  // [kh][lidx], bf16 raw slab
    __shared__ __align__(16) ushort Bs[128][200];   // [pos][k], K=192 (+8 pad)
    __shared__ float sredS[4][64], sredQ[4][64];
    const int bx = blockIdx.x;
    const int pt = bx & 1;
    const int oh = (bx >> 1) & 255;
    const int n  = bx >> 9;
    const int tid = threadIdx.x;
    const int w = tid >> 6, lane = tid & 63;
    const int quad = lane >> 4, m = lane & 15;
    const int posb = pt * 128;

    // ---- phase A: global fp32 -> raw bf16 (coalesced) ----
    // lidx <-> flatcol = posb*6 - 9 + lidx; flatcol = iw*3+ci in [0,1536)
    const int base_fc = posb * 6 - 9;
    for (int e = tid; e < 7 * 792; e += 256) {
        const int kh = e / 792, lidx = e - kh * 792;
        const int ih = oh * 2 - 3 + kh;
        const int fc = base_fc + lidx;
        float v = 0.f;
        if ((unsigned)ih < 512u && (unsigned)fc < 1536u)
            v = x[(size_t)(n * 512 + ih) * 1536 + fc];
        raw[kh][lidx] = f2bf_bits(v);
    }
    __syncthreads();

    // ---- phase B: raw -> Bs im2col (vector LDS->LDS, no repack) ----
    // 24 k-groups of 8 per pos; g<21: kh=g/3, t0=(g%3)*8; g>=21: zero pad
    for (int e = tid; e < 128 * 24; e += 256) {
        const int g = e >> 7;            // wave-uniform
        const int p = e & 127;
        uint4 v;
        if (g < 21) {
            const int kh = g / 3;
            const int gi = g - kh * 3;
            const uint* rr = (const uint*)&raw[kh][0];
            const int idx = 3 * p + gi * 4;      // shorts: p*6 + gi*8 (even)
            uint u0 = rr[idx], u1 = rr[idx + 1], u2 = rr[idx + 2], u3 = rr[idx + 3];
            if (gi == 2) { u2 &= 0xFFFFu; u3 = 0u; }   // t=21..23 pad
            v = (uint4){u0, u1, u2, u3};
        } else {
            v = (uint4){0u, 0u, 0u, 0u};
        }
        *(uint4*)&Bs[p][g * 8] = v;
    }
    __syncthreads();

    // ---- K-loop: 6 steps x (4 A-frags global + 2 B-frags LDS + 8 MFMA) ----
    f32x4 acc[4][2] = {};
    const int prow0 = w * 32 + m;
#pragma unroll
    for (int ks = 0; ks < 6; ks++) {
        const int ko = ks * 32 + quad * 8;
        const short8 b0 = *(const short8*)&Bs[prow0][ko];
        const short8 b1 = *(const short8*)&Bs[prow0 + 16][ko];
#pragma unroll
        for (int mt = 0; mt < 4; mt++) {
            const short8 a = *(const short8*)(w2b + (size_t)(mt * 16 + m) * 192 + ko);
            acc[mt][0] = __builtin_amdgcn_mfma_f32_16x16x32_bf16(a, b0, acc[mt][0], 0, 0, 0);
            acc[mt][1] = __builtin_amdgcn_mfma_f32_16x16x32_bf16(a, b1, acc[mt][1], 0, 0, 0);
        }
    }

    // ---- epilogue: store bf16 + BN partial sums ----
#pragma unroll
    for (int mt = 0; mt < 4; mt++) {
#pragma unroll
        for (int nt = 0; nt < 2; nt++) {
            const int opos = posb + w * 32 + nt * 16 + m;
            const f32x4 a = acc[mt][nt];
#pragma unroll
            for (int r = 0; r < 4; r++) {
                const int oc = mt * 16 + quad * 4 + r;
                out[(size_t)(n * 64 + oc) * 65536 + oh * 256 + opos] =
                    __float2bfloat16(a[r]);
            }
        }
    }
#pragma unroll
    for (int mt = 0; mt < 4; mt++) {
        const f32x4 a0 = acc[mt][0], a1 = acc[mt][1];
#pragma unroll
        for (int r = 0; r < 4; r++) {
            float s = a0[r] + a1[r];
            float q = a0[r] * a0[r] + a1[r] * a1[r];
#pragma unroll
            for (int off = 1; off < 16; off <<= 1) {
                s += __shfl_xor(s, off, 64);
                q += __shfl_xor(q, off, 64);
            }
            if (m == 0) {
                const int ocl = mt * 16 + quad * 4 + r;
                sredS[w][ocl] = s;
                sredQ[w][ocl] = q;
            }
        }
    }
    __syncthreads();
    if (tid < 128) {
        const int oc = tid >> 1, comp = tid & 1;
        float v = 0.f;
#pragma unroll
        for (int ww = 0; ww < 4; ww++)
            v += comp ? sredQ[ww][oc] : sredS[ww][oc];
        partial[bx * 128 + tid] = v;
    }
}

// ======================= K2: BN finalize ===================================
__global__ __launch_bounds__(256) void k_bnstats(const float* __restrict__ partial,
                                                 int nblk,
                                                 const float* __restrict__ gamma,
                                                 const float* __restrict__ beta,
                                                 float* __restrict__ stats,
                                                 float inv_n) {
    const int c = blockIdx.x;
    const int tid = threadIdx.x;
    float s = 0.f, ss = 0.f;
    for (int b = tid; b < nblk; b += 256) {
        s  += partial[b * 128 + c * 2 + 0];
        ss += partial[b * 128 + c * 2 + 1];
    }
    __shared__ float sh[8], sh2[8];
#pragma unroll
    for (int off = 32; off; off >>= 1) {
        s += __shfl_xor(s, off, 64);
        ss += __shfl_xor(ss, off, 64);
    }
    if ((tid & 63) == 0) { sh[tid >> 6] = s; sh2[tid >> 6] = ss; }
    __syncthreads();
    if (tid == 0) {
        s = sh[0] + sh[1] + sh[2] + sh[3];
        ss = sh2[0] + sh2[1] + sh2[2] + sh2[3];
        float mn = s * inv_n;
        float var = ss * inv_n - mn * mn;
        float a = gamma[c] * rsqrtf(var + 1e-5f);
        stats[c] = a;
        stats[64 + c] = beta[c] - mn * a;
    }
}

__global__ __launch_bounds__(256) void k_bn1stats(const float* __restrict__ c1,
                                                  const float* __restrict__ gamma,
                                                  const float* __restrict__ beta,
                                                  float* __restrict__ stats1) {
    const int c = blockIdx.x;
    const int tid = threadIdx.x;
    float s = 0.f, ss = 0.f;
    for (int e = tid; e < 7056; e += 256) {
        int n = e / 441, p = e - n * 441;
        float v = c1[(n * 64 + c) * 441 + p];
        s += v; ss += v * v;
    }
    __shared__ float sh[8], sh2[8];
#pragma unroll
    for (int off = 32; off; off >>= 1) {
        s += __shfl_xor(s, off, 64);
        ss += __shfl_xor(ss, off, 64);
    }
    if ((tid & 63) == 0) { sh[tid >> 6] = s; sh2[tid >> 6] = ss; }
    __syncthreads();
    if (tid == 0) {
        s = sh[0] + sh[1] + sh[2] + sh[3];
        ss = sh2[0] + sh2[1] + sh2[2] + sh2[3];
        const float inv_n = 1.f / 7056.f;
        float mn = s * inv_n;
        float var = ss * inv_n - mn * mn;
        float a = gamma[c] * rsqrtf(var + 1e-5f);
        stats1[c] = a;
        stats1[64 + c] = beta[c] - mn * a;
    }
}

// =============== K3: BN apply + relu + maxpool 3x3/s2/p1 ===================
__global__ __launch_bounds__(256) void k_bnpool(const __hip_bfloat16* __restrict__ sin_,
                                                const float* __restrict__ stats,
                                                float* __restrict__ f) {
    const int t = blockIdx.x * 256 + threadIdx.x;   // 16*64*128*128 exact
    const int pw = t & 127;
    const int ph = (t >> 7) & 127;
    const int c = (t >> 14) & 63;
    const float a = stats[c], b = stats[64 + c];
    const __hip_bfloat16* base = sin_ + (size_t)(t >> 14) * 65536;
    const int r0 = ph * 2 - 1, c0 = pw * 2 - 1;
    float mx = -1e30f;
#pragma unroll
    for (int dr = 0; dr < 3; dr++) {
        int r = r0 + dr;
        if ((unsigned)r >= 256u) continue;
#pragma unroll
        for (int dc = 0; dc < 3; dc++) {
            int cc = c0 + dc;
            if ((unsigned)cc >= 256u) continue;
            float v = __bfloat162float(base[r * 256 + cc]);
            mx = fmaxf(mx, a * v + b);
        }
    }
    f[t] = fmaxf(mx, 0.f);
}

// ============== K4: grid_sample, both rotations in one pass ================
__device__ __forceinline__ float gs_gather(const float* img, float yy, float xx, float wt) {
    bool valid = (xx >= 0.f) & (xx < 128.f) & (yy >= 0.f) & (yy < 128.f);
    int xi = (int)fminf(fmaxf(xx, 0.f), 127.f);
    int yi = (int)fminf(fmaxf(yy, 0.f), 127.f);
    return valid ? img[yi * 128 + xi] * wt : 0.f;
}

__device__ __forceinline__ float gs_one(const float* img, float ix, float iy) {
    float x0 = floorf(ix), y0 = floorf(iy);
    float lx = ix - x0, ly = iy - y0;
    float wa = (1.f - lx) * (1.f - ly);
    float wb = (1.f - lx) * ly;
    float wc = lx * (1.f - ly);
    float wd = lx * ly;
    return gs_gather(img, y0,       x0,       wa)
         + gs_gather(img, y0 + 1.f, x0,       wb)
         + gs_gather(img, y0,       x0 + 1.f, wc)
         + gs_gather(img, y0 + 1.f, x0 + 1.f, wd);
}

__global__ __launch_bounds__(256) void k_gridsample2(const float* __restrict__ f,
                                                     float* __restrict__ xt1,
                                                     float* __restrict__ xt2) {
    const int t = blockIdx.x * 256 + threadIdx.x;
    const int w = t & 127;
    const int h = (t >> 7) & 127;
    const float* img = f + ((size_t)(t >> 14) << 14);
    float gx = (2 * w + 1) * (1.f / 128.f) - 1.f;
    float gy = (2 * h + 1) * (1.f / 128.f) - 1.f;
    // theta1: ct=C5, st=S5 ; theta2: st=-S5
    float g0a = C5 * gx + S5 * gy,  g1a = -S5 * gx + C5 * gy;
    float g0b = C5 * gx - S5 * gy,  g1b =  S5 * gx + C5 * gy;
    xt1[t] = gs_one(img, ((g0a + 1.f) * 128.f - 1.f) * 0.5f,
                         ((g1a + 1.f) * 128.f - 1.f) * 0.5f);
    xt2[t] = gs_one(img, ((g0b + 1.f) * 128.f - 1.f) * 0.5f,
                         ((g1b + 1.f) * 128.f - 1.f) * 0.5f);
}

// ======================= K5: roialign into concat h (bf16) =================
// grid 1408 = n(16) * job(11) * cg(8); block 256. 8 ch x 23x23 per block.
__global__ __launch_bounds__(256) void k_roialign(const float* __restrict__ f,
                                                  const float* __restrict__ xt1,
                                                  const float* __restrict__ xt2,
                                                  const float* __restrict__ box,
                                                  __hip_bfloat16* __restrict__ h) {
    const int bx = blockIdx.x;
    const int cg = bx & 7;
    const int job = (bx >> 3) % 11;
    const int n = bx / 88;
    int j, cbase;
    const float* src;
    if (job < 7)      { j = job;     cbase = job * 64;             src = f;   }
    else if (job < 9) { j = job - 7; cbase = 448 + (job - 7) * 64; src = xt1; }
    else              { j = job - 9; cbase = 576 + (job - 9) * 64; src = xt2; }
    const float* bp = box + n * 28 + j * 4;
    const float x1 = bp[0] * 0.25f, y1 = bp[1] * 0.25f;
    const float x2 = bp[2] * 0.25f, y2 = bp[3] * 0.25f;
    const float bw = fmaxf(x2 - x1, 1.f) * (1.f / 23.f);
    const float bh = fmaxf(y2 - y1, 1.f) * (1.f / 23.f);

    for (int idx = threadIdx.x; idx < 8 * 529; idx += 256) {
        const int cl = idx / 529;
        const int pp = idx - cl * 529;
        const int ph = pp / 23, pw = pp - ph * 23;
        const float* img = src + (size_t)(n * 64 + cg * 8 + cl) * 16384;
        float sum = 0.f;
#pragma unroll
        for (int r1 = 0; r1 < 2; r1++) {
            const float yv = y1 + (ph + r1 * 0.5f + 0.25f) * bh;
#pragma unroll
            for (int r2 = 0; r2 < 2; r2++) {
                const float xv = x1 + (pw + r2 * 0.5f + 0.25f) * bw;
                if (yv < -1.f || yv > 128.f || xv < -1.f || xv > 128.f) continue;
                float y = fminf(fmaxf(yv, 0.f), 127.f);
                float x = fminf(fmaxf(xv, 0.f), 127.f);
                float y0f = floorf(y), x0f = floorf(x);
                int y0 = (int)y0f, x0 = (int)x0f;
                int y1i = min(y0 + 1, 127), x1i = min(x0 + 1, 127);
                float ly = y - y0f, lx = x - x0f;
                float hy = 1.f - ly, hx = 1.f - lx;
                sum += img[y0 * 128 + x0]  * hy * hx + img[y0 * 128 + x1i]  * hy * lx
                     + img[y1i * 128 + x0] * ly * hx + img[y1i * 128 + x1i] * ly * lx;
            }
        }
        h[(size_t)(n * 704 + cbase + cg * 8 + cl) * 529 + pp] =
            __float2bfloat16(sum * 0.25f);
    }
}

// =================== K6: conv1 MFMA bf16, split-K=3 ========================
__global__ __launch_bounds__(256) void k_conv1m(const ushort* __restrict__ hb,
                                                const ushort* __restrict__ w1b,
                                                float* __restrict__ c1p) {
    __shared__ __align__(16) ushort Bs[2][32][40];   // [panel][pos][kk], stride 40
    const int bx = blockIdx.x;
    const int pt = bx % 17;
    const int n  = (bx / 17) & 15;
    const int s  = bx / 272;
    const int tid = threadIdx.x;
    const int w = tid >> 6, lane = tid & 63;
    const int quad = lane >> 4, m = lane & 15;
    const int kbase = s * 2112;
    const int posb = pt * 32;
    const size_t hb_n = (size_t)n * 704 * 529;
    f32x4 acc0 = {0.f, 0.f, 0.f, 0.f};
    f32x4 acc1 = {0.f, 0.f, 0.f, 0.f};
    const ushort* wrow = w1b + (size_t)(w * 16 + m) * 6336;

    for (int it = 0; it < 33; it++) {
        const int k0 = kbase + it * 64;
        __syncthreads();
        for (int e = tid; e < 2048; e += 256) {
            int panel = e >> 10, kk = (e >> 5) & 31, pos = e & 31;
            int k = k0 + panel * 32 + kk;
            int ci = k / 9, tap = k - ci * 9;
            int kh = tap / 3, kw = tap - kh * 3;
            Bs[panel][pos][kk] =
                hb[hb_n + (size_t)ci * 529 + kh * 23 + kw + posb + pos];
        }
        __syncthreads();
        const short8 a0  = *(const short8*)(wrow + k0 + quad * 8);
        const short8 a1  = *(const short8*)(wrow + k0 + 32 + quad * 8);
        const short8 b00 = *(const short8*)&Bs[0][m][quad * 8];
        const short8 b01 = *(const short8*)&Bs[0][16 + m][quad * 8];
        const short8 b10 = *(const short8*)&Bs[1][m][quad * 8];
        const short8 b11 = *(const short8*)&Bs[1][16 + m][quad * 8];
        acc0 = __builtin_amdgcn_mfma_f32_16x16x32_bf16(a0, b00, acc0, 0, 0, 0);
        acc1 = __builtin_amdgcn_mfma_f32_16x16x32_bf16(a0, b01, acc1, 0, 0, 0);
        acc0 = __builtin_amdgcn_mfma_f32_16x16x32_bf16(a1, b10, acc0, 0, 0, 0);
        acc1 = __builtin_amdgcn_mfma_f32_16x16x32_bf16(a1, b11, acc1, 0, 0, 0);
    }
    float* outp = c1p + ((size_t)(s * 16 + n) * 64) * 544;
#pragma unroll
    for (int r = 0; r < 4; r++) {
        const int oc = w * 16 + quad * 4 + r;
        outp[(size_t)oc * 544 + posb + m]      = acc0[r];
        outp[(size_t)oc * 544 + posb + 16 + m] = acc1[r];
    }
}

// =================== K6b: split-K reduce + bias ============================
__global__ __launch_bounds__(256) void k_c1red(const float* __restrict__ c1p,
                                               const float* __restrict__ b1,
                                               float* __restrict__ c1) {
    const int t = blockIdx.x * 256 + threadIdx.x;   // 451584 exact
    const int p = t % 441;
    const int oc = (t / 441) % 64;
    const int n = t / 28224;
    const int ph = p / 21, pw = p - ph * 21;
    const int p529 = ph * 23 + pw;
    const size_t base = ((size_t)n * 64 + oc) * 544 + p529;
    const size_t sstr = (size_t)16 * 64 * 544;
    c1[t] = c1p[base] + c1p[base + sstr] + c1p[base + 2 * sstr] + b1[oc];
}

// ================ K8: BN1 apply + relu + maxpool 2x2/s2 ====================
__global__ __launch_bounds__(256) void k_bnpool2(const float* __restrict__ c1,
                                                 const float* __restrict__ stats1,
                                                 float* __restrict__ p1) {
    const int t = blockIdx.x * 256 + threadIdx.x;   // 102400 exact
    const int pw = t % 10;
    const int ph = (t / 10) % 10;
    const int c = (t / 100) % 64;
    const int n = t / 6400;
    const float a = stats1[c], b = stats1[64 + c];
    const float* base = c1 + (size_t)(n * 64 + c) * 441;
    const int r = ph * 2, cc = pw * 2;
    float v0 = a * base[r * 21 + cc] + b;
    float v1 = a * base[r * 21 + cc + 1] + b;
    float v2 = a * base[(r + 1) * 21 + cc] + b;
    float v3 = a * base[(r + 1) * 21 + cc + 1] + b;
    p1[t] = fmaxf(fmaxf(fmaxf(v0, v1), fmaxf(v2, v3)), 0.f);
}

// ================ K9: conv2 3x3 (64->32) + bias + relu =====================
__global__ __launch_bounds__(256) void k_conv2(const float* __restrict__ p1,
                                               const float* __restrict__ w2,
                                               const float* __restrict__ b2,
                                               float* __restrict__ c2) {
    const int t = blockIdx.x * 256 + threadIdx.x;   // 32768 exact
    const int pw = t & 7;
    const int ph = (t >> 3) & 7;
    const int oc = (t >> 6) & 31;
    const int n = t >> 11;
    float s = b2[oc];
    for (int ci = 0; ci < 64; ci++) {
        const float* ib = p1 + (size_t)(n * 64 + ci) * 100;
        const float* wb = w2 + (size_t)(oc * 64 + ci) * 9;
#pragma unroll
        for (int kh = 0; kh < 3; kh++)
#pragma unroll
            for (int kw = 0; kw < 3; kw++)
                s += ib[(ph + kh) * 10 + pw + kw] * wb[kh * 3 + kw];
    }
    c2[t] = fmaxf(s, 0.f);
}

// ======================= K10: fc1 + relu ===================================
__global__ __launch_bounds__(64) void k_fc1(const float* __restrict__ c2,
                                            const float* __restrict__ fw,
                                            const float* __restrict__ fb,
                                            float* __restrict__ fo) {
    const int bx = blockIdx.x;
    const int oc = bx & 127, n = bx >> 7;
    const int lane = threadIdx.x;
    const float* a = c2 + (size_t)n * 2048;
    const float* w = fw + (size_t)oc * 2048;
    float s = 0.f;
    for (int k = lane; k < 2048; k += 64) s += a[k] * w[k];
#pragma unroll
    for (int off = 32; off; off >>= 1) s += __shfl_xor(s, off, 64);
    if (lane == 0) fo[n * 128 + oc] = fmaxf(s + fb[oc], 0.f);
}

// ======================= K11: head + tanh ==================================
__global__ __launch_bounds__(64) void k_head(const float* __restrict__ fo,
                                             const float* __restrict__ hw,
                                             const float* __restrict__ hb,
                                             float* __restrict__ out) {
    const int bx = blockIdx.x;
    const int oc = bx % 12, n = bx / 12;
    const int lane = threadIdx.x;
    float s = 0.f;
    for (int k = lane; k < 128; k += 64) s += fo[n * 128 + k] * hw[oc * 128 + k];
#pragma unroll
    for (int off = 32; off; off >>= 1) s += __shfl_xor(s, off, 64);
    if (lane == 0) out[bx] = tanhf(s + hb[oc]);
}

// ===========================================================================
extern "C" void kernel_launch(void* const* d_in, const int* in_sizes, int n_in,
                              void* d_out, int out_size, void* d_ws, size_t ws_size,
                              hipStream_t stream) {
    const float* x       = (const float*)d_in[0];
    const float* box     = (const float*)d_in[1];
    const float* stem_w  = (const float*)d_in[2];
    const float* stem_g  = (const float*)d_in[3];
    const float* stem_b  = (const float*)d_in[4];
    const float* conv1_w = (const float*)d_in[5];
    const float* conv1_b = (const float*)d_in[6];
    const float* bn1_g   = (const float*)d_in[7];
    const float* bn1_b   = (const float*)d_in[8];
    const float* conv2_w = (const float*)d_in[9];
    const float* conv2_b = (const float*)d_in[10];
    const float* fc1_w   = (const float*)d_in[11];
    const float* fc1_b   = (const float*)d_in[12];
    const float* head_w  = (const float*)d_in[13];
    const float* head_b  = (const float*)d_in[14];
    float* out = (float*)d_out;
    float* w = (float*)d_ws;

    const size_t F_SZ = 16777216;                         // 16*64*128*128
    float* f   = w;                                       // fp32
    __hip_bfloat16* stem = (__hip_bfloat16*)(w + F_SZ);   // bf16, spans 2*F_SZ floats
    float* xt1 = w + F_SZ;                                // aliases stem (dead after K3)
    float* xt2 = w + 2 * F_SZ;
    float* base3 = w + 3 * F_SZ;
    __hip_bfloat16* hbuf = (__hip_bfloat16*)base3;        // 5958656 els = 2979328+pad
    float* c1   = base3 + 2979392;                        // 451584
    float* c1p  = c1 + 451584;                            // 3*16*64*544 = 1671168
    float* p1   = c1p + 1671168;                          // 102400
    float* c2   = p1 + 102400;                            // 32768
    float* fo   = c2 + 32768;                             // 2048
    float* partial = fo + 2048;                           // 8192*128 = 1048576
    float* stats   = partial + 1048576;                   // 128
    float* stats1  = stats + 128;                         // 128
    __hip_bfloat16* w1b = (__hip_bfloat16*)(stats1 + 128); // 405504 els = 202752 floats
    __hip_bfloat16* w2b = (__hip_bfloat16*)(stats1 + 128 + 202752); // 12288 els = 6144 floats

    k_cvtw1<<<1584, 256, 0, stream>>>(conv1_w, w1b);
    k_cvtw2<<<48, 256, 0, stream>>>(stem_w, w2b);
    k_stem<<<8192, 256, 0, stream>>>(x, (const ushort*)w2b, stem, partial);
    k_bnstats<<<64, 256, 0, stream>>>(partial, 8192, stem_g, stem_b, stats,
                                      1.f / 1048576.f);
    k_bnpool<<<65536, 256, 0, stream>>>(stem, stats, f);
    k_gridsample2<<<65536, 256, 0, stream>>>(f, xt1, xt2);
    k_roialign<<<1408, 256, 0, stream>>>(f, xt1, xt2, box, hbuf);
    k_conv1m<<<816, 256, 0, stream>>>((const ushort*)hbuf, (const ushort*)w1b, c1p);
    k_c1red<<<1764, 256, 0, stream>>>(c1p, conv1_b, c1);
    k_bn1stats<<<64, 256, 0, stream>>>(c1, bn1_g, bn1_b, stats1);
    k_bnpool2<<<400, 256, 0, stream>>>(c1, stats1, p1);
    k_conv2<<<128, 256, 0, stream>>>(p1, conv2_w, conv2_b, c2);
    k_fc1<<<2048, 64, 0, stream>>>(c2, fc1_w, fc1_b, fo);
    k_head<<<192, 64, 0, stream>>>(fo, head_w, head_b, out);
}

// Round 5
// 693.778 us; speedup vs baseline: 2.3573x; 1.1900x over previous
//
#include <hip/hip_runtime.h>
#include <hip/hip_bf16.h>

// ---------------------------------------------------------------------------
// FocusPolicy pipeline, MI355X.
//  K0a convert conv1_w -> bf16                        -> w1b
//  K0b reorder+convert stem_w -> bf16 K=192           -> w2b  (k = kh*24+kw*3+ci)
//  K1 stem conv 7x7/s2 MFMA bf16 + BN partials        -> stem(bf16), partials
//     (no im2col tile: B-frags read directly from raw slab; k-groups that
//      straddle positions / kh==7 are multiplied by zero weights)
//  K2 BN finalize                                     -> stats
//  K3 BN apply + relu + maxpool3/2p1                  -> f   (16,64,128,128)
//  K4 grid_sample (+-5 deg), both in one pass         -> xt1, xt2
//  K5 roialign (11 jobs) -> concat (bf16)             -> h   (16,704,23,23)
//  K6 conv1 3x3 (704->64) MFMA bf16, split-K=3        -> c1p
//  K6b reduce split-K + bias                          -> c1  (16,64,21,21)
//  K7 BN1 stats;  K8 BN+relu+maxpool2/2;  K9 conv2;  K10 fc1;  K11 head
// ---------------------------------------------------------------------------

#define C5 0.9961946980917455f
#define S5 0.08715574274765817f

typedef __attribute__((ext_vector_type(8))) short short8;
typedef __attribute__((ext_vector_type(4))) float f32x4;

__device__ __forceinline__ ushort f2bf_bits(float v) {
    __hip_bfloat16 b = __float2bfloat16(v);
    ushort u;
    __builtin_memcpy(&u, &b, 2);
    return u;
}

// ======================= K0a: conv1 weights -> bf16 ========================
__global__ __launch_bounds__(256) void k_cvtw1(const float* __restrict__ w1,
                                               __hip_bfloat16* __restrict__ w1b) {
    const int t = blockIdx.x * 256 + threadIdx.x;   // 64*6336 = 405504 exact
    w1b[t] = __float2bfloat16(w1[t]);
}

// ============ K0b: stem weights -> bf16, k-order kh*24+kw*3+ci =============
// k in [168,192) (kh==7) and t in [21,24) are ZERO — the stem K-loop relies
// on this to neutralize garbage B-fragment lanes.
__global__ __launch_bounds__(256) void k_cvtw2(const float* __restrict__ sw,
                                               __hip_bfloat16* __restrict__ w2b) {
    const int e = blockIdx.x * 256 + threadIdx.x;   // 64*192 = 12288 exact
    const int oc = e / 192, k = e - oc * 192;
    const int kh = k / 24, t = k - kh * 24;
    float v = 0.f;
    if (t < 21 && kh < 7) {
        int kw = t / 3, ci = t - kw * 3;
        v = sw[oc * 147 + ci * 49 + kh * 7 + kw];
    }
    w2b[e] = __float2bfloat16(v);
}

// =================== K1: stem conv MFMA + BN partials ======================
// grid 8192 = n(16) x oh(256) x pt(2); block 256 = 4 waves.
// Tile: M=64 oc, N=128 positions, K=192 (147 real + zero pad).
// LDS ~15 KB -> 5 blocks/CU (launch_bounds(256,5)).
__global__ __launch_bounds__(256, 5) void k_stem(const float* __restrict__ x,
                                                 const ushort* __restrict__ w2b,
                                                 __hip_bfloat16* __restrict__ out,
                                                 float* __restrict__ partial) {
    __shared__ __align__(16) ushort raw[8 * 792];   // [kh][lidx]; row7 zero-weighted
    __shared__ float sredS[4][64], sredQ[4][64];
    const int bx = blockIdx.x;
    const int pt = bx & 1;
    const int oh = (bx >> 1) & 255;
    const int n  = bx >> 9;
    const int tid = threadIdx.x;
    const int w = tid >> 6, lane = tid & 63;
    const int quad = lane >> 4, m = lane & 15;
    const int posb = pt * 128;

    // ---- phase A: global fp32 -> raw bf16 slab (coalesced) ----
    // lidx <-> flatcol = posb*6 - 9 + lidx; flatcol = iw*3+ci in [0,1536)
    const int base_fc = posb * 6 - 9;
    for (int e = tid; e < 8 * 792; e += 256) {
        const int kh = e / 792, lidx = e - kh * 792;
        const int ih = oh * 2 - 3 + kh;
        const int fc = base_fc + lidx;
        float v = 0.f;
        if ((unsigned)ih < 512u && (unsigned)fc < 1536u)
            v = x[(size_t)(n * 512 + ih) * 1536 + fc];
        raw[e] = f2bf_bits(v);
    }
    __syncthreads();

    // ---- K-loop: B-frags straight from raw (sliding-window im2col) ----
    // k' = 8g + j, g = ks*4 + quad; tap base shorts = kh*792 + 6*pos + 8*gi
    // (dword-aligned since 6*pos and 8*gi are even). Straddle/kh==7 lanes
    // carry garbage activations but multiply w2b zeros.
    f32x4 acc[4][2] = {};
    const int p0 = w * 32 + m;
#pragma unroll
    for (int ks = 0; ks < 6; ks++) {
        const int g  = ks * 4 + quad;
        const int kh = g / 3;
        const int gi = g - kh * 3;
        const uint* rr = (const uint*)raw + kh * 396 + 4 * gi;
        const uint* q0 = rr + 3 * p0;
        const uint* q1 = rr + 3 * (p0 + 16);
        uint4 t0 = (uint4){q0[0], q0[1], q0[2], q0[3]};
        uint4 t1 = (uint4){q1[0], q1[1], q1[2], q1[3]};
        short8 b0, b1;
        __builtin_memcpy(&b0, &t0, 16);
        __builtin_memcpy(&b1, &t1, 16);
        const int ko = ks * 32 + quad * 8;
#pragma unroll
        for (int mt = 0; mt < 4; mt++) {
            const short8 a = *(const short8*)(w2b + (size_t)(mt * 16 + m) * 192 + ko);
            acc[mt][0] = __builtin_amdgcn_mfma_f32_16x16x32_bf16(a, b0, acc[mt][0], 0, 0, 0);
            acc[mt][1] = __builtin_amdgcn_mfma_f32_16x16x32_bf16(a, b1, acc[mt][1], 0, 0, 0);
        }
    }

    // ---- BN partial sums from accumulators ----
#pragma unroll
    for (int mt = 0; mt < 4; mt++) {
        const f32x4 a0 = acc[mt][0], a1 = acc[mt][1];
#pragma unroll
        for (int r = 0; r < 4; r++) {
            float s = a0[r] + a1[r];
            float q = a0[r] * a0[r] + a1[r] * a1[r];
#pragma unroll
            for (int off = 1; off < 16; off <<= 1) {
                s += __shfl_xor(s, off, 64);
                q += __shfl_xor(q, off, 64);
            }
            if (m == 0) {
                const int ocl = mt * 16 + quad * 4 + r;
                sredS[w][ocl] = s;
                sredQ[w][ocl] = q;
            }
        }
    }

    // ---- coalesced bf16 store via LDS transpose (reuses raw) ----
    ushort* tile = raw;                         // 16 oc x 128 pos, xor-swizzled
#pragma unroll
    for (int mt = 0; mt < 4; mt++) {
        __syncthreads();
#pragma unroll
        for (int nt = 0; nt < 2; nt++) {
#pragma unroll
            for (int r = 0; r < 4; r++) {
                const int ocl = quad * 4 + r;
                const int pos = w * 32 + nt * 16 + m;
                tile[ocl * 128 + (pos ^ ((ocl * 8) & 127))] =
                    f2bf_bits(acc[mt][nt][r]);
            }
        }
        __syncthreads();
        const int ocl = tid >> 4;
        const int pos = (tid & 15) * 8;
        const int sp  = pos ^ ((ocl * 8) & 127);
        uint4 v = *(const uint4*)&tile[ocl * 128 + sp];
        *(uint4*)((ushort*)out + (size_t)(n * 64 + mt * 16 + ocl) * 65536
                  + oh * 256 + posb + pos) = v;
    }

    // ---- final partial write (transpose barriers cover sred visibility) ----
    if (tid < 128) {
        const int oc = tid >> 1, comp = tid & 1;
        float v = 0.f;
#pragma unroll
        for (int ww = 0; ww < 4; ww++)
            v += comp ? sredQ[ww][oc] : sredS[ww][oc];
        partial[bx * 128 + tid] = v;
    }
}

// ======================= K2: BN finalize ===================================
__global__ __launch_bounds__(256) void k_bnstats(const float* __restrict__ partial,
                                                 int nblk,
                                                 const float* __restrict__ gamma,
                                                 const float* __restrict__ beta,
                                                 float* __restrict__ stats,
                                                 float inv_n) {
    const int c = blockIdx.x;
    const int tid = threadIdx.x;
    float s = 0.f, ss = 0.f;
    for (int b = tid; b < nblk; b += 256) {
        s  += partial[b * 128 + c * 2 + 0];
        ss += partial[b * 128 + c * 2 + 1];
    }
    __shared__ float sh[8], sh2[8];
#pragma unroll
    for (int off = 32; off; off >>= 1) {
        s += __shfl_xor(s, off, 64);
        ss += __shfl_xor(ss, off, 64);
    }
    if ((tid & 63) == 0) { sh[tid >> 6] = s; sh2[tid >> 6] = ss; }
    __syncthreads();
    if (tid == 0) {
        s = sh[0] + sh[1] + sh[2] + sh[3];
        ss = sh2[0] + sh2[1] + sh2[2] + sh2[3];
        float mn = s * inv_n;
        float var = ss * inv_n - mn * mn;
        float a = gamma[c] * rsqrtf(var + 1e-5f);
        stats[c] = a;
        stats[64 + c] = beta[c] - mn * a;
    }
}

__global__ __launch_bounds__(256) void k_bn1stats(const float* __restrict__ c1,
                                                  const float* __restrict__ gamma,
                                                  const float* __restrict__ beta,
                                                  float* __restrict__ stats1) {
    const int c = blockIdx.x;
    const int tid = threadIdx.x;
    float s = 0.f, ss = 0.f;
    for (int e = tid; e < 7056; e += 256) {
        int n = e / 441, p = e - n * 441;
        float v = c1[(n * 64 + c) * 441 + p];
        s += v; ss += v * v;
    }
    __shared__ float sh[8], sh2[8];
#pragma unroll
    for (int off = 32; off; off >>= 1) {
        s += __shfl_xor(s, off, 64);
        ss += __shfl_xor(ss, off, 64);
    }
    if ((tid & 63) == 0) { sh[tid >> 6] = s; sh2[tid >> 6] = ss; }
    __syncthreads();
    if (tid == 0) {
        s = sh[0] + sh[1] + sh[2] + sh[3];
        ss = sh2[0] + sh2[1] + sh2[2] + sh2[3];
        const float inv_n = 1.f / 7056.f;
        float mn = s * inv_n;
        float var = ss * inv_n - mn * mn;
        float a = gamma[c] * rsqrtf(var + 1e-5f);
        stats1[c] = a;
        stats1[64 + c] = beta[c] - mn * a;
    }
}

// =============== K3: BN apply + relu + maxpool 3x3/s2/p1 ===================
__global__ __launch_bounds__(256) void k_bnpool(const __hip_bfloat16* __restrict__ sin_,
                                                const float* __restrict__ stats,
                                                float* __restrict__ f) {
    const int t = blockIdx.x * 256 + threadIdx.x;   // 16*64*128*128 exact
    const int pw = t & 127;
    const int ph = (t >> 7) & 127;
    const int c = (t >> 14) & 63;
    const float a = stats[c], b = stats[64 + c];
    const __hip_bfloat16* base = sin_ + (size_t)(t >> 14) * 65536;
    const int r0 = ph * 2 - 1, c0 = pw * 2 - 1;
    float mx = -1e30f;
#pragma unroll
    for (int dr = 0; dr < 3; dr++) {
        int r = r0 + dr;
        if ((unsigned)r >= 256u) continue;
#pragma unroll
        for (int dc = 0; dc < 3; dc++) {
            int cc = c0 + dc;
            if ((unsigned)cc >= 256u) continue;
            float v = __bfloat162float(base[r * 256 + cc]);
            mx = fmaxf(mx, a * v + b);
        }
    }
    f[t] = fmaxf(mx, 0.f);
}

// ============== K4: grid_sample, both rotations in one pass ================
__device__ __forceinline__ float gs_gather(const float* img, float yy, float xx, float wt) {
    bool valid = (xx >= 0.f) & (xx < 128.f) & (yy >= 0.f) & (yy < 128.f);
    int xi = (int)fminf(fmaxf(xx, 0.f), 127.f);
    int yi = (int)fminf(fmaxf(yy, 0.f), 127.f);
    return valid ? img[yi * 128 + xi] * wt : 0.f;
}

__device__ __forceinline__ float gs_one(const float* img, float ix, float iy) {
    float x0 = floorf(ix), y0 = floorf(iy);
    float lx = ix - x0, ly = iy - y0;
    float wa = (1.f - lx) * (1.f - ly);
    float wb = (1.f - lx) * ly;
    float wc = lx * (1.f - ly);
    float wd = lx * ly;
    return gs_gather(img, y0,       x0,       wa)
         + gs_gather(img, y0 + 1.f, x0,       wb)
         + gs_gather(img, y0,       x0 + 1.f, wc)
         + gs_gather(img, y0 + 1.f, x0 + 1.f, wd);
}

__global__ __launch_bounds__(256) void k_gridsample2(const float* __restrict__ f,
                                                     float* __restrict__ xt1,
                                                     float* __restrict__ xt2) {
    const int t = blockIdx.x * 256 + threadIdx.x;
    const int w = t & 127;
    const int h = (t >> 7) & 127;
    const float* img = f + ((size_t)(t >> 14) << 14);
    float gx = (2 * w + 1) * (1.f / 128.f) - 1.f;
    float gy = (2 * h + 1) * (1.f / 128.f) - 1.f;
    float g0a = C5 * gx + S5 * gy,  g1a = -S5 * gx + C5 * gy;
    float g0b = C5 * gx - S5 * gy,  g1b =  S5 * gx + C5 * gy;
    xt1[t] = gs_one(img, ((g0a + 1.f) * 128.f - 1.f) * 0.5f,
                         ((g1a + 1.f) * 128.f - 1.f) * 0.5f);
    xt2[t] = gs_one(img, ((g0b + 1.f) * 128.f - 1.f) * 0.5f,
                         ((g1b + 1.f) * 128.f - 1.f) * 0.5f);
}

// ======================= K5: roialign into concat h (bf16) =================
__global__ __launch_bounds__(256) void k_roialign(const float* __restrict__ f,
                                                  const float* __restrict__ xt1,
                                                  const float* __restrict__ xt2,
                                                  const float* __restrict__ box,
                                                  __hip_bfloat16* __restrict__ h) {
    const int bx = blockIdx.x;
    const int cg = bx & 7;
    const int job = (bx >> 3) % 11;
    const int n = bx / 88;
    int j, cbase;
    const float* src;
    if (job < 7)      { j = job;     cbase = job * 64;             src = f;   }
    else if (job < 9) { j = job - 7; cbase = 448 + (job - 7) * 64; src = xt1; }
    else              { j = job - 9; cbase = 576 + (job - 9) * 64; src = xt2; }
    const float* bp = box + n * 28 + j * 4;
    const float x1 = bp[0] * 0.25f, y1 = bp[1] * 0.25f;
    const float x2 = bp[2] * 0.25f, y2 = bp[3] * 0.25f;
    const float bw = fmaxf(x2 - x1, 1.f) * (1.f / 23.f);
    const float bh = fmaxf(y2 - y1, 1.f) * (1.f / 23.f);

    for (int idx = threadIdx.x; idx < 8 * 529; idx += 256) {
        const int cl = idx / 529;
        const int pp = idx - cl * 529;
        const int ph = pp / 23, pw = pp - ph * 23;
        const float* img = src + (size_t)(n * 64 + cg * 8 + cl) * 16384;
        float sum = 0.f;
#pragma unroll
        for (int r1 = 0; r1 < 2; r1++) {
            const float yv = y1 + (ph + r1 * 0.5f + 0.25f) * bh;
#pragma unroll
            for (int r2 = 0; r2 < 2; r2++) {
                const float xv = x1 + (pw + r2 * 0.5f + 0.25f) * bw;
                if (yv < -1.f || yv > 128.f || xv < -1.f || xv > 128.f) continue;
                float y = fminf(fmaxf(yv, 0.f), 127.f);
                float x = fminf(fmaxf(xv, 0.f), 127.f);
                float y0f = floorf(y), x0f = floorf(x);
                int y0 = (int)y0f, x0 = (int)x0f;
                int y1i = min(y0 + 1, 127), x1i = min(x0 + 1, 127);
                float ly = y - y0f, lx = x - x0f;
                float hy = 1.f - ly, hx = 1.f - lx;
                sum += img[y0 * 128 + x0]  * hy * hx + img[y0 * 128 + x1i]  * hy * lx
                     + img[y1i * 128 + x0] * ly * hx + img[y1i * 128 + x1i] * ly * lx;
            }
        }
        h[(size_t)(n * 704 + cbase + cg * 8 + cl) * 529 + pp] =
            __float2bfloat16(sum * 0.25f);
    }
}

// =================== K6: conv1 MFMA bf16, split-K=3 ========================
__global__ __launch_bounds__(256) void k_conv1m(const ushort* __restrict__ hb,
                                                const ushort* __restrict__ w1b,
                                                float* __restrict__ c1p) {
    __shared__ __align__(16) ushort Bs[2][32][40];   // [panel][pos][kk], stride 40
    const int bx = blockIdx.x;
    const int pt = bx % 17;
    const int n  = (bx / 17) & 15;
    const int s  = bx / 272;
    const int tid = threadIdx.x;
    const int w = tid >> 6, lane = tid & 63;
    const int quad = lane >> 4, m = lane & 15;
    const int kbase = s * 2112;
    const int posb = pt * 32;
    const size_t hb_n = (size_t)n * 704 * 529;
    f32x4 acc0 = {0.f, 0.f, 0.f, 0.f};
    f32x4 acc1 = {0.f, 0.f, 0.f, 0.f};
    const ushort* wrow = w1b + (size_t)(w * 16 + m) * 6336;

    for (int it = 0; it < 33; it++) {
        const int k0 = kbase + it * 64;
        __syncthreads();
        for (int e = tid; e < 2048; e += 256) {
            int panel = e >> 10, kk = (e >> 5) & 31, pos = e & 31;
            int k = k0 + panel * 32 + kk;
            int ci = k / 9, tap = k - ci * 9;
            int kh = tap / 3, kw = tap - kh * 3;
            Bs[panel][pos][kk] =
                hb[hb_n + (size_t)ci * 529 + kh * 23 + kw + posb + pos];
        }
        __syncthreads();
        const short8 a0  = *(const short8*)(wrow + k0 + quad * 8);
        const short8 a1  = *(const short8*)(wrow + k0 + 32 + quad * 8);
        const short8 b00 = *(const short8*)&Bs[0][m][quad * 8];
        const short8 b01 = *(const short8*)&Bs[0][16 + m][quad * 8];
        const short8 b10 = *(const short8*)&Bs[1][m][quad * 8];
        const short8 b11 = *(const short8*)&Bs[1][16 + m][quad * 8];
        acc0 = __builtin_amdgcn_mfma_f32_16x16x32_bf16(a0, b00, acc0, 0, 0, 0);
        acc1 = __builtin_amdgcn_mfma_f32_16x16x32_bf16(a0, b01, acc1, 0, 0, 0);
        acc0 = __builtin_amdgcn_mfma_f32_16x16x32_bf16(a1, b10, acc0, 0, 0, 0);
        acc1 = __builtin_amdgcn_mfma_f32_16x16x32_bf16(a1, b11, acc1, 0, 0, 0);
    }
    float* outp = c1p + ((size_t)(s * 16 + n) * 64) * 544;
#pragma unroll
    for (int r = 0; r < 4; r++) {
        const int oc = w * 16 + quad * 4 + r;
        outp[(size_t)oc * 544 + posb + m]      = acc0[r];
        outp[(size_t)oc * 544 + posb + 16 + m] = acc1[r];
    }
}

// =================== K6b: split-K reduce + bias ============================
__global__ __launch_bounds__(256) void k_c1red(const float* __restrict__ c1p,
                                               const float* __restrict__ b1,
                                               float* __restrict__ c1) {
    const int t = blockIdx.x * 256 + threadIdx.x;   // 451584 exact
    const int p = t % 441;
    const int oc = (t / 441) % 64;
    const int n = t / 28224;
    const int ph = p / 21, pw = p - ph * 21;
    const int p529 = ph * 23 + pw;
    const size_t base = ((size_t)n * 64 + oc) * 544 + p529;
    const size_t sstr = (size_t)16 * 64 * 544;
    c1[t] = c1p[base] + c1p[base + sstr] + c1p[base + 2 * sstr] + b1[oc];
}

// ================ K8: BN1 apply + relu + maxpool 2x2/s2 ====================
__global__ __launch_bounds__(256) void k_bnpool2(const float* __restrict__ c1,
                                                 const float* __restrict__ stats1,
                                                 float* __restrict__ p1) {
    const int t = blockIdx.x * 256 + threadIdx.x;   // 102400 exact
    const int pw = t % 10;
    const int ph = (t / 10) % 10;
    const int c = (t / 100) % 64;
    const int n = t / 6400;
    const float a = stats1[c], b = stats1[64 + c];
    const float* base = c1 + (size_t)(n * 64 + c) * 441;
    const int r = ph * 2, cc = pw * 2;
    float v0 = a * base[r * 21 + cc] + b;
    float v1 = a * base[r * 21 + cc + 1] + b;
    float v2 = a * base[(r + 1) * 21 + cc] + b;
    float v3 = a * base[(r + 1) * 21 + cc + 1] + b;
    p1[t] = fmaxf(fmaxf(fmaxf(v0, v1), fmaxf(v2, v3)), 0.f);
}

// ================ K9: conv2 3x3 (64->32) + bias + relu =====================
__global__ __launch_bounds__(256) void k_conv2(const float* __restrict__ p1,
                                               const float* __restrict__ w2,
                                               const float* __restrict__ b2,
                                               float* __restrict__ c2) {
    const int t = blockIdx.x * 256 + threadIdx.x;   // 32768 exact
    const int pw = t & 7;
    const int ph = (t >> 3) & 7;
    const int oc = (t >> 6) & 31;
    const int n = t >> 11;
    float s = b2[oc];
    for (int ci = 0; ci < 64; ci++) {
        const float* ib = p1 + (size_t)(n * 64 + ci) * 100;
        const float* wb = w2 + (size_t)(oc * 64 + ci) * 9;
#pragma unroll
        for (int kh = 0; kh < 3; kh++)
#pragma unroll
            for (int kw = 0; kw < 3; kw++)
                s += ib[(ph + kh) * 10 + pw + kw] * wb[kh * 3 + kw];
    }
    c2[t] = fmaxf(s, 0.f);
}

// ======================= K10: fc1 + relu ===================================
__global__ __launch_bounds__(64) void k_fc1(const float* __restrict__ c2,
                                            const float* __restrict__ fw,
                                            const float* __restrict__ fb,
                                            float* __restrict__ fo) {
    const int bx = blockIdx.x;
    const int oc = bx & 127, n = bx >> 7;
    const int lane = threadIdx.x;
    const float* a = c2 + (size_t)n * 2048;
    const float* w = fw + (size_t)oc * 2048;
    float s = 0.f;
    for (int k = lane; k < 2048; k += 64) s += a[k] * w[k];
#pragma unroll
    for (int off = 32; off; off >>= 1) s += __shfl_xor(s, off, 64);
    if (lane == 0) fo[n * 128 + oc] = fmaxf(s + fb[oc], 0.f);
}

// ======================= K11: head + tanh ==================================
__global__ __launch_bounds__(64) void k_head(const float* __restrict__ fo,
                                             const float* __restrict__ hw,
                                             const float* __restrict__ hb,
                                             float* __restrict__ out) {
    const int bx = blockIdx.x;
    const int oc = bx % 12, n = bx / 12;
    const int lane = threadIdx.x;
    float s = 0.f;
    for (int k = lane; k < 128; k += 64) s += fo[n * 128 + k] * hw[oc * 128 + k];
#pragma unroll
    for (int off = 32; off; off >>= 1) s += __shfl_xor(s, off, 64);
    if (lane == 0) out[bx] = tanhf(s + hb[oc]);
}

// ===========================================================================
extern "C" void kernel_launch(void* const* d_in, const int* in_sizes, int n_in,
                              void* d_out, int out_size, void* d_ws, size_t ws_size,
                              hipStream_t stream) {
    const float* x       = (const float*)d_in[0];
    const float* box     = (const float*)d_in[1];
    const float* stem_w  = (const float*)d_in[2];
    const float* stem_g  = (const float*)d_in[3];
    const float* stem_b  = (const float*)d_in[4];
    const float* conv1_w = (const float*)d_in[5];
    const float* conv1_b = (const float*)d_in[6];
    const float* bn1_g   = (const float*)d_in[7];
    const float* bn1_b   = (const float*)d_in[8];
    const float* conv2_w = (const float*)d_in[9];
    const float* conv2_b = (const float*)d_in[10];
    const float* fc1_w   = (const float*)d_in[11];
    const float* fc1_b   = (const float*)d_in[12];
    const float* head_w  = (const float*)d_in[13];
    const float* head_b  = (const float*)d_in[14];
    float* out = (float*)d_out;
    float* w = (float*)d_ws;

    const size_t F_SZ = 16777216;                         // 16*64*128*128
    float* f   = w;                                       // fp32
    __hip_bfloat16* stem = (__hip_bfloat16*)(w + F_SZ);   // bf16, spans 2*F_SZ floats
    float* xt1 = w + F_SZ;                                // aliases stem (dead after K3)
    float* xt2 = w + 2 * F_SZ;
    float* base3 = w + 3 * F_SZ;
    __hip_bfloat16* hbuf = (__hip_bfloat16*)base3;        // 5958656 els = 2979328+pad
    float* c1   = base3 + 2979392;                        // 451584
    float* c1p  = c1 + 451584;                            // 3*16*64*544 = 1671168
    float* p1   = c1p + 1671168;                          // 102400
    float* c2   = p1 + 102400;                            // 32768
    float* fo   = c2 + 32768;                             // 2048
    float* partial = fo + 2048;                           // 8192*128 = 1048576
    float* stats   = partial + 1048576;                   // 128
    float* stats1  = stats + 128;                         // 128
    __hip_bfloat16* w1b = (__hip_bfloat16*)(stats1 + 128); // 405504 els = 202752 floats
    __hip_bfloat16* w2b = (__hip_bfloat16*)(stats1 + 128 + 202752); // 12288 els

    k_cvtw1<<<1584, 256, 0, stream>>>(conv1_w, w1b);
    k_cvtw2<<<48, 256, 0, stream>>>(stem_w, w2b);
    k_stem<<<8192, 256, 0, stream>>>(x, (const ushort*)w2b, stem, partial);
    k_bnstats<<<64, 256, 0, stream>>>(partial, 8192, stem_g, stem_b, stats,
                                      1.f / 1048576.f);
    k_bnpool<<<65536, 256, 0, stream>>>(stem, stats, f);
    k_gridsample2<<<65536, 256, 0, stream>>>(f, xt1, xt2);
    k_roialign<<<1408, 256, 0, stream>>>(f, xt1, xt2, box, hbuf);
    k_conv1m<<<816, 256, 0, stream>>>((const ushort*)hbuf, (const ushort*)w1b, c1p);
    k_c1red<<<1764, 256, 0, stream>>>(c1p, conv1_b, c1);
    k_bn1stats<<<64, 256, 0, stream>>>(c1, bn1_g, bn1_b, stats1);
    k_bnpool2<<<400, 256, 0, stream>>>(c1, stats1, p1);
    k_conv2<<<128, 256, 0, stream>>>(p1, conv2_w, conv2_b, c2);
    k_fc1<<<2048, 64, 0, stream>>>(c2, fc1_w, fc1_b, fo);
    k_head<<<192, 64, 0, stream>>>(fo, head_w, head_b, out);
}

// Round 6
// 658.050 us; speedup vs baseline: 2.4853x; 1.0543x over previous
//
#include <hip/hip_runtime.h>
#include <hip/hip_bf16.h>

// ---------------------------------------------------------------------------
// FocusPolicy pipeline, MI355X.
//  K0a convert conv1_w -> bf16                        -> w1b
//  K0b reorder+convert stem_w -> bf16 K=192           -> w2b  (k = kh*24+kw*3+ci+3)
//  K1 stem conv 7x7/s2 MFMA bf16 + BN partials        -> stem(bf16), partials
//     (B-frags read directly from raw slab; u-shift-3 makes slab float4-aligned;
//      straddle / kh==7 / u<3 lanes multiply zero weights)
//  K2 BN finalize                                     -> stats
//  K3 BN apply + relu + maxpool3/2p1                  -> f   (16,64,128,128)
//  K4 grid_sample (+-5 deg), both in one pass         -> xt1, xt2
//  K5 roialign (11 jobs) -> concat (bf16)             -> h   (16,704,23,23)
//  K6 conv1 3x3 (704->64) MFMA bf16, split-K=3        -> c1p
//  K6b reduce split-K + bias                          -> c1  (16,64,21,21)
//  K7 BN1 stats;  K8 BN+relu+maxpool2/2;  K9 conv2;  K10 fc1;  K11 head
// ---------------------------------------------------------------------------

#define C5 0.9961946980917455f
#define S5 0.08715574274765817f

typedef __attribute__((ext_vector_type(8))) short short8;
typedef __attribute__((ext_vector_type(4))) float f32x4;

__device__ __forceinline__ ushort f2bf_bits(float v) {
    __hip_bfloat16 b = __float2bfloat16(v);
    ushort u;
    __builtin_memcpy(&u, &b, 2);
    return u;
}

// ======================= K0a: conv1 weights -> bf16 ========================
__global__ __launch_bounds__(256) void k_cvtw1(const float* __restrict__ w1,
                                               __hip_bfloat16* __restrict__ w1b) {
    const int t = blockIdx.x * 256 + threadIdx.x;   // 64*6336 = 405504 exact
    w1b[t] = __float2bfloat16(w1[t]);
}

// ========== K0b: stem weights -> bf16, k-order kh*24 + (kw*3+ci+3) =========
// Zeros at u in {0,1,2} and kh==7 — the stem K-loop relies on these to
// neutralize garbage B-fragment lanes (position straddle / pad rows).
__global__ __launch_bounds__(256) void k_cvtw2(const float* __restrict__ sw,
                                               __hip_bfloat16* __restrict__ w2b) {
    const int e = blockIdx.x * 256 + threadIdx.x;   // 64*192 = 12288 exact
    const int oc = e / 192, k = e - oc * 192;
    const int kh = k / 24, u = k - kh * 24;
    float v = 0.f;
    if (u >= 3 && kh < 7) {
        int t = u - 3;
        int kw = t / 3, ci = t - kw * 3;
        v = sw[oc * 147 + ci * 49 + kh * 7 + kw];
    }
    w2b[e] = __float2bfloat16(v);
}

// =================== K1: stem conv MFMA + BN partials ======================
// grid 8192 = n(16) x oh(256) x pt(2); block 256 = 4 waves.
// Tile: M=64 oc, N=128 positions, K=192 (147 real + zero pad).
// Phase A: 8 float4 loads ALL IN FLIGHT (batched), then cvt + ds_write_b64.
__global__ __launch_bounds__(256, 6) void k_stem(const float* __restrict__ x,
                                                 const ushort* __restrict__ w2b,
                                                 __hip_bfloat16* __restrict__ out,
                                                 float* __restrict__ partial) {
    __shared__ __align__(16) ushort smem[64 * 136];  // raw 8x792 / tile 64x136
    __shared__ float sredS[4][64], sredQ[4][64];
    ushort* raw = smem;
    const int bx = blockIdx.x;
    const int pt = bx & 1;
    const int oh = (bx >> 1) & 255;
    const int n  = bx >> 9;
    const int tid = threadIdx.x;
    const int w = tid >> 6, lane = tid & 63;
    const int quad = lane >> 4, m = lane & 15;
    const int posb = pt * 128;

    // ---- phase A: global fp32 -> raw bf16 slab, batched float4 loads ----
    // raw[kh][lidx] = x[ih = 2*oh-3+kh][fc = base_fc + lidx], base_fc = 6*posb-12
    const int base_fc = posb * 6 - 12;               // -12 or 756, both %4==0
    if (tid < 198) {
        const bool colv = (pt == 0) ? (tid >= 3) : (tid < 195);
        const float* xn = x + (size_t)n * 786432 + base_fc + 4 * tid;
        float4 v[8];
#pragma unroll
        for (int r = 0; r < 8; r++) {
            const int ih = oh * 2 - 3 + r;
            float4 t = {0.f, 0.f, 0.f, 0.f};
            if (colv && (unsigned)ih < 512u)
                t = *(const float4*)(xn + (size_t)ih * 1536);
            v[r] = t;
        }
#pragma unroll
        for (int r = 0; r < 8; r++) {
            uint2 p;
            p.x = (uint)f2bf_bits(v[r].x) | ((uint)f2bf_bits(v[r].y) << 16);
            p.y = (uint)f2bf_bits(v[r].z) | ((uint)f2bf_bits(v[r].w) << 16);
            *(uint2*)&raw[r * 792 + 4 * tid] = p;
        }
    }
    __syncthreads();

    // ---- K-loop: B-frags straight from raw (sliding-window im2col) ----
    // group g = ks*4 + quad; kh = g/3, gi = g%3; dwords: kh*396 + 3*pos + 4*gi
    f32x4 acc[4][2] = {};
    const int p0 = w * 32 + m;
#pragma unroll
    for (int ks = 0; ks < 6; ks++) {
        const int g  = ks * 4 + quad;
        const int kh = g / 3;
        const int gi = g - kh * 3;
        const uint* rr = (const uint*)raw + kh * 396 + 4 * gi;
        const uint* q0 = rr + 3 * p0;
        const uint* q1 = rr + 3 * (p0 + 16);
        uint4 t0 = (uint4){q0[0], q0[1], q0[2], q0[3]};
        uint4 t1 = (uint4){q1[0], q1[1], q1[2], q1[3]};
        short8 b0, b1;
        __builtin_memcpy(&b0, &t0, 16);
        __builtin_memcpy(&b1, &t1, 16);
        const int ko = ks * 32 + quad * 8;
#pragma unroll
        for (int mt = 0; mt < 4; mt++) {
            const short8 a = *(const short8*)(w2b + (size_t)(mt * 16 + m) * 192 + ko);
            acc[mt][0] = __builtin_amdgcn_mfma_f32_16x16x32_bf16(a, b0, acc[mt][0], 0, 0, 0);
            acc[mt][1] = __builtin_amdgcn_mfma_f32_16x16x32_bf16(a, b1, acc[mt][1], 0, 0, 0);
        }
    }

    // ---- BN partial sums from accumulators (registers + shfl only) ----
#pragma unroll
    for (int mt = 0; mt < 4; mt++) {
        const f32x4 a0 = acc[mt][0], a1 = acc[mt][1];
#pragma unroll
        for (int r = 0; r < 4; r++) {
            float s = a0[r] + a1[r];
            float q = a0[r] * a0[r] + a1[r] * a1[r];
#pragma unroll
            for (int off = 1; off < 16; off <<= 1) {
                s += __shfl_xor(s, off, 64);
                q += __shfl_xor(q, off, 64);
            }
            if (m == 0) {
                const int ocl = mt * 16 + quad * 4 + r;
                sredS[w][ocl] = s;
                sredQ[w][ocl] = q;
            }
        }
    }
    __syncthreads();                     // raw dead; sred visible after here

    // ---- full 64x136 transpose tile, then coalesced 16B stores ----
    ushort* tile = smem;
#pragma unroll
    for (int mt = 0; mt < 4; mt++)
#pragma unroll
        for (int nt = 0; nt < 2; nt++) {
            const int pos = w * 32 + nt * 16 + m;
#pragma unroll
            for (int r = 0; r < 4; r++) {
                const int oc = mt * 16 + quad * 4 + r;
                tile[oc * 136 + pos] = f2bf_bits(acc[mt][nt][r]);
            }
        }
    __syncthreads();
    {
        const int row = tid >> 2, seg = tid & 3;
        const uint4* src = (const uint4*)&tile[row * 136 + seg * 32];
        uint4 a0 = src[0], a1 = src[1], a2 = src[2], a3 = src[3];
        uint4* d4 = (uint4*)((ushort*)out + (size_t)(n * 64 + row) * 65536
                             + oh * 256 + posb + seg * 32);
        d4[0] = a0; d4[1] = a1; d4[2] = a2; d4[3] = a3;
    }

    if (tid < 128) {
        const int oc = tid >> 1, comp = tid & 1;
        float v = 0.f;
#pragma unroll
        for (int ww = 0; ww < 4; ww++)
            v += comp ? sredQ[ww][oc] : sredS[ww][oc];
        partial[bx * 128 + tid] = v;
    }
}

// ======================= K2: BN finalize ===================================
__global__ __launch_bounds__(256) void k_bnstats(const float* __restrict__ partial,
                                                 int nblk,
                                                 const float* __restrict__ gamma,
                                                 const float* __restrict__ beta,
                                                 float* __restrict__ stats,
                                                 float inv_n) {
    const int c = blockIdx.x;
    const int tid = threadIdx.x;
    float s = 0.f, ss = 0.f;
    for (int b = tid; b < nblk; b += 256) {
        s  += partial[b * 128 + c * 2 + 0];
        ss += partial[b * 128 + c * 2 + 1];
    }
    __shared__ float sh[8], sh2[8];
#pragma unroll
    for (int off = 32; off; off >>= 1) {
        s += __shfl_xor(s, off, 64);
        ss += __shfl_xor(ss, off, 64);
    }
    if ((tid & 63) == 0) { sh[tid >> 6] = s; sh2[tid >> 6] = ss; }
    __syncthreads();
    if (tid == 0) {
        s = sh[0] + sh[1] + sh[2] + sh[3];
        ss = sh2[0] + sh2[1] + sh2[2] + sh2[3];
        float mn = s * inv_n;
        float var = ss * inv_n - mn * mn;
        float a = gamma[c] * rsqrtf(var + 1e-5f);
        stats[c] = a;
        stats[64 + c] = beta[c] - mn * a;
    }
}

__global__ __launch_bounds__(256) void k_bn1stats(const float* __restrict__ c1,
                                                  const float* __restrict__ gamma,
                                                  const float* __restrict__ beta,
                                                  float* __restrict__ stats1) {
    const int c = blockIdx.x;
    const int tid = threadIdx.x;
    float s = 0.f, ss = 0.f;
    for (int e = tid; e < 7056; e += 256) {
        int n = e / 441, p = e - n * 441;
        float v = c1[(n * 64 + c) * 441 + p];
        s += v; ss += v * v;
    }
    __shared__ float sh[8], sh2[8];
#pragma unroll
    for (int off = 32; off; off >>= 1) {
        s += __shfl_xor(s, off, 64);
        ss += __shfl_xor(ss, off, 64);
    }
    if ((tid & 63) == 0) { sh[tid >> 6] = s; sh2[tid >> 6] = ss; }
    __syncthreads();
    if (tid == 0) {
        s = sh[0] + sh[1] + sh[2] + sh[3];
        ss = sh2[0] + sh2[1] + sh2[2] + sh2[3];
        const float inv_n = 1.f / 7056.f;
        float mn = s * inv_n;
        float var = ss * inv_n - mn * mn;
        float a = gamma[c] * rsqrtf(var + 1e-5f);
        stats1[c] = a;
        stats1[64 + c] = beta[c] - mn * a;
    }
}

// =============== K3: BN apply + relu + maxpool 3x3/s2/p1 ===================
__global__ __launch_bounds__(256) void k_bnpool(const __hip_bfloat16* __restrict__ sin_,
                                                const float* __restrict__ stats,
                                                float* __restrict__ f) {
    const int t = blockIdx.x * 256 + threadIdx.x;   // 16*64*128*128 exact
    const int pw = t & 127;
    const int ph = (t >> 7) & 127;
    const int c = (t >> 14) & 63;
    const float a = stats[c], b = stats[64 + c];
    const __hip_bfloat16* base = sin_ + (size_t)(t >> 14) * 65536;
    const int r0 = ph * 2 - 1, c0 = pw * 2 - 1;
    float mx = -1e30f;
#pragma unroll
    for (int dr = 0; dr < 3; dr++) {
        int r = r0 + dr;
        if ((unsigned)r >= 256u) continue;
#pragma unroll
        for (int dc = 0; dc < 3; dc++) {
            int cc = c0 + dc;
            if ((unsigned)cc >= 256u) continue;
            float v = __bfloat162float(base[r * 256 + cc]);
            mx = fmaxf(mx, a * v + b);
        }
    }
    f[t] = fmaxf(mx, 0.f);
}

// ============== K4: grid_sample, both rotations in one pass ================
__device__ __forceinline__ float gs_gather(const float* img, float yy, float xx, float wt) {
    bool valid = (xx >= 0.f) & (xx < 128.f) & (yy >= 0.f) & (yy < 128.f);
    int xi = (int)fminf(fmaxf(xx, 0.f), 127.f);
    int yi = (int)fminf(fmaxf(yy, 0.f), 127.f);
    return valid ? img[yi * 128 + xi] * wt : 0.f;
}

__device__ __forceinline__ float gs_one(const float* img, float ix, float iy) {
    float x0 = floorf(ix), y0 = floorf(iy);
    float lx = ix - x0, ly = iy - y0;
    float wa = (1.f - lx) * (1.f - ly);
    float wb = (1.f - lx) * ly;
    float wc = lx * (1.f - ly);
    float wd = lx * ly;
    return gs_gather(img, y0,       x0,       wa)
         + gs_gather(img, y0 + 1.f, x0,       wb)
         + gs_gather(img, y0,       x0 + 1.f, wc)
         + gs_gather(img, y0 + 1.f, x0 + 1.f, wd);
}

__global__ __launch_bounds__(256) void k_gridsample2(const float* __restrict__ f,
                                                     float* __restrict__ xt1,
                                                     float* __restrict__ xt2) {
    const int t = blockIdx.x * 256 + threadIdx.x;
    const int w = t & 127;
    const int h = (t >> 7) & 127;
    const float* img = f + ((size_t)(t >> 14) << 14);
    float gx = (2 * w + 1) * (1.f / 128.f) - 1.f;
    float gy = (2 * h + 1) * (1.f / 128.f) - 1.f;
    float g0a = C5 * gx + S5 * gy,  g1a = -S5 * gx + C5 * gy;
    float g0b = C5 * gx - S5 * gy,  g1b =  S5 * gx + C5 * gy;
    xt1[t] = gs_one(img, ((g0a + 1.f) * 128.f - 1.f) * 0.5f,
                         ((g1a + 1.f) * 128.f - 1.f) * 0.5f);
    xt2[t] = gs_one(img, ((g0b + 1.f) * 128.f - 1.f) * 0.5f,
                         ((g1b + 1.f) * 128.f - 1.f) * 0.5f);
}

// ======================= K5: roialign into concat h (bf16) =================
__global__ __launch_bounds__(256) void k_roialign(const float* __restrict__ f,
                                                  const float* __restrict__ xt1,
                                                  const float* __restrict__ xt2,
                                                  const float* __restrict__ box,
                                                  __hip_bfloat16* __restrict__ h) {
    const int bx = blockIdx.x;
    const int cg = bx & 7;
    const int job = (bx >> 3) % 11;
    const int n = bx / 88;
    int j, cbase;
    const float* src;
    if (job < 7)      { j = job;     cbase = job * 64;             src = f;   }
    else if (job < 9) { j = job - 7; cbase = 448 + (job - 7) * 64; src = xt1; }
    else              { j = job - 9; cbase = 576 + (job - 9) * 64; src = xt2; }
    const float* bp = box + n * 28 + j * 4;
    const float x1 = bp[0] * 0.25f, y1 = bp[1] * 0.25f;
    const float x2 = bp[2] * 0.25f, y2 = bp[3] * 0.25f;
    const float bw = fmaxf(x2 - x1, 1.f) * (1.f / 23.f);
    const float bh = fmaxf(y2 - y1, 1.f) * (1.f / 23.f);

    for (int idx = threadIdx.x; idx < 8 * 529; idx += 256) {
        const int cl = idx / 529;
        const int pp = idx - cl * 529;
        const int ph = pp / 23, pw = pp - ph * 23;
        const float* img = src + (size_t)(n * 64 + cg * 8 + cl) * 16384;
        float sum = 0.f;
#pragma unroll
        for (int r1 = 0; r1 < 2; r1++) {
            const float yv = y1 + (ph + r1 * 0.5f + 0.25f) * bh;
#pragma unroll
            for (int r2 = 0; r2 < 2; r2++) {
                const float xv = x1 + (pw + r2 * 0.5f + 0.25f) * bw;
                if (yv < -1.f || yv > 128.f || xv < -1.f || xv > 128.f) continue;
                float y = fminf(fmaxf(yv, 0.f), 127.f);
                float x = fminf(fmaxf(xv, 0.f), 127.f);
                float y0f = floorf(y), x0f = floorf(x);
                int y0 = (int)y0f, x0 = (int)x0f;
                int y1i = min(y0 + 1, 127), x1i = min(x0 + 1, 127);
                float ly = y - y0f, lx = x - x0f;
                float hy = 1.f - ly, hx = 1.f - lx;
                sum += img[y0 * 128 + x0]  * hy * hx + img[y0 * 128 + x1i]  * hy * lx
                     + img[y1i * 128 + x0] * ly * hx + img[y1i * 128 + x1i] * ly * lx;
            }
        }
        h[(size_t)(n * 704 + cbase + cg * 8 + cl) * 529 + pp] =
            __float2bfloat16(sum * 0.25f);
    }
}

// =================== K6: conv1 MFMA bf16, split-K=3 ========================
__global__ __launch_bounds__(256) void k_conv1m(const ushort* __restrict__ hb,
                                                const ushort* __restrict__ w1b,
                                                float* __restrict__ c1p) {
    __shared__ __align__(16) ushort Bs[2][32][40];   // [panel][pos][kk], stride 40
    const int bx = blockIdx.x;
    const int pt = bx % 17;
    const int n  = (bx / 17) & 15;
    const int s  = bx / 272;
    const int tid = threadIdx.x;
    const int w = tid >> 6, lane = tid & 63;
    const int quad = lane >> 4, m = lane & 15;
    const int kbase = s * 2112;
    const int posb = pt * 32;
    const size_t hb_n = (size_t)n * 704 * 529;
    f32x4 acc0 = {0.f, 0.f, 0.f, 0.f};
    f32x4 acc1 = {0.f, 0.f, 0.f, 0.f};
    const ushort* wrow = w1b + (size_t)(w * 16 + m) * 6336;

    for (int it = 0; it < 33; it++) {
        const int k0 = kbase + it * 64;
        __syncthreads();
        for (int e = tid; e < 2048; e += 256) {
            int panel = e >> 10, kk = (e >> 5) & 31, pos = e & 31;
            int k = k0 + panel * 32 + kk;
            int ci = k / 9, tap = k - ci * 9;
            int kh = tap / 3, kw = tap - kh * 3;
            Bs[panel][pos][kk] =
                hb[hb_n + (size_t)ci * 529 + kh * 23 + kw + posb + pos];
        }
        __syncthreads();
        const short8 a0  = *(const short8*)(wrow + k0 + quad * 8);
        const short8 a1  = *(const short8*)(wrow + k0 + 32 + quad * 8);
        const short8 b00 = *(const short8*)&Bs[0][m][quad * 8];
        const short8 b01 = *(const short8*)&Bs[0][16 + m][quad * 8];
        const short8 b10 = *(const short8*)&Bs[1][m][quad * 8];
        const short8 b11 = *(const short8*)&Bs[1][16 + m][quad * 8];
        acc0 = __builtin_amdgcn_mfma_f32_16x16x32_bf16(a0, b00, acc0, 0, 0, 0);
        acc1 = __builtin_amdgcn_mfma_f32_16x16x32_bf16(a0, b01, acc1, 0, 0, 0);
        acc0 = __builtin_amdgcn_mfma_f32_16x16x32_bf16(a1, b10, acc0, 0, 0, 0);
        acc1 = __builtin_amdgcn_mfma_f32_16x16x32_bf16(a1, b11, acc1, 0, 0, 0);
    }
    float* outp = c1p + ((size_t)(s * 16 + n) * 64) * 544;
#pragma unroll
    for (int r = 0; r < 4; r++) {
        const int oc = w * 16 + quad * 4 + r;
        outp[(size_t)oc * 544 + posb + m]      = acc0[r];
        outp[(size_t)oc * 544 + posb + 16 + m] = acc1[r];
    }
}

// =================== K6b: split-K reduce + bias ============================
__global__ __launch_bounds__(256) void k_c1red(const float* __restrict__ c1p,
                                               const float* __restrict__ b1,
                                               float* __restrict__ c1) {
    const int t = blockIdx.x * 256 + threadIdx.x;   // 451584 exact
    const int p = t % 441;
    const int oc = (t / 441) % 64;
    const int n = t / 28224;
    const int ph = p / 21, pw = p - ph * 21;
    const int p529 = ph * 23 + pw;
    const size_t base = ((size_t)n * 64 + oc) * 544 + p529;
    const size_t sstr = (size_t)16 * 64 * 544;
    c1[t] = c1p[base] + c1p[base + sstr] + c1p[base + 2 * sstr] + b1[oc];
}

// ================ K8: BN1 apply + relu + maxpool 2x2/s2 ====================
__global__ __launch_bounds__(256) void k_bnpool2(const float* __restrict__ c1,
                                                 const float* __restrict__ stats1,
                                                 float* __restrict__ p1) {
    const int t = blockIdx.x * 256 + threadIdx.x;   // 102400 exact
    const int pw = t % 10;
    const int ph = (t / 10) % 10;
    const int c = (t / 100) % 64;
    const int n = t / 6400;
    const float a = stats1[c], b = stats1[64 + c];
    const float* base = c1 + (size_t)(n * 64 + c) * 441;
    const int r = ph * 2, cc = pw * 2;
    float v0 = a * base[r * 21 + cc] + b;
    float v1 = a * base[r * 21 + cc + 1] + b;
    float v2 = a * base[(r + 1) * 21 + cc] + b;
    float v3 = a * base[(r + 1) * 21 + cc + 1] + b;
    p1[t] = fmaxf(fmaxf(fmaxf(v0, v1), fmaxf(v2, v3)), 0.f);
}

// ================ K9: conv2 3x3 (64->32) + bias + relu =====================
__global__ __launch_bounds__(256) void k_conv2(const float* __restrict__ p1,
                                               const float* __restrict__ w2,
                                               const float* __restrict__ b2,
                                               float* __restrict__ c2) {
    const int t = blockIdx.x * 256 + threadIdx.x;   // 32768 exact
    const int pw = t & 7;
    const int ph = (t >> 3) & 7;
    const int oc = (t >> 6) & 31;
    const int n = t >> 11;
    float s = b2[oc];
    for (int ci = 0; ci < 64; ci++) {
        const float* ib = p1 + (size_t)(n * 64 + ci) * 100;
        const float* wb = w2 + (size_t)(oc * 64 + ci) * 9;
#pragma unroll
        for (int kh = 0; kh < 3; kh++)
#pragma unroll
            for (int kw = 0; kw < 3; kw++)
                s += ib[(ph + kh) * 10 + pw + kw] * wb[kh * 3 + kw];
    }
    c2[t] = fmaxf(s, 0.f);
}

// ======================= K10: fc1 + relu ===================================
__global__ __launch_bounds__(64) void k_fc1(const float* __restrict__ c2,
                                            const float* __restrict__ fw,
                                            const float* __restrict__ fb,
                                            float* __restrict__ fo) {
    const int bx = blockIdx.x;
    const int oc = bx & 127, n = bx >> 7;
    const int lane = threadIdx.x;
    const float* a = c2 + (size_t)n * 2048;
    const float* w = fw + (size_t)oc * 2048;
    float s = 0.f;
    for (int k = lane; k < 2048; k += 64) s += a[k] * w[k];
#pragma unroll
    for (int off = 32; off; off >>= 1) s += __shfl_xor(s, off, 64);
    if (lane == 0) fo[n * 128 + oc] = fmaxf(s + fb[oc], 0.f);
}

// ======================= K11: head + tanh ==================================
__global__ __launch_bounds__(64) void k_head(const float* __restrict__ fo,
                                             const float* __restrict__ hw,
                                             const float* __restrict__ hb,
                                             float* __restrict__ out) {
    const int bx = blockIdx.x;
    const int oc = bx % 12, n = bx / 12;
    const int lane = threadIdx.x;
    float s = 0.f;
    for (int k = lane; k < 128; k += 64) s += fo[n * 128 + k] * hw[oc * 128 + k];
#pragma unroll
    for (int off = 32; off; off >>= 1) s += __shfl_xor(s, off, 64);
    if (lane == 0) out[bx] = tanhf(s + hb[oc]);
}

// ===========================================================================
extern "C" void kernel_launch(void* const* d_in, const int* in_sizes, int n_in,
                              void* d_out, int out_size, void* d_ws, size_t ws_size,
                              hipStream_t stream) {
    const float* x       = (const float*)d_in[0];
    const float* box     = (const float*)d_in[1];
    const float* stem_w  = (const float*)d_in[2];
    const float* stem_g  = (const float*)d_in[3];
    const float* stem_b  = (const float*)d_in[4];
    const float* conv1_w = (const float*)d_in[5];
    const float* conv1_b = (const float*)d_in[6];
    const float* bn1_g   = (const float*)d_in[7];
    const float* bn1_b   = (const float*)d_in[8];
    const float* conv2_w = (const float*)d_in[9];
    const float* conv2_b = (const float*)d_in[10];
    const float* fc1_w   = (const float*)d_in[11];
    const float* fc1_b   = (const float*)d_in[12];
    const float* head_w  = (const float*)d_in[13];
    const float* head_b  = (const float*)d_in[14];
    float* out = (float*)d_out;
    float* w = (float*)d_ws;

    const size_t F_SZ = 16777216;                         // 16*64*128*128
    float* f   = w;                                       // fp32
    __hip_bfloat16* stem = (__hip_bfloat16*)(w + F_SZ);   // bf16, spans 2*F_SZ floats
    float* xt1 = w + F_SZ;                                // aliases stem (dead after K3)
    float* xt2 = w + 2 * F_SZ;
    float* base3 = w + 3 * F_SZ;
    __hip_bfloat16* hbuf = (__hip_bfloat16*)base3;        // 5958656 els = 2979328+pad
    float* c1   = base3 + 2979392;                        // 451584
    float* c1p  = c1 + 451584;                            // 3*16*64*544 = 1671168
    float* p1   = c1p + 1671168;                          // 102400
    float* c2   = p1 + 102400;                            // 32768
    float* fo   = c2 + 32768;                             // 2048
    float* partial = fo + 2048;                           // 8192*128 = 1048576
    float* stats   = partial + 1048576;                   // 128
    float* stats1  = stats + 128;                         // 128
    __hip_bfloat16* w1b = (__hip_bfloat16*)(stats1 + 128); // 405504 els = 202752 floats
    __hip_bfloat16* w2b = (__hip_bfloat16*)(stats1 + 128 + 202752); // 12288 els

    k_cvtw1<<<1584, 256, 0, stream>>>(conv1_w, w1b);
    k_cvtw2<<<48, 256, 0, stream>>>(stem_w, w2b);
    k_stem<<<8192, 256, 0, stream>>>(x, (const ushort*)w2b, stem, partial);
    k_bnstats<<<64, 256, 0, stream>>>(partial, 8192, stem_g, stem_b, stats,
                                      1.f / 1048576.f);
    k_bnpool<<<65536, 256, 0, stream>>>(stem, stats, f);
    k_gridsample2<<<65536, 256, 0, stream>>>(f, xt1, xt2);
    k_roialign<<<1408, 256, 0, stream>>>(f, xt1, xt2, box, hbuf);
    k_conv1m<<<816, 256, 0, stream>>>((const ushort*)hbuf, (const ushort*)w1b, c1p);
    k_c1red<<<1764, 256, 0, stream>>>(c1p, conv1_b, c1);
    k_bn1stats<<<64, 256, 0, stream>>>(c1, bn1_g, bn1_b, stats1);
    k_bnpool2<<<400, 256, 0, stream>>>(c1, stats1, p1);
    k_conv2<<<128, 256, 0, stream>>>(p1, conv2_w, conv2_b, c2);
    k_fc1<<<2048, 64, 0, stream>>>(c2, fc1_w, fc1_b, fo);
    k_head<<<192, 64, 0, stream>>>(fo, head_w, head_b, out);
}

// Round 8
// 647.696 us; speedup vs baseline: 2.5250x; 1.0160x over previous
//
#include <hip/hip_runtime.h>
#include <hip/hip_bf16.h>

// ---------------------------------------------------------------------------
// FocusPolicy pipeline, MI355X.
//  K0a convert conv1_w -> bf16                        -> w1b
//  K0b reorder+convert stem_w -> bf16 K=192           -> w2b  (k = kh*24+kw*3+ci+3)
//  K1 stem conv 7x7/s2 MFMA bf16 + BN partials        -> stem(bf16), partials
//     (full-width: 1 block = 1 output row, N=256, 4096 blocks)
//  K2 BN finalize                                     -> stats
//  K3 BN apply + relu + maxpool3/2p1 (8 out/thread)   -> f   (16,64,128,128)
//  K4 grid_sample (+-5 deg), both in one pass         -> xt1, xt2
//  K5 roialign (11 jobs) -> concat (bf16)             -> h   (16,704,23,23)
//  K6 conv1 3x3 (704->64) MFMA bf16, split-K=3        -> c1p
//  K6b reduce split-K + bias                          -> c1  (16,64,21,21)
//  K7 BN1 stats;  K8 BN+relu+maxpool2/2;  K9 conv2 (LDS);  K10 fc1;  K11 head
// ---------------------------------------------------------------------------

#define C5 0.9961946980917455f
#define S5 0.08715574274765817f

typedef __attribute__((ext_vector_type(8))) short short8;
typedef __attribute__((ext_vector_type(4))) float f32x4;

__device__ __forceinline__ ushort f2bf_bits(float v) {
    __hip_bfloat16 b = __float2bfloat16(v);
    ushort u;
    __builtin_memcpy(&u, &b, 2);
    return u;
}
__device__ __forceinline__ float bfbits2f(ushort u) {
    __hip_bfloat16 b;
    __builtin_memcpy(&b, &u, 2);
    return __bfloat162float(b);
}

// ======================= K0a: conv1 weights -> bf16 ========================
__global__ __launch_bounds__(256) void k_cvtw1(const float* __restrict__ w1,
                                               __hip_bfloat16* __restrict__ w1b) {
    const int t = blockIdx.x * 256 + threadIdx.x;   // 64*6336 = 405504 exact
    w1b[t] = __float2bfloat16(w1[t]);
}

// ========== K0b: stem weights -> bf16, k-order kh*24 + (kw*3+ci+3) =========
__global__ __launch_bounds__(256) void k_cvtw2(const float* __restrict__ sw,
                                               __hip_bfloat16* __restrict__ w2b) {
    const int e = blockIdx.x * 256 + threadIdx.x;   // 64*192 = 12288 exact
    const int oc = e / 192, k = e - oc * 192;
    const int kh = k / 24, u = k - kh * 24;
    float v = 0.f;
    if (u >= 3 && kh < 7) {
        int t = u - 3;
        int kw = t / 3, ci = t - kw * 3;
        v = sw[oc * 147 + ci * 49 + kh * 7 + kw];
    }
    w2b[e] = __float2bfloat16(v);
}

// =================== K1: stem conv MFMA + BN partials ======================
// grid 4096 = n(16) x oh(256); block 256 = 4 waves. Full output row per block:
// M=64 oc, N=256 positions (wave w -> pos w*64..+63), K=192.
// Slab: 8 rows x 1560 shorts (lidx = fc+12; zeros at edges).
__global__ __launch_bounds__(256, 3) void k_stem(const float* __restrict__ x,
                                                 const ushort* __restrict__ w2b,
                                                 __hip_bfloat16* __restrict__ out,
                                                 float* __restrict__ partial) {
    __shared__ __align__(16) ushort smem[64 * 264];  // slab 8x1560 / tile 64x264
    __shared__ float sredS[4][64], sredQ[4][64];
    const int bx = blockIdx.x;
    const int oh = bx & 255;
    const int n  = bx >> 8;
    const int tid = threadIdx.x;
    const int w = tid >> 6, lane = tid & 63;
    const int quad = lane >> 4, m = lane & 15;

    // ---- phase A: 3120 float4 slots, two batched flights ----
    // slot e: row = e/390, col = e%390; fc = 4*col-12; valid col in [3,386]
    const float* xn = x + (size_t)n * 786432;
    {
        float4 v[7];
#pragma unroll
        for (int i = 0; i < 7; i++) {
            const int e = tid + 256 * i;
            const int row = e / 390, col = e - row * 390;
            const int ih = oh * 2 - 3 + row;
            float4 t = {0.f, 0.f, 0.f, 0.f};
            if (col >= 3 && col <= 386 && (unsigned)ih < 512u)
                t = *(const float4*)(xn + (size_t)ih * 1536 + 4 * col - 12);
            v[i] = t;
        }
#pragma unroll
        for (int i = 0; i < 7; i++) {
            const int e = tid + 256 * i;
            const int row = e / 390, col = e - row * 390;
            uint2 p;
            p.x = (uint)f2bf_bits(v[i].x) | ((uint)f2bf_bits(v[i].y) << 16);
            p.y = (uint)f2bf_bits(v[i].z) | ((uint)f2bf_bits(v[i].w) << 16);
            *(uint2*)((uint*)smem + row * 780 + 2 * col) = p;
        }
    }
    {
        float4 v[6];
#pragma unroll
        for (int i = 0; i < 6; i++) {
            const int e = tid + 1792 + 256 * i;
            const int row = e / 390, col = e - row * 390;
            const int ih = oh * 2 - 3 + row;
            float4 t = {0.f, 0.f, 0.f, 0.f};
            if (e < 3120 && col >= 3 && col <= 386 && (unsigned)ih < 512u)
                t = *(const float4*)(xn + (size_t)ih * 1536 + 4 * col - 12);
            v[i] = t;
        }
#pragma unroll
        for (int i = 0; i < 6; i++) {
            const int e = tid + 1792 + 256 * i;
            if (e < 3120) {
                const int row = e / 390, col = e - row * 390;
                uint2 p;
                p.x = (uint)f2bf_bits(v[i].x) | ((uint)f2bf_bits(v[i].y) << 16);
                p.y = (uint)f2bf_bits(v[i].z) | ((uint)f2bf_bits(v[i].w) << 16);
                *(uint2*)((uint*)smem + row * 780 + 2 * col) = p;
            }
        }
    }
    __syncthreads();

    // ---- K-loop: B-frags straight from slab (sliding-window im2col) ----
    f32x4 acc[4][4] = {};
#pragma unroll
    for (int ks = 0; ks < 6; ks++) {
        const int g  = ks * 4 + quad;
        const int kh = g / 3;
        const int gi = g - kh * 3;
        const uint* rr = (const uint*)smem + kh * 780 + 4 * gi;
        short8 b[4];
#pragma unroll
        for (int nt = 0; nt < 4; nt++) {
            const uint* q = rr + 3 * (w * 64 + nt * 16 + m);
            uint4 t = (uint4){q[0], q[1], q[2], q[3]};
            __builtin_memcpy(&b[nt], &t, 16);
        }
        const int ko = ks * 32 + quad * 8;
#pragma unroll
        for (int mt = 0; mt < 4; mt++) {
            const short8 a = *(const short8*)(w2b + (size_t)(mt * 16 + m) * 192 + ko);
#pragma unroll
            for (int nt = 0; nt < 4; nt++)
                acc[mt][nt] = __builtin_amdgcn_mfma_f32_16x16x32_bf16(a, b[nt], acc[mt][nt], 0, 0, 0);
        }
    }

    // ---- BN partial sums ----
#pragma unroll
    for (int mt = 0; mt < 4; mt++) {
#pragma unroll
        for (int r = 0; r < 4; r++) {
            float s = acc[mt][0][r] + acc[mt][1][r] + acc[mt][2][r] + acc[mt][3][r];
            float q = acc[mt][0][r] * acc[mt][0][r] + acc[mt][1][r] * acc[mt][1][r]
                    + acc[mt][2][r] * acc[mt][2][r] + acc[mt][3][r] * acc[mt][3][r];
#pragma unroll
            for (int off = 1; off < 16; off <<= 1) {
                s += __shfl_xor(s, off, 64);
                q += __shfl_xor(q, off, 64);
            }
            if (m == 0) {
                const int ocl = mt * 16 + quad * 4 + r;
                sredS[w][ocl] = s;
                sredQ[w][ocl] = q;
            }
        }
    }
    __syncthreads();                     // slab dead; sred visible

    // ---- transpose tile 64 oc x 264(pad) pos, then coalesced stores ----
#pragma unroll
    for (int mt = 0; mt < 4; mt++)
#pragma unroll
        for (int nt = 0; nt < 4; nt++) {
            const int pos = w * 64 + nt * 16 + m;
#pragma unroll
            for (int r = 0; r < 4; r++) {
                const int oc = mt * 16 + quad * 4 + r;
                smem[oc * 264 + pos] = f2bf_bits(acc[mt][nt][r]);
            }
        }
    __syncthreads();
    {
        // 64 rows x 4 segs of 64 pos; each thread copies 64 shorts = 8 uint4
        const int row = tid >> 2, seg = tid & 3;
        const uint4* src = (const uint4*)&smem[row * 264 + seg * 64];
        uint4* d4 = (uint4*)((ushort*)out + (size_t)(n * 64 + row) * 65536
                             + oh * 256 + seg * 64);
        uint4 a0 = src[0], a1 = src[1], a2 = src[2], a3 = src[3];
        uint4 a4 = src[4], a5 = src[5], a6 = src[6], a7 = src[7];
        d4[0] = a0; d4[1] = a1; d4[2] = a2; d4[3] = a3;
        d4[4] = a4; d4[5] = a5; d4[6] = a6; d4[7] = a7;
    }

    if (tid < 128) {
        const int oc = tid >> 1, comp = tid & 1;
        float v = 0.f;
#pragma unroll
        for (int ww = 0; ww < 4; ww++)
            v += comp ? sredQ[ww][oc] : sredS[ww][oc];
        partial[bx * 128 + tid] = v;
    }
}

// ======================= K2: BN finalize ===================================
__global__ __launch_bounds__(256) void k_bnstats(const float* __restrict__ partial,
                                                 int nblk,
                                                 const float* __restrict__ gamma,
                                                 const float* __restrict__ beta,
                                                 float* __restrict__ stats,
                                                 float inv_n) {
    const int c = blockIdx.x;
    const int tid = threadIdx.x;
    float s = 0.f, ss = 0.f;
    for (int b = tid; b < nblk; b += 256) {
        s  += partial[b * 128 + c * 2 + 0];
        ss += partial[b * 128 + c * 2 + 1];
    }
    __shared__ float sh[8], sh2[8];
#pragma unroll
    for (int off = 32; off; off >>= 1) {
        s += __shfl_xor(s, off, 64);
        ss += __shfl_xor(ss, off, 64);
    }
    if ((tid & 63) == 0) { sh[tid >> 6] = s; sh2[tid >> 6] = ss; }
    __syncthreads();
    if (tid == 0) {
        s = sh[0] + sh[1] + sh[2] + sh[3];
        ss = sh2[0] + sh2[1] + sh2[2] + sh2[3];
        float mn = s * inv_n;
        float var = ss * inv_n - mn * mn;
        float a = gamma[c] * rsqrtf(var + 1e-5f);
        stats[c] = a;
        stats[64 + c] = beta[c] - mn * a;
    }
}

__global__ __launch_bounds__(256) void k_bn1stats(const float* __restrict__ c1,
                                                  const float* __restrict__ gamma,
                                                  const float* __restrict__ beta,
                                                  float* __restrict__ stats1) {
    const int c = blockIdx.x;
    const int tid = threadIdx.x;
    float s = 0.f, ss = 0.f;
    for (int e = tid; e < 7056; e += 256) {
        int n = e / 441, p = e - n * 441;
        float v = c1[(n * 64 + c) * 441 + p];
        s += v; ss += v * v;
    }
    __shared__ float sh[8], sh2[8];
#pragma unroll
    for (int off = 32; off; off >>= 1) {
        s += __shfl_xor(s, off, 64);
        ss += __shfl_xor(ss, off, 64);
    }
    if ((tid & 63) == 0) { sh[tid >> 6] = s; sh2[tid >> 6] = ss; }
    __syncthreads();
    if (tid == 0) {
        s = sh[0] + sh[1] + sh[2] + sh[3];
        ss = sh2[0] + sh2[1] + sh2[2] + sh2[3];
        const float inv_n = 1.f / 7056.f;
        float mn = s * inv_n;
        float var = ss * inv_n - mn * mn;
        float a = gamma[c] * rsqrtf(var + 1e-5f);
        stats1[c] = a;
        stats1[64 + c] = beta[c] - mn * a;
    }
}

// ===== K3: BN apply + relu + maxpool 3x3/s2/p1 — 8 outputs per thread ======
// grid 8192; idx = n(4b)|c(6b)|ph(7b)|pwg(4b); pw0 = pwg*8.
__global__ __launch_bounds__(256) void k_bnpool(const __hip_bfloat16* __restrict__ sin_,
                                                const float* __restrict__ stats,
                                                float* __restrict__ f) {
    const int idx = blockIdx.x * 256 + threadIdx.x;
    const int pwg = idx & 15;
    const int ph = (idx >> 4) & 127;
    const int c = (idx >> 11) & 63;
    const int n = idx >> 17;
    const int pw0 = pwg * 8;
    const float a = stats[c], b = stats[64 + c];
    const uint* base = (const uint*)((const ushort*)sin_ + (size_t)(n * 64 + c) * 65536);

    float colmax[17];
#pragma unroll
    for (int k = 0; k < 17; k++) colmax[k] = -1e30f;

    const int r0 = ph * 2 - 1;
#pragma unroll
    for (int dr = 0; dr < 3; dr++) {
        const int r = r0 + dr;
        const bool rv = (unsigned)r < 256u;
        uint d[9];
        const uint* rp = base + r * 128 + pw0 - 1;
#pragma unroll
        for (int j = 0; j < 9; j++)
            d[j] = (rv && (pw0 > 0 || j > 0)) ? rp[j] : 0u;
#pragma unroll
        for (int j = 0; j < 9; j++) {
            float vhi = a * bfbits2f((ushort)(d[j] >> 16)) + b;
            colmax[2 * j] = rv ? fmaxf(colmax[2 * j], vhi) : colmax[2 * j];
            if (j > 0) {
                float vlo = a * bfbits2f((ushort)(d[j] & 0xFFFFu)) + b;
                colmax[2 * j - 1] = rv ? fmaxf(colmax[2 * j - 1], vlo) : colmax[2 * j - 1];
            }
        }
    }
    if (pw0 == 0) colmax[0] = -1e30f;   // col -1 invalid at left edge

    float o[8];
#pragma unroll
    for (int i = 0; i < 8; i++)
        o[i] = fmaxf(fmaxf(colmax[2 * i], fmaxf(colmax[2 * i + 1], colmax[2 * i + 2])), 0.f);
    float* fp = f + (size_t)(n * 64 + c) * 16384 + ph * 128 + pw0;
    *(float4*)fp       = (float4){o[0], o[1], o[2], o[3]};
    *(float4*)(fp + 4) = (float4){o[4], o[5], o[6], o[7]};
}

// ============== K4: grid_sample, both rotations in one pass ================
__device__ __forceinline__ float gs_gather(const float* img, float yy, float xx, float wt) {
    bool valid = (xx >= 0.f) & (xx < 128.f) & (yy >= 0.f) & (yy < 128.f);
    int xi = (int)fminf(fmaxf(xx, 0.f), 127.f);
    int yi = (int)fminf(fmaxf(yy, 0.f), 127.f);
    return valid ? img[yi * 128 + xi] * wt : 0.f;
}

__device__ __forceinline__ float gs_one(const float* img, float ix, float iy) {
    float x0 = floorf(ix), y0 = floorf(iy);
    float lx = ix - x0, ly = iy - y0;
    float wa = (1.f - lx) * (1.f - ly);
    float wb = (1.f - lx) * ly;
    float wc = lx * (1.f - ly);
    float wd = lx * ly;
    return gs_gather(img, y0,       x0,       wa)
         + gs_gather(img, y0 + 1.f, x0,       wb)
         + gs_gather(img, y0,       x0 + 1.f, wc)
         + gs_gather(img, y0 + 1.f, x0 + 1.f, wd);
}

__global__ __launch_bounds__(256) void k_gridsample2(const float* __restrict__ f,
                                                     float* __restrict__ xt1,
                                                     float* __restrict__ xt2) {
    const int t = blockIdx.x * 256 + threadIdx.x;
    const int w = t & 127;
    const int h = (t >> 7) & 127;
    const float* img = f + ((size_t)(t >> 14) << 14);
    float gx = (2 * w + 1) * (1.f / 128.f) - 1.f;
    float gy = (2 * h + 1) * (1.f / 128.f) - 1.f;
    float g0a = C5 * gx + S5 * gy,  g1a = -S5 * gx + C5 * gy;
    float g0b = C5 * gx - S5 * gy,  g1b =  S5 * gx + C5 * gy;
    xt1[t] = gs_one(img, ((g0a + 1.f) * 128.f - 1.f) * 0.5f,
                         ((g1a + 1.f) * 128.f - 1.f) * 0.5f);
    xt2[t] = gs_one(img, ((g0b + 1.f) * 128.f - 1.f) * 0.5f,
                         ((g1b + 1.f) * 128.f - 1.f) * 0.5f);
}

// ========= K5: roialign into concat h (bf16), coords once per pp ==========
// grid 1408 = n(16) * job(11) * cg(8); block 256; inner loop over 8 channels.
__global__ __launch_bounds__(256) void k_roialign(const float* __restrict__ f,
                                                  const float* __restrict__ xt1,
                                                  const float* __restrict__ xt2,
                                                  const float* __restrict__ box,
                                                  __hip_bfloat16* __restrict__ h) {
    const int bx = blockIdx.x;
    const int cg = bx & 7;
    const int job = (bx >> 3) % 11;
    const int n = bx / 88;
    int j, cbase;
    const float* src;
    if (job < 7)      { j = job;     cbase = job * 64;             src = f;   }
    else if (job < 9) { j = job - 7; cbase = 448 + (job - 7) * 64; src = xt1; }
    else              { j = job - 9; cbase = 576 + (job - 9) * 64; src = xt2; }
    const float* bp = box + n * 28 + j * 4;
    const float x1 = bp[0] * 0.25f, y1 = bp[1] * 0.25f;
    const float x2 = bp[2] * 0.25f, y2 = bp[3] * 0.25f;
    const float bw = fmaxf(x2 - x1, 1.f) * (1.f / 23.f);
    const float bh = fmaxf(y2 - y1, 1.f) * (1.f / 23.f);
    const float* imgb = src + (size_t)(n * 64 + cg * 8) * 16384;
    __hip_bfloat16* hb = h + (size_t)(n * 704 + cbase + cg * 8) * 529;

    for (int pp = threadIdx.x; pp < 529; pp += 256) {
        const int ph = pp / 23, pw = pp - ph * 23;
        int   off[4][4];
        float wt[4][4];
#pragma unroll
        for (int s = 0; s < 4; s++) {
            const int r1 = s >> 1, r2 = s & 1;
            const float yv = y1 + (ph + r1 * 0.5f + 0.25f) * bh;
            const float xv = x1 + (pw + r2 * 0.5f + 0.25f) * bw;
            const bool ok = !(yv < -1.f || yv > 128.f || xv < -1.f || xv > 128.f);
            float y = fminf(fmaxf(yv, 0.f), 127.f);
            float x = fminf(fmaxf(xv, 0.f), 127.f);
            float y0f = floorf(y), x0f = floorf(x);
            int y0 = (int)y0f, x0 = (int)x0f;
            int y1i = min(y0 + 1, 127), x1i = min(x0 + 1, 127);
            float ly = y - y0f, lx = x - x0f;
            float hy = 1.f - ly, hx = 1.f - lx;
            const float sc = ok ? 1.f : 0.f;
            off[s][0] = y0 * 128 + x0;   wt[s][0] = hy * hx * sc;
            off[s][1] = y0 * 128 + x1i;  wt[s][1] = hy * lx * sc;
            off[s][2] = y1i * 128 + x0;  wt[s][2] = ly * hx * sc;
            off[s][3] = y1i * 128 + x1i; wt[s][3] = ly * lx * sc;
        }
#pragma unroll
        for (int cl = 0; cl < 8; cl++) {
            const float* img = imgb + (size_t)cl * 16384;
            float sum = 0.f;
#pragma unroll
            for (int s = 0; s < 4; s++)
                sum += img[off[s][0]] * wt[s][0] + img[off[s][1]] * wt[s][1]
                     + img[off[s][2]] * wt[s][2] + img[off[s][3]] * wt[s][3];
            hb[(size_t)cl * 529 + pp] = __float2bfloat16(sum * 0.25f);
        }
    }
}

// =================== K6: conv1 MFMA bf16, split-K=3 ========================
__global__ __launch_bounds__(256) void k_conv1m(const ushort* __restrict__ hb,
                                                const ushort* __restrict__ w1b,
                                                float* __restrict__ c1p) {
    __shared__ __align__(16) ushort Bs[2][32][40];   // [panel][pos][kk], stride 40
    const int bx = blockIdx.x;
    const int pt = bx % 17;
    const int n  = (bx / 17) & 15;
    const int s  = bx / 272;
    const int tid = threadIdx.x;
    const int w = tid >> 6, lane = tid & 63;
    const int quad = lane >> 4, m = lane & 15;
    const int kbase = s * 2112;
    const int posb = pt * 32;
    const size_t hb_n = (size_t)n * 704 * 529;
    f32x4 acc0 = {0.f, 0.f, 0.f, 0.f};
    f32x4 acc1 = {0.f, 0.f, 0.f, 0.f};
    const ushort* wrow = w1b + (size_t)(w * 16 + m) * 6336;

    for (int it = 0; it < 33; it++) {
        const int k0 = kbase + it * 64;
        __syncthreads();
        for (int e = tid; e < 2048; e += 256) {
            int panel = e >> 10, kk = (e >> 5) & 31, pos = e & 31;
            int k = k0 + panel * 32 + kk;
            int ci = k / 9, tap = k - ci * 9;
            int kh = tap / 3, kw = tap - kh * 3;
            Bs[panel][pos][kk] =
                hb[hb_n + (size_t)ci * 529 + kh * 23 + kw + posb + pos];
        }
        __syncthreads();
        const short8 a0  = *(const short8*)(wrow + k0 + quad * 8);
        const short8 a1  = *(const short8*)(wrow + k0 + 32 + quad * 8);
        const short8 b00 = *(const short8*)&Bs[0][m][quad * 8];
        const short8 b01 = *(const short8*)&Bs[0][16 + m][quad * 8];
        const short8 b10 = *(const short8*)&Bs[1][m][quad * 8];
        const short8 b11 = *(const short8*)&Bs[1][16 + m][quad * 8];
        acc0 = __builtin_amdgcn_mfma_f32_16x16x32_bf16(a0, b00, acc0, 0, 0, 0);
        acc1 = __builtin_amdgcn_mfma_f32_16x16x32_bf16(a0, b01, acc1, 0, 0, 0);
        acc0 = __builtin_amdgcn_mfma_f32_16x16x32_bf16(a1, b10, acc0, 0, 0, 0);
        acc1 = __builtin_amdgcn_mfma_f32_16x16x32_bf16(a1, b11, acc1, 0, 0, 0);
    }
    float* outp = c1p + ((size_t)(s * 16 + n) * 64) * 544;
#pragma unroll
    for (int r = 0; r < 4; r++) {
        const int oc = w * 16 + quad * 4 + r;
        outp[(size_t)oc * 544 + posb + m]      = acc0[r];
        outp[(size_t)oc * 544 + posb + 16 + m] = acc1[r];
    }
}

// =================== K6b: split-K reduce + bias ============================
__global__ __launch_bounds__(256) void k_c1red(const float* __restrict__ c1p,
                                               const float* __restrict__ b1,
                                               float* __restrict__ c1) {
    const int t = blockIdx.x * 256 + threadIdx.x;   // 451584 exact
    const int p = t % 441;
    const int oc = (t / 441) % 64;
    const int n = t / 28224;
    const int ph = p / 21, pw = p - ph * 21;
    const int p529 = ph * 23 + pw;
    const size_t base = ((size_t)n * 64 + oc) * 544 + p529;
    const size_t sstr = (size_t)16 * 64 * 544;
    c1[t] = c1p[base] + c1p[base + sstr] + c1p[base + 2 * sstr] + b1[oc];
}

// ================ K8: BN1 apply + relu + maxpool 2x2/s2 ====================
__global__ __launch_bounds__(256) void k_bnpool2(const float* __restrict__ c1,
                                                 const float* __restrict__ stats1,
                                                 float* __restrict__ p1) {
    const int t = blockIdx.x * 256 + threadIdx.x;   // 102400 exact
    const int pw = t % 10;
    const int ph = (t / 10) % 10;
    const int c = (t / 100) % 64;
    const int n = t / 6400;
    const float a = stats1[c], b = stats1[64 + c];
    const float* base = c1 + (size_t)(n * 64 + c) * 441;
    const int r = ph * 2, cc = pw * 2;
    float v0 = a * base[r * 21 + cc] + b;
    float v1 = a * base[r * 21 + cc + 1] + b;
    float v2 = a * base[(r + 1) * 21 + cc] + b;
    float v3 = a * base[(r + 1) * 21 + cc + 1] + b;
    p1[t] = fmaxf(fmaxf(fmaxf(v0, v1), fmaxf(v2, v3)), 0.f);
}

// ========== K9: conv2 3x3 (64->32) + bias + relu, LDS-staged ===============
// grid 128 = n(16) x ocq(8); block 256 = 4 oc x 64 pos.
__global__ __launch_bounds__(256) void k_conv2(const float* __restrict__ p1,
                                               const float* __restrict__ w2,
                                               const float* __restrict__ b2,
                                               float* __restrict__ c2) {
    __shared__ float ip[6400];      // 64 ci x 100
    __shared__ float wl[2304];      // 4 oc x 576
    const int bx = blockIdx.x;
    const int n = bx >> 3, ocq = bx & 7;
    const int tid = threadIdx.x;
    const float4* p14 = (const float4*)(p1 + (size_t)n * 6400);
    float4* ip4 = (float4*)ip;
    for (int e = tid; e < 1600; e += 256) ip4[e] = p14[e];
    for (int e = tid; e < 2304; e += 256) wl[e] = w2[ocq * 2304 + e];
    __syncthreads();

    const int ocl = tid >> 6, pos = tid & 63;
    const int ph = pos >> 3, pw = pos & 7;
    const int oc = ocq * 4 + ocl;
    float s = b2[oc];
    const float* wb = wl + ocl * 576;
    const float* ib = ip + ph * 10 + pw;
    for (int ci = 0; ci < 64; ci++) {
        const float* r = ib + ci * 100;
        const float* ww = wb + ci * 9;
        s += r[0] * ww[0] + r[1] * ww[1] + r[2] * ww[2]
           + r[10] * ww[3] + r[11] * ww[4] + r[12] * ww[5]
           + r[20] * ww[6] + r[21] * ww[7] + r[22] * ww[8];
    }
    c2[(size_t)(n * 32 + oc) * 64 + pos] = fmaxf(s, 0.f);
}

// ======================= K10: fc1 + relu ===================================
__global__ __launch_bounds__(64) void k_fc1(const float* __restrict__ c2,
                                            const float* __restrict__ fw,
                                            const float* __restrict__ fb,
                                            float* __restrict__ fo) {
    const int bx = blockIdx.x;
    const int oc = bx & 127, n = bx >> 7;
    const int lane = threadIdx.x;
    const float* a = c2 + (size_t)n * 2048;
    const float* w = fw + (size_t)oc * 2048;
    float s = 0.f;
    for (int k = lane; k < 2048; k += 64) s += a[k] * w[k];
#pragma unroll
    for (int off = 32; off; off >>= 1) s += __shfl_xor(s, off, 64);
    if (lane == 0) fo[n * 128 + oc] = fmaxf(s + fb[oc], 0.f);
}

// ======================= K11: head + tanh ==================================
__global__ __launch_bounds__(64) void k_head(const float* __restrict__ fo,
                                             const float* __restrict__ hw,
                                             const float* __restrict__ hb,
                                             float* __restrict__ out) {
    const int bx = blockIdx.x;
    const int oc = bx % 12, n = bx / 12;
    const int lane = threadIdx.x;
    float s = 0.f;
    for (int k = lane; k < 128; k += 64) s += fo[n * 128 + k] * hw[oc * 128 + k];
#pragma unroll
    for (int off = 32; off; off >>= 1) s += __shfl_xor(s, off, 64);
    if (lane == 0) out[bx] = tanhf(s + hb[oc]);
}

// ===========================================================================
extern "C" void kernel_launch(void* const* d_in, const int* in_sizes, int n_in,
                              void* d_out, int out_size, void* d_ws, size_t ws_size,
                              hipStream_t stream) {
    const float* x       = (const float*)d_in[0];
    const float* box     = (const float*)d_in[1];
    const float* stem_w  = (const float*)d_in[2];
    const float* stem_g  = (const float*)d_in[3];
    const float* stem_b  = (const float*)d_in[4];
    const float* conv1_w = (const float*)d_in[5];
    const float* conv1_b = (const float*)d_in[6];
    const float* bn1_g   = (const float*)d_in[7];
    const float* bn1_b   = (const float*)d_in[8];
    const float* conv2_w = (const float*)d_in[9];
    const float* conv2_b = (const float*)d_in[10];
    const float* fc1_w   = (const float*)d_in[11];
    const float* fc1_b   = (const float*)d_in[12];
    const float* head_w  = (const float*)d_in[13];
    const float* head_b  = (const float*)d_in[14];
    float* out = (float*)d_out;
    float* w = (float*)d_ws;

    const size_t F_SZ = 16777216;                         // 16*64*128*128
    float* f   = w;                                       // fp32
    __hip_bfloat16* stem = (__hip_bfloat16*)(w + F_SZ);   // bf16, spans 2*F_SZ floats
    float* xt1 = w + F_SZ;                                // aliases stem (dead after K3)
    float* xt2 = w + 2 * F_SZ;
    float* base3 = w + 3 * F_SZ;
    __hip_bfloat16* hbuf = (__hip_bfloat16*)base3;        // 5958656 els = 2979328+pad
    float* c1   = base3 + 2979392;                        // 451584
    float* c1p  = c1 + 451584;                            // 3*16*64*544 = 1671168
    float* p1   = c1p + 1671168;                          // 102400
    float* c2   = p1 + 102400;                            // 32768
    float* fo   = c2 + 32768;                             // 2048
    float* partial = fo + 2048;                           // 4096*128 used
    float* stats   = partial + 1048576;                   // 128
    float* stats1  = stats + 128;                         // 128
    __hip_bfloat16* w1b = (__hip_bfloat16*)(stats1 + 128); // 405504 els
    __hip_bfloat16* w2b = (__hip_bfloat16*)(stats1 + 128 + 202752); // 12288 els

    k_cvtw1<<<1584, 256, 0, stream>>>(conv1_w, w1b);
    k_cvtw2<<<48, 256, 0, stream>>>(stem_w, w2b);
    k_stem<<<4096, 256, 0, stream>>>(x, (const ushort*)w2b, stem, partial);
    k_bnstats<<<64, 256, 0, stream>>>(partial, 4096, stem_g, stem_b, stats,
                                      1.f / 1048576.f);
    k_bnpool<<<8192, 256, 0, stream>>>(stem, stats, f);
    k_gridsample2<<<65536, 256, 0, stream>>>(f, xt1, xt2);
    k_roialign<<<1408, 256, 0, stream>>>(f, xt1, xt2, box, hbuf);
    k_conv1m<<<816, 256, 0, stream>>>((const ushort*)hbuf, (const ushort*)w1b, c1p);
    k_c1red<<<1764, 256, 0, stream>>>(c1p, conv1_b, c1);
    k_bn1stats<<<64, 256, 0, stream>>>(c1, bn1_g, bn1_b, stats1);
    k_bnpool2<<<400, 256, 0, stream>>>(c1, stats1, p1);
    k_conv2<<<128, 256, 0, stream>>>(p1, conv2_w, conv2_b, c2);
    k_fc1<<<2048, 64, 0, stream>>>(c2, fc1_w, fc1_b, fo);
    k_head<<<192, 64, 0, stream>>>(fo, head_w, head_b, out);
}

// Round 9
// 600.591 us; speedup vs baseline: 2.7231x; 1.0784x over previous
//
#include <hip/hip_runtime.h>
#include <hip/hip_bf16.h>

// ---------------------------------------------------------------------------
// FocusPolicy pipeline, MI355X.
//  K0  convert conv1_w + stem_w -> bf16 (fused)       -> w1b, w2b
//  K1 stem conv 7x7/s2 MFMA bf16 + BN partials        -> stem(bf16), partials
//     (full row per block; 2-half transpose epilogue, LDS 26.4 KB, 5-6 blk/CU)
//  K2 BN finalize                                     -> stats
//  K3 BN apply + relu + maxpool3/2p1 (8 out/thread)   -> f   (16,64,128,128)
//  K4 grid_sample both rotations, banded-LDS          -> xt1, xt2
//  K5 roialign (11 jobs) -> concat (bf16)             -> h   (16,704,23,23)
//  K6 conv1 3x3 (704->64) MFMA bf16, split-K=3, dbuf  -> c1p
//  K6b reduce split-K + bias                          -> c1  (16,64,21,21)
//  K7 BN1 stats;  K8 BN+relu+maxpool2/2;  K9 conv2 (LDS);  K10 fc1;  K11 head
// ---------------------------------------------------------------------------

#define C5 0.9961946980917455f
#define S5 0.08715574274765817f

typedef __attribute__((ext_vector_type(8))) short short8;
typedef __attribute__((ext_vector_type(4))) float f32x4;

__device__ __forceinline__ ushort f2bf_bits(float v) {
    __hip_bfloat16 b = __float2bfloat16(v);
    ushort u;
    __builtin_memcpy(&u, &b, 2);
    return u;
}
__device__ __forceinline__ float bfbits2f(ushort u) {
    __hip_bfloat16 b;
    __builtin_memcpy(&b, &u, 2);
    return __bfloat162float(b);
}

// ============ K0: conv1 + stem weights -> bf16 (stem: kh*24+kw*3+ci+3) =====
__global__ __launch_bounds__(256) void k_cvt(const float* __restrict__ w1,
                                             __hip_bfloat16* __restrict__ w1b,
                                             const float* __restrict__ sw,
                                             __hip_bfloat16* __restrict__ w2b) {
    const int t = blockIdx.x * 256 + threadIdx.x;   // 405504 + 12288 = 417792
    if (t < 405504) {
        w1b[t] = __float2bfloat16(w1[t]);
    } else {
        const int e = t - 405504;
        const int oc = e / 192, k = e - oc * 192;
        const int kh = k / 24, u = k - kh * 24;
        float v = 0.f;
        if (u >= 3 && kh < 7) {
            int tt = u - 3;
            int kw = tt / 3, ci = tt - kw * 3;
            v = sw[oc * 147 + ci * 49 + kh * 7 + kw];
        }
        w2b[e] = __float2bfloat16(v);
    }
}

// =================== K1: stem conv MFMA + BN partials ======================
// grid 4096 = n(16) x oh(256); block 256 = 4 waves. Full output row per block:
// M=64 oc, N=256 positions (wave w -> pos w*64..+63), K=192.
// smem (12480 shorts = 24.96 KB) = slab 8x1560 OR half-tile 32x264.
__global__ __launch_bounds__(256, 5) void k_stem(const float* __restrict__ x,
                                                 const ushort* __restrict__ w2b,
                                                 __hip_bfloat16* __restrict__ out,
                                                 float* __restrict__ partial) {
    __shared__ __align__(16) ushort smem[12480];
    __shared__ float sredS[4][64], sredQ[4][64];
    const int bx = blockIdx.x;
    const int oh = bx & 255;
    const int n  = bx >> 8;
    const int tid = threadIdx.x;
    const int w = tid >> 6, lane = tid & 63;
    const int quad = lane >> 4, m = lane & 15;

    // ---- phase A: 3120 float4 slots, two batched flights ----
    // slot e: row = e/390, col = e%390; fc = 4*col-12; valid col in [3,386]
    const float* xn = x + (size_t)n * 786432;
    {
        float4 v[7];
#pragma unroll
        for (int i = 0; i < 7; i++) {
            const int e = tid + 256 * i;
            const int row = e / 390, col = e - row * 390;
            const int ih = oh * 2 - 3 + row;
            float4 t = {0.f, 0.f, 0.f, 0.f};
            if (col >= 3 && col <= 386 && (unsigned)ih < 512u)
                t = *(const float4*)(xn + (size_t)ih * 1536 + 4 * col - 12);
            v[i] = t;
        }
#pragma unroll
        for (int i = 0; i < 7; i++) {
            const int e = tid + 256 * i;
            const int row = e / 390, col = e - row * 390;
            uint2 p;
            p.x = (uint)f2bf_bits(v[i].x) | ((uint)f2bf_bits(v[i].y) << 16);
            p.y = (uint)f2bf_bits(v[i].z) | ((uint)f2bf_bits(v[i].w) << 16);
            *(uint2*)((uint*)smem + row * 780 + 2 * col) = p;
        }
    }
    {
        float4 v[6];
#pragma unroll
        for (int i = 0; i < 6; i++) {
            const int e = tid + 1792 + 256 * i;
            const int row = e / 390, col = e - row * 390;
            const int ih = oh * 2 - 3 + row;
            float4 t = {0.f, 0.f, 0.f, 0.f};
            if (e < 3120 && col >= 3 && col <= 386 && (unsigned)ih < 512u)
                t = *(const float4*)(xn + (size_t)ih * 1536 + 4 * col - 12);
            v[i] = t;
        }
#pragma unroll
        for (int i = 0; i < 6; i++) {
            const int e = tid + 1792 + 256 * i;
            if (e < 3120) {
                const int row = e / 390, col = e - row * 390;
                uint2 p;
                p.x = (uint)f2bf_bits(v[i].x) | ((uint)f2bf_bits(v[i].y) << 16);
                p.y = (uint)f2bf_bits(v[i].z) | ((uint)f2bf_bits(v[i].w) << 16);
                *(uint2*)((uint*)smem + row * 780 + 2 * col) = p;
            }
        }
    }
    __syncthreads();

    // ---- K-loop: B-frags straight from slab (sliding-window im2col) ----
    f32x4 acc[4][4] = {};
#pragma unroll
    for (int ks = 0; ks < 6; ks++) {
        const int g  = ks * 4 + quad;
        const int kh = g / 3;
        const int gi = g - kh * 3;
        const uint* rr = (const uint*)smem + kh * 780 + 4 * gi;
        short8 b[4];
#pragma unroll
        for (int nt = 0; nt < 4; nt++) {
            const uint* q = rr + 3 * (w * 64 + nt * 16 + m);
            uint4 t = (uint4){q[0], q[1], q[2], q[3]};
            __builtin_memcpy(&b[nt], &t, 16);
        }
        const int ko = ks * 32 + quad * 8;
#pragma unroll
        for (int mt = 0; mt < 4; mt++) {
            const short8 a = *(const short8*)(w2b + (size_t)(mt * 16 + m) * 192 + ko);
#pragma unroll
            for (int nt = 0; nt < 4; nt++)
                acc[mt][nt] = __builtin_amdgcn_mfma_f32_16x16x32_bf16(a, b[nt], acc[mt][nt], 0, 0, 0);
        }
    }

    // ---- BN partial sums ----
#pragma unroll
    for (int mt = 0; mt < 4; mt++) {
#pragma unroll
        for (int r = 0; r < 4; r++) {
            float s = acc[mt][0][r] + acc[mt][1][r] + acc[mt][2][r] + acc[mt][3][r];
            float q = acc[mt][0][r] * acc[mt][0][r] + acc[mt][1][r] * acc[mt][1][r]
                    + acc[mt][2][r] * acc[mt][2][r] + acc[mt][3][r] * acc[mt][3][r];
#pragma unroll
            for (int off = 1; off < 16; off <<= 1) {
                s += __shfl_xor(s, off, 64);
                q += __shfl_xor(q, off, 64);
            }
            if (m == 0) {
                const int ocl = mt * 16 + quad * 4 + r;
                sredS[w][ocl] = s;
                sredQ[w][ocl] = q;
            }
        }
    }
    __syncthreads();                     // slab dead; sred visible

    // ---- 2-half transpose (32 oc x 264-pad pos) + coalesced stores ----
#pragma unroll
    for (int half = 0; half < 2; half++) {
#pragma unroll
        for (int mi = 0; mi < 2; mi++) {
            const int mt = 2 * half + mi;
#pragma unroll
            for (int nt = 0; nt < 4; nt++) {
                const int pos = w * 64 + nt * 16 + m;
#pragma unroll
                for (int r = 0; r < 4; r++) {
                    const int ocl = mi * 16 + quad * 4 + r;
                    smem[ocl * 264 + pos] = f2bf_bits(acc[mt][nt][r]);
                }
            }
        }
        __syncthreads();
        {
            const int row = tid >> 3, seg = tid & 7;   // 32 rows x 8 segs x 32 pos
            const uint4* src = (const uint4*)&smem[row * 264 + seg * 32];
            uint4 a0 = src[0], a1 = src[1], a2 = src[2], a3 = src[3];
            uint4* d4 = (uint4*)((ushort*)out
                                 + (size_t)(n * 64 + half * 32 + row) * 65536
                                 + oh * 256 + seg * 32);
            d4[0] = a0; d4[1] = a1; d4[2] = a2; d4[3] = a3;
        }
        __syncthreads();
    }

    if (tid < 128) {
        const int oc = tid >> 1, comp = tid & 1;
        float v = 0.f;
#pragma unroll
        for (int ww = 0; ww < 4; ww++)
            v += comp ? sredQ[ww][oc] : sredS[ww][oc];
        partial[bx * 128 + tid] = v;
    }
}

// ======================= K2: BN finalize ===================================
__global__ __launch_bounds__(256) void k_bnstats(const float* __restrict__ partial,
                                                 int nblk,
                                                 const float* __restrict__ gamma,
                                                 const float* __restrict__ beta,
                                                 float* __restrict__ stats,
                                                 float inv_n) {
    const int c = blockIdx.x;
    const int tid = threadIdx.x;
    float s = 0.f, ss = 0.f;
    for (int b = tid; b < nblk; b += 256) {
        s  += partial[b * 128 + c * 2 + 0];
        ss += partial[b * 128 + c * 2 + 1];
    }
    __shared__ float sh[8], sh2[8];
#pragma unroll
    for (int off = 32; off; off >>= 1) {
        s += __shfl_xor(s, off, 64);
        ss += __shfl_xor(ss, off, 64);
    }
    if ((tid & 63) == 0) { sh[tid >> 6] = s; sh2[tid >> 6] = ss; }
    __syncthreads();
    if (tid == 0) {
        s = sh[0] + sh[1] + sh[2] + sh[3];
        ss = sh2[0] + sh2[1] + sh2[2] + sh2[3];
        float mn = s * inv_n;
        float var = ss * inv_n - mn * mn;
        float a = gamma[c] * rsqrtf(var + 1e-5f);
        stats[c] = a;
        stats[64 + c] = beta[c] - mn * a;
    }
}

__global__ __launch_bounds__(256) void k_bn1stats(const float* __restrict__ c1,
                                                  const float* __restrict__ gamma,
                                                  const float* __restrict__ beta,
                                                  float* __restrict__ stats1) {
    const int c = blockIdx.x;
    const int tid = threadIdx.x;
    float s = 0.f, ss = 0.f;
    for (int e = tid; e < 7056; e += 256) {
        int n = e / 441, p = e - n * 441;
        float v = c1[(n * 64 + c) * 441 + p];
        s += v; ss += v * v;
    }
    __shared__ float sh[8], sh2[8];
#pragma unroll
    for (int off = 32; off; off >>= 1) {
        s += __shfl_xor(s, off, 64);
        ss += __shfl_xor(ss, off, 64);
    }
    if ((tid & 63) == 0) { sh[tid >> 6] = s; sh2[tid >> 6] = ss; }
    __syncthreads();
    if (tid == 0) {
        s = sh[0] + sh[1] + sh[2] + sh[3];
        ss = sh2[0] + sh2[1] + sh2[2] + sh2[3];
        const float inv_n = 1.f / 7056.f;
        float mn = s * inv_n;
        float var = ss * inv_n - mn * mn;
        float a = gamma[c] * rsqrtf(var + 1e-5f);
        stats1[c] = a;
        stats1[64 + c] = beta[c] - mn * a;
    }
}

// ===== K3: BN apply + relu + maxpool 3x3/s2/p1 — 8 outputs per thread ======
__global__ __launch_bounds__(256) void k_bnpool(const __hip_bfloat16* __restrict__ sin_,
                                                const float* __restrict__ stats,
                                                float* __restrict__ f) {
    const int idx = blockIdx.x * 256 + threadIdx.x;
    const int pwg = idx & 15;
    const int ph = (idx >> 4) & 127;
    const int c = (idx >> 11) & 63;
    const int n = idx >> 17;
    const int pw0 = pwg * 8;
    const float a = stats[c], b = stats[64 + c];
    const uint* base = (const uint*)((const ushort*)sin_ + (size_t)(n * 64 + c) * 65536);

    float colmax[17];
#pragma unroll
    for (int k = 0; k < 17; k++) colmax[k] = -1e30f;

    const int r0 = ph * 2 - 1;
#pragma unroll
    for (int dr = 0; dr < 3; dr++) {
        const int r = r0 + dr;
        const bool rv = (unsigned)r < 256u;
        uint d[9];
        const uint* rp = base + r * 128 + pw0 - 1;
#pragma unroll
        for (int j = 0; j < 9; j++)
            d[j] = (rv && (pw0 > 0 || j > 0)) ? rp[j] : 0u;
#pragma unroll
        for (int j = 0; j < 9; j++) {
            float vhi = a * bfbits2f((ushort)(d[j] >> 16)) + b;
            colmax[2 * j] = rv ? fmaxf(colmax[2 * j], vhi) : colmax[2 * j];
            if (j > 0) {
                float vlo = a * bfbits2f((ushort)(d[j] & 0xFFFFu)) + b;
                colmax[2 * j - 1] = rv ? fmaxf(colmax[2 * j - 1], vlo) : colmax[2 * j - 1];
            }
        }
    }
    if (pw0 == 0) colmax[0] = -1e30f;

    float o[8];
#pragma unroll
    for (int i = 0; i < 8; i++)
        o[i] = fmaxf(fmaxf(colmax[2 * i], fmaxf(colmax[2 * i + 1], colmax[2 * i + 2])), 0.f);
    float* fp = f + (size_t)(n * 64 + c) * 16384 + ph * 128 + pw0;
    *(float4*)fp       = (float4){o[0], o[1], o[2], o[3]};
    *(float4*)(fp + 4) = (float4){o[4], o[5], o[6], o[7]};
}

// ====== K4: grid_sample, both rotations, banded-LDS (bit-identical) ========
// grid 2048 = (n*64+c)*2 + half; block 256; band <= 78 source rows in LDS.
__device__ __forceinline__ float gs_tap(const float* band, int nrows, int ry0,
                                        float yy, float xx, float wt) {
    bool valid = (xx >= 0.f) & (xx < 128.f) & (yy >= 0.f) & (yy < 128.f);
    int xi = (int)fminf(fmaxf(xx, 0.f), 127.f);
    int yi = (int)fminf(fmaxf(yy, 0.f), 127.f);
    int r = min(max(yi - ry0, 0), nrows - 1);
    return valid ? band[r * 128 + xi] * wt : 0.f;
}

__device__ __forceinline__ float gs_band(const float* band, int nrows, int ry0,
                                         float ix, float iy) {
    float x0 = floorf(ix), y0 = floorf(iy);
    float lx = ix - x0, ly = iy - y0;
    float wa = (1.f - lx) * (1.f - ly);
    float wb = (1.f - lx) * ly;
    float wc = lx * (1.f - ly);
    float wd = lx * ly;
    return gs_tap(band, nrows, ry0, y0,       x0,       wa)
         + gs_tap(band, nrows, ry0, y0 + 1.f, x0,       wb)
         + gs_tap(band, nrows, ry0, y0,       x0 + 1.f, wc)
         + gs_tap(band, nrows, ry0, y0 + 1.f, x0 + 1.f, wd);
}

__global__ __launch_bounds__(256, 4) void k_gridsample2(const float* __restrict__ f,
                                                        float* __restrict__ xt1,
                                                        float* __restrict__ xt2) {
    __shared__ float band[78 * 128];
    const int bx = blockIdx.x;
    const int half = bx & 1;
    const int img_i = bx >> 1;          // n*64+c
    const int h0 = half * 64;
    // band rows: iy = 64*g1 + 63.5, g1 in [C5*gy0 - S5*gxm, C5*gy1 + S5*gxm]
    const float gy0 = (2.f * h0 + 1.f) * (1.f / 128.f) - 1.f;
    const float gy1 = (2.f * (h0 + 63) + 1.f) * (1.f / 128.f) - 1.f;
    const float gxm = 255.f * (1.f / 128.f) - 1.f;   // 0.9922
    const float iymin = 64.f * (C5 * gy0 - S5 * gxm) + 63.5f;
    const float iymax = 64.f * (C5 * gy1 + S5 * gxm) + 63.5f;
    const int ry0 = max(0, (int)floorf(iymin) - 1);
    const int ry1 = min(127, (int)floorf(iymax) + 2);
    const int nrows = ry1 - ry0 + 1;                 // <= 78
    const float* img = f + (size_t)img_i * 16384;
    const int tid = threadIdx.x;
    const float4* src4 = (const float4*)(img + ry0 * 128);
    for (int e = tid; e < nrows * 32; e += 256)
        ((float4*)band)[e] = src4[e];
    __syncthreads();

    float* o1 = xt1 + (size_t)img_i * 16384 + h0 * 128;
    float* o2 = xt2 + (size_t)img_i * 16384 + h0 * 128;
    for (int e = tid; e < 8192; e += 256) {
        const int h = h0 + (e >> 7);
        const int w = e & 127;
        float gx = (2 * w + 1) * (1.f / 128.f) - 1.f;
        float gy = (2 * h + 1) * (1.f / 128.f) - 1.f;
        float g0a = C5 * gx + S5 * gy,  g1a = -S5 * gx + C5 * gy;
        float g0b = C5 * gx - S5 * gy,  g1b =  S5 * gx + C5 * gy;
        o1[e] = gs_band(band, nrows, ry0, ((g0a + 1.f) * 128.f - 1.f) * 0.5f,
                                          ((g1a + 1.f) * 128.f - 1.f) * 0.5f);
        o2[e] = gs_band(band, nrows, ry0, ((g0b + 1.f) * 128.f - 1.f) * 0.5f,
                                          ((g1b + 1.f) * 128.f - 1.f) * 0.5f);
    }
}

// ========= K5: roialign into concat h (bf16), coords once per pp ==========
__global__ __launch_bounds__(256) void k_roialign(const float* __restrict__ f,
                                                  const float* __restrict__ xt1,
                                                  const float* __restrict__ xt2,
                                                  const float* __restrict__ box,
                                                  __hip_bfloat16* __restrict__ h) {
    const int bx = blockIdx.x;
    const int cg = bx & 7;
    const int job = (bx >> 3) % 11;
    const int n = bx / 88;
    int j, cbase;
    const float* src;
    if (job < 7)      { j = job;     cbase = job * 64;             src = f;   }
    else if (job < 9) { j = job - 7; cbase = 448 + (job - 7) * 64; src = xt1; }
    else              { j = job - 9; cbase = 576 + (job - 9) * 64; src = xt2; }
    const float* bp = box + n * 28 + j * 4;
    const float x1 = bp[0] * 0.25f, y1 = bp[1] * 0.25f;
    const float x2 = bp[2] * 0.25f, y2 = bp[3] * 0.25f;
    const float bw = fmaxf(x2 - x1, 1.f) * (1.f / 23.f);
    const float bh = fmaxf(y2 - y1, 1.f) * (1.f / 23.f);
    const float* imgb = src + (size_t)(n * 64 + cg * 8) * 16384;
    __hip_bfloat16* hb = h + (size_t)(n * 704 + cbase + cg * 8) * 529;

    for (int pp = threadIdx.x; pp < 529; pp += 256) {
        const int ph = pp / 23, pw = pp - ph * 23;
        int   off[4][4];
        float wt[4][4];
#pragma unroll
        for (int s = 0; s < 4; s++) {
            const int r1 = s >> 1, r2 = s & 1;
            const float yv = y1 + (ph + r1 * 0.5f + 0.25f) * bh;
            const float xv = x1 + (pw + r2 * 0.5f + 0.25f) * bw;
            const bool ok = !(yv < -1.f || yv > 128.f || xv < -1.f || xv > 128.f);
            float y = fminf(fmaxf(yv, 0.f), 127.f);
            float x = fminf(fmaxf(xv, 0.f), 127.f);
            float y0f = floorf(y), x0f = floorf(x);
            int y0 = (int)y0f, x0 = (int)x0f;
            int y1i = min(y0 + 1, 127), x1i = min(x0 + 1, 127);
            float ly = y - y0f, lx = x - x0f;
            float hy = 1.f - ly, hx = 1.f - lx;
            const float sc = ok ? 1.f : 0.f;
            off[s][0] = y0 * 128 + x0;   wt[s][0] = hy * hx * sc;
            off[s][1] = y0 * 128 + x1i;  wt[s][1] = hy * lx * sc;
            off[s][2] = y1i * 128 + x0;  wt[s][2] = ly * hx * sc;
            off[s][3] = y1i * 128 + x1i; wt[s][3] = ly * lx * sc;
        }
#pragma unroll
        for (int cl = 0; cl < 8; cl++) {
            const float* img = imgb + (size_t)cl * 16384;
            float sum = 0.f;
#pragma unroll
            for (int s = 0; s < 4; s++)
                sum += img[off[s][0]] * wt[s][0] + img[off[s][1]] * wt[s][1]
                     + img[off[s][2]] * wt[s][2] + img[off[s][3]] * wt[s][3];
            hb[(size_t)cl * 529 + pp] = __float2bfloat16(sum * 0.25f);
        }
    }
}

// ========= K6: conv1 MFMA bf16, split-K=3, double-buffered staging =========
__global__ __launch_bounds__(256) void k_conv1m(const ushort* __restrict__ hb,
                                                const ushort* __restrict__ w1b,
                                                float* __restrict__ c1p) {
    __shared__ __align__(16) ushort Bs[2][2][32][40];  // [buf][panel][pos][kk]
    const int bx = blockIdx.x;
    const int pt = bx % 17;
    const int n  = (bx / 17) & 15;
    const int s  = bx / 272;
    const int tid = threadIdx.x;
    const int w = tid >> 6, lane = tid & 63;
    const int quad = lane >> 4, m = lane & 15;
    const int kbase = s * 2112;
    const int posb = pt * 32;
    const size_t hb_n = (size_t)n * 704 * 529;
    f32x4 acc0 = {0.f, 0.f, 0.f, 0.f};
    f32x4 acc1 = {0.f, 0.f, 0.f, 0.f};
    const ushort* wrow = w1b + (size_t)(w * 16 + m) * 6336;

    int ep[8], ek[8], epos[8];
#pragma unroll
    for (int i = 0; i < 8; i++) {
        const int e = tid + 256 * i;
        ep[i] = e >> 10; ek[i] = (e >> 5) & 31; epos[i] = e & 31;
    }
    ushort rbuf[8];
#pragma unroll
    for (int i = 0; i < 8; i++) {          // preload it=0
        const int k = kbase + ep[i] * 32 + ek[i];
        const int ci = k / 9, tap = k - ci * 9;
        const int kh = tap / 3, kw = tap - kh * 3;
        rbuf[i] = hb[hb_n + (size_t)ci * 529 + kh * 23 + kw + posb + epos[i]];
    }
#pragma unroll
    for (int i = 0; i < 8; i++) Bs[0][ep[i]][epos[i]][ek[i]] = rbuf[i];

    for (int it = 0; it < 33; it++) {
        __syncthreads();                    // Bs[it&1] ready
        const int cur = it & 1;
        if (it < 32) {
            const int k0 = kbase + (it + 1) * 64;
#pragma unroll
            for (int i = 0; i < 8; i++) {
                const int k = k0 + ep[i] * 32 + ek[i];
                const int ci = k / 9, tap = k - ci * 9;
                const int kh = tap / 3, kw = tap - kh * 3;
                rbuf[i] = hb[hb_n + (size_t)ci * 529 + kh * 23 + kw + posb + epos[i]];
            }
        }
        const int k0 = kbase + it * 64;
        const short8 a0  = *(const short8*)(wrow + k0 + quad * 8);
        const short8 a1  = *(const short8*)(wrow + k0 + 32 + quad * 8);
        const short8 b00 = *(const short8*)&Bs[cur][0][m][quad * 8];
        const short8 b01 = *(const short8*)&Bs[cur][0][16 + m][quad * 8];
        const short8 b10 = *(const short8*)&Bs[cur][1][m][quad * 8];
        const short8 b11 = *(const short8*)&Bs[cur][1][16 + m][quad * 8];
        acc0 = __builtin_amdgcn_mfma_f32_16x16x32_bf16(a0, b00, acc0, 0, 0, 0);
        acc1 = __builtin_amdgcn_mfma_f32_16x16x32_bf16(a0, b01, acc1, 0, 0, 0);
        acc0 = __builtin_amdgcn_mfma_f32_16x16x32_bf16(a1, b10, acc0, 0, 0, 0);
        acc1 = __builtin_amdgcn_mfma_f32_16x16x32_bf16(a1, b11, acc1, 0, 0, 0);
        if (it < 32) {
#pragma unroll
            for (int i = 0; i < 8; i++) Bs[cur ^ 1][ep[i]][epos[i]][ek[i]] = rbuf[i];
        }
    }
    float* outp = c1p + ((size_t)(s * 16 + n) * 64) * 544;
#pragma unroll
    for (int r = 0; r < 4; r++) {
        const int oc = w * 16 + quad * 4 + r;
        outp[(size_t)oc * 544 + posb + m]      = acc0[r];
        outp[(size_t)oc * 544 + posb + 16 + m] = acc1[r];
    }
}

// =================== K6b: split-K reduce + bias ============================
__global__ __launch_bounds__(256) void k_c1red(const float* __restrict__ c1p,
                                               const float* __restrict__ b1,
                                               float* __restrict__ c1) {
    const int t = blockIdx.x * 256 + threadIdx.x;   // 451584 exact
    const int p = t % 441;
    const int oc = (t / 441) % 64;
    const int n = t / 28224;
    const int ph = p / 21, pw = p - ph * 21;
    const int p529 = ph * 23 + pw;
    const size_t base = ((size_t)n * 64 + oc) * 544 + p529;
    const size_t sstr = (size_t)16 * 64 * 544;
    c1[t] = c1p[base] + c1p[base + sstr] + c1p[base + 2 * sstr] + b1[oc];
}

// ================ K8: BN1 apply + relu + maxpool 2x2/s2 ====================
__global__ __launch_bounds__(256) void k_bnpool2(const float* __restrict__ c1,
                                                 const float* __restrict__ stats1,
                                                 float* __restrict__ p1) {
    const int t = blockIdx.x * 256 + threadIdx.x;   // 102400 exact
    const int pw = t % 10;
    const int ph = (t / 10) % 10;
    const int c = (t / 100) % 64;
    const int n = t / 6400;
    const float a = stats1[c], b = stats1[64 + c];
    const float* base = c1 + (size_t)(n * 64 + c) * 441;
    const int r = ph * 2, cc = pw * 2;
    float v0 = a * base[r * 21 + cc] + b;
    float v1 = a * base[r * 21 + cc + 1] + b;
    float v2 = a * base[(r + 1) * 21 + cc] + b;
    float v3 = a * base[(r + 1) * 21 + cc + 1] + b;
    p1[t] = fmaxf(fmaxf(fmaxf(v0, v1), fmaxf(v2, v3)), 0.f);
}

// ========== K9: conv2 3x3 (64->32) + bias + relu, LDS-staged ===============
__global__ __launch_bounds__(256) void k_conv2(const float* __restrict__ p1,
                                               const float* __restrict__ w2,
                                               const float* __restrict__ b2,
                                               float* __restrict__ c2) {
    __shared__ float ip[6400];      // 64 ci x 100
    __shared__ float wl[2304];      // 4 oc x 576
    const int bx = blockIdx.x;
    const int n = bx >> 3, ocq = bx & 7;
    const int tid = threadIdx.x;
    const float4* p14 = (const float4*)(p1 + (size_t)n * 6400);
    float4* ip4 = (float4*)ip;
    for (int e = tid; e < 1600; e += 256) ip4[e] = p14[e];
    for (int e = tid; e < 2304; e += 256) wl[e] = w2[ocq * 2304 + e];
    __syncthreads();

    const int ocl = tid >> 6, pos = tid & 63;
    const int ph = pos >> 3, pw = pos & 7;
    const int oc = ocq * 4 + ocl;
    float s = b2[oc];
    const float* wb = wl + ocl * 576;
    const float* ib = ip + ph * 10 + pw;
    for (int ci = 0; ci < 64; ci++) {
        const float* r = ib + ci * 100;
        const float* ww = wb + ci * 9;
        s += r[0] * ww[0] + r[1] * ww[1] + r[2] * ww[2]
           + r[10] * ww[3] + r[11] * ww[4] + r[12] * ww[5]
           + r[20] * ww[6] + r[21] * ww[7] + r[22] * ww[8];
    }
    c2[(size_t)(n * 32 + oc) * 64 + pos] = fmaxf(s, 0.f);
}

// ======================= K10: fc1 + relu ===================================
__global__ __launch_bounds__(64) void k_fc1(const float* __restrict__ c2,
                                            const float* __restrict__ fw,
                                            const float* __restrict__ fb,
                                            float* __restrict__ fo) {
    const int bx = blockIdx.x;
    const int oc = bx & 127, n = bx >> 7;
    const int lane = threadIdx.x;
    const float* a = c2 + (size_t)n * 2048;
    const float* w = fw + (size_t)oc * 2048;
    float s = 0.f;
    for (int k = lane; k < 2048; k += 64) s += a[k] * w[k];
#pragma unroll
    for (int off = 32; off; off >>= 1) s += __shfl_xor(s, off, 64);
    if (lane == 0) fo[n * 128 + oc] = fmaxf(s + fb[oc], 0.f);
}

// ======================= K11: head + tanh ==================================
__global__ __launch_bounds__(64) void k_head(const float* __restrict__ fo,
                                             const float* __restrict__ hw,
                                             const float* __restrict__ hb,
                                             float* __restrict__ out) {
    const int bx = blockIdx.x;
    const int oc = bx % 12, n = bx / 12;
    const int lane = threadIdx.x;
    float s = 0.f;
    for (int k = lane; k < 128; k += 64) s += fo[n * 128 + k] * hw[oc * 128 + k];
#pragma unroll
    for (int off = 32; off; off >>= 1) s += __shfl_xor(s, off, 64);
    if (lane == 0) out[bx] = tanhf(s + hb[oc]);
}

// ===========================================================================
extern "C" void kernel_launch(void* const* d_in, const int* in_sizes, int n_in,
                              void* d_out, int out_size, void* d_ws, size_t ws_size,
                              hipStream_t stream) {
    const float* x       = (const float*)d_in[0];
    const float* box     = (const float*)d_in[1];
    const float* stem_w  = (const float*)d_in[2];
    const float* stem_g  = (const float*)d_in[3];
    const float* stem_b  = (const float*)d_in[4];
    const float* conv1_w = (const float*)d_in[5];
    const float* conv1_b = (const float*)d_in[6];
    const float* bn1_g   = (const float*)d_in[7];
    const float* bn1_b   = (const float*)d_in[8];
    const float* conv2_w = (const float*)d_in[9];
    const float* conv2_b = (const float*)d_in[10];
    const float* fc1_w   = (const float*)d_in[11];
    const float* fc1_b   = (const float*)d_in[12];
    const float* head_w  = (const float*)d_in[13];
    const float* head_b  = (const float*)d_in[14];
    float* out = (float*)d_out;
    float* w = (float*)d_ws;

    const size_t F_SZ = 16777216;                         // 16*64*128*128
    float* f   = w;                                       // fp32
    __hip_bfloat16* stem = (__hip_bfloat16*)(w + F_SZ);   // bf16, spans 2*F_SZ floats
    float* xt1 = w + F_SZ;                                // aliases stem (dead after K3)
    float* xt2 = w + 2 * F_SZ;
    float* base3 = w + 3 * F_SZ;
    __hip_bfloat16* hbuf = (__hip_bfloat16*)base3;        // 5958656 els = 2979328+pad
    float* c1   = base3 + 2979392;                        // 451584
    float* c1p  = c1 + 451584;                            // 3*16*64*544 = 1671168
    float* p1   = c1p + 1671168;                          // 102400
    float* c2   = p1 + 102400;                            // 32768
    float* fo   = c2 + 32768;                             // 2048
    float* partial = fo + 2048;                           // 4096*128 used
    float* stats   = partial + 1048576;                   // 128
    float* stats1  = stats + 128;                         // 128
    __hip_bfloat16* w1b = (__hip_bfloat16*)(stats1 + 128); // 405504 els
    __hip_bfloat16* w2b = (__hip_bfloat16*)(stats1 + 128 + 202752); // 12288 els

    k_cvt<<<1632, 256, 0, stream>>>(conv1_w, w1b, stem_w, w2b);
    k_stem<<<4096, 256, 0, stream>>>(x, (const ushort*)w2b, stem, partial);
    k_bnstats<<<64, 256, 0, stream>>>(partial, 4096, stem_g, stem_b, stats,
                                      1.f / 1048576.f);
    k_bnpool<<<8192, 256, 0, stream>>>(stem, stats, f);
    k_gridsample2<<<2048, 256, 0, stream>>>(f, xt1, xt2);
    k_roialign<<<1408, 256, 0, stream>>>(f, xt1, xt2, box, hbuf);
    k_conv1m<<<816, 256, 0, stream>>>((const ushort*)hbuf, (const ushort*)w1b, c1p);
    k_c1red<<<1764, 256, 0, stream>>>(c1p, conv1_b, c1);
    k_bn1stats<<<64, 256, 0, stream>>>(c1, bn1_g, bn1_b, stats1);
    k_bnpool2<<<400, 256, 0, stream>>>(c1, stats1, p1);
    k_conv2<<<128, 256, 0, stream>>>(p1, conv2_w, conv2_b, c2);
    k_fc1<<<2048, 64, 0, stream>>>(c2, fc1_w, fc1_b, fo);
    k_head<<<192, 64, 0, stream>>>(fo, head_w, head_b, out);
}

// Round 10
// 528.435 us; speedup vs baseline: 3.0949x; 1.1365x over previous
//
#include <hip/hip_runtime.h>
#include <hip/hip_bf16.h>

// ---------------------------------------------------------------------------
// FocusPolicy pipeline, MI355X.
//  K0  convert conv1_w + stem_w -> bf16 (fused)       -> w1b, w2b
//  K1 stem conv 7x7/s2 MFMA bf16 + BN partials        -> stem(bf16), partials
//     (full row per block; 2-half transpose, LDS 25 KB, (256,3) spill-free,
//      XCD-swizzled block order for input-row L2 locality)
//  K2 BN finalize                                     -> stats
//  K3 BN apply + relu + maxpool3/2p1 (8 out/thread)   -> f   (16,64,128,128)
//  K4 grid_sample both rotations, banded-LDS          -> xt1, xt2
//  K5 roialign (11 jobs) -> concat (bf16)             -> h   (16,704,23,23)
//  K6 conv1 3x3 (704->64) MFMA bf16, split-K=3, dbuf  -> c1p
//  K6b reduce split-K + bias                          -> c1  (16,64,21,21)
//  K7 BN1 stats;  K8 BN+relu+maxpool2/2;  K9 conv2 (LDS);  K10 fc1;  K11 head
// ---------------------------------------------------------------------------

#define C5 0.9961946980917455f
#define S5 0.08715574274765817f

typedef __attribute__((ext_vector_type(8))) short short8;
typedef __attribute__((ext_vector_type(4))) float f32x4;

__device__ __forceinline__ ushort f2bf_bits(float v) {
    __hip_bfloat16 b = __float2bfloat16(v);
    ushort u;
    __builtin_memcpy(&u, &b, 2);
    return u;
}
__device__ __forceinline__ float bfbits2f(ushort u) {
    __hip_bfloat16 b;
    __builtin_memcpy(&b, &u, 2);
    return __bfloat162float(b);
}

// ============ K0: conv1 + stem weights -> bf16 (stem: kh*24+kw*3+ci+3) =====
__global__ __launch_bounds__(256) void k_cvt(const float* __restrict__ w1,
                                             __hip_bfloat16* __restrict__ w1b,
                                             const float* __restrict__ sw,
                                             __hip_bfloat16* __restrict__ w2b) {
    const int t = blockIdx.x * 256 + threadIdx.x;   // 405504 + 12288 = 417792
    if (t < 405504) {
        w1b[t] = __float2bfloat16(w1[t]);
    } else {
        const int e = t - 405504;
        const int oc = e / 192, k = e - oc * 192;
        const int kh = k / 24, u = k - kh * 24;
        float v = 0.f;
        if (u >= 3 && kh < 7) {
            int tt = u - 3;
            int kw = tt / 3, ci = tt - kw * 3;
            v = sw[oc * 147 + ci * 49 + kh * 7 + kw];
        }
        w2b[e] = __float2bfloat16(v);
    }
}

// =================== K1: stem conv MFMA + BN partials ======================
// grid 4096; XCD swizzle: gi = (bx&7)*512 + (bx>>3); n = gi>>8, oh = gi&255.
// block 256 = 4 waves; M=64 oc, N=256 positions, K=192.
// smem (12480 shorts ~ 25 KB) = slab 8x1560 OR half-tile 32x264.
// (256,3): 72 VGPR + 64 AGPR fits — do NOT raise min-waves (r9 spill lesson).
__global__ __launch_bounds__(256, 3) void k_stem(const float* __restrict__ x,
                                                 const ushort* __restrict__ w2b,
                                                 __hip_bfloat16* __restrict__ out,
                                                 float* __restrict__ partial) {
    __shared__ __align__(16) ushort smem[12480];
    __shared__ float sredS[4][64], sredQ[4][64];
    const int bx = blockIdx.x;
    const int gi = ((bx & 7) << 9) + (bx >> 3);   // XCD-local oh contiguity
    const int oh = gi & 255;
    const int n  = gi >> 8;
    const int tid = threadIdx.x;
    const int w = tid >> 6, lane = tid & 63;
    const int quad = lane >> 4, m = lane & 15;

    // ---- phase A: 3120 float4 slots, two batched flights ----
    // slot e: row = e/390, col = e%390; fc = 4*col-12; valid col in [3,386]
    const float* xn = x + (size_t)n * 786432;
    {
        float4 v[7];
#pragma unroll
        for (int i = 0; i < 7; i++) {
            const int e = tid + 256 * i;
            const int row = e / 390, col = e - row * 390;
            const int ih = oh * 2 - 3 + row;
            float4 t = {0.f, 0.f, 0.f, 0.f};
            if (col >= 3 && col <= 386 && (unsigned)ih < 512u)
                t = *(const float4*)(xn + (size_t)ih * 1536 + 4 * col - 12);
            v[i] = t;
        }
#pragma unroll
        for (int i = 0; i < 7; i++) {
            const int e = tid + 256 * i;
            const int row = e / 390, col = e - row * 390;
            uint2 p;
            p.x = (uint)f2bf_bits(v[i].x) | ((uint)f2bf_bits(v[i].y) << 16);
            p.y = (uint)f2bf_bits(v[i].z) | ((uint)f2bf_bits(v[i].w) << 16);
            *(uint2*)((uint*)smem + row * 780 + 2 * col) = p;
        }
    }
    {
        float4 v[6];
#pragma unroll
        for (int i = 0; i < 6; i++) {
            const int e = tid + 1792 + 256 * i;
            const int row = e / 390, col = e - row * 390;
            const int ih = oh * 2 - 3 + row;
            float4 t = {0.f, 0.f, 0.f, 0.f};
            if (e < 3120 && col >= 3 && col <= 386 && (unsigned)ih < 512u)
                t = *(const float4*)(xn + (size_t)ih * 1536 + 4 * col - 12);
            v[i] = t;
        }
#pragma unroll
        for (int i = 0; i < 6; i++) {
            const int e = tid + 1792 + 256 * i;
            if (e < 3120) {
                const int row = e / 390, col = e - row * 390;
                uint2 p;
                p.x = (uint)f2bf_bits(v[i].x) | ((uint)f2bf_bits(v[i].y) << 16);
                p.y = (uint)f2bf_bits(v[i].z) | ((uint)f2bf_bits(v[i].w) << 16);
                *(uint2*)((uint*)smem + row * 780 + 2 * col) = p;
            }
        }
    }
    __syncthreads();

    // ---- K-loop: B-frags straight from slab (sliding-window im2col) ----
    f32x4 acc[4][4] = {};
#pragma unroll
    for (int ks = 0; ks < 6; ks++) {
        const int g  = ks * 4 + quad;
        const int kh = g / 3;
        const int gi2 = g - kh * 3;
        const uint* rr = (const uint*)smem + kh * 780 + 4 * gi2;
        short8 b[4];
#pragma unroll
        for (int nt = 0; nt < 4; nt++) {
            const uint* q = rr + 3 * (w * 64 + nt * 16 + m);
            uint4 t = (uint4){q[0], q[1], q[2], q[3]};
            __builtin_memcpy(&b[nt], &t, 16);
        }
        const int ko = ks * 32 + quad * 8;
#pragma unroll
        for (int mt = 0; mt < 4; mt++) {
            const short8 a = *(const short8*)(w2b + (size_t)(mt * 16 + m) * 192 + ko);
#pragma unroll
            for (int nt = 0; nt < 4; nt++)
                acc[mt][nt] = __builtin_amdgcn_mfma_f32_16x16x32_bf16(a, b[nt], acc[mt][nt], 0, 0, 0);
        }
    }

    // ---- BN partial sums ----
#pragma unroll
    for (int mt = 0; mt < 4; mt++) {
#pragma unroll
        for (int r = 0; r < 4; r++) {
            float s = acc[mt][0][r] + acc[mt][1][r] + acc[mt][2][r] + acc[mt][3][r];
            float q = acc[mt][0][r] * acc[mt][0][r] + acc[mt][1][r] * acc[mt][1][r]
                    + acc[mt][2][r] * acc[mt][2][r] + acc[mt][3][r] * acc[mt][3][r];
#pragma unroll
            for (int off = 1; off < 16; off <<= 1) {
                s += __shfl_xor(s, off, 64);
                q += __shfl_xor(q, off, 64);
            }
            if (m == 0) {
                const int ocl = mt * 16 + quad * 4 + r;
                sredS[w][ocl] = s;
                sredQ[w][ocl] = q;
            }
        }
    }
    __syncthreads();                     // slab dead; sred visible

    // ---- 2-half transpose (32 oc x 264-pad pos) + coalesced stores ----
#pragma unroll
    for (int half = 0; half < 2; half++) {
#pragma unroll
        for (int mi = 0; mi < 2; mi++) {
            const int mt = 2 * half + mi;
#pragma unroll
            for (int nt = 0; nt < 4; nt++) {
                const int pos = w * 64 + nt * 16 + m;
#pragma unroll
                for (int r = 0; r < 4; r++) {
                    const int ocl = mi * 16 + quad * 4 + r;
                    smem[ocl * 264 + pos] = f2bf_bits(acc[mt][nt][r]);
                }
            }
        }
        __syncthreads();
        {
            const int row = tid >> 3, seg = tid & 7;   // 32 rows x 8 segs x 32 pos
            const uint4* src = (const uint4*)&smem[row * 264 + seg * 32];
            uint4 a0 = src[0], a1 = src[1], a2 = src[2], a3 = src[3];
            uint4* d4 = (uint4*)((ushort*)out
                                 + (size_t)(n * 64 + half * 32 + row) * 65536
                                 + oh * 256 + seg * 32);
            d4[0] = a0; d4[1] = a1; d4[2] = a2; d4[3] = a3;
        }
        __syncthreads();
    }

    if (tid < 128) {
        const int oc = tid >> 1, comp = tid & 1;
        float v = 0.f;
#pragma unroll
        for (int ww = 0; ww < 4; ww++)
            v += comp ? sredQ[ww][oc] : sredS[ww][oc];
        partial[bx * 128 + tid] = v;
    }
}

// ======================= K2: BN finalize ===================================
__global__ __launch_bounds__(256) void k_bnstats(const float* __restrict__ partial,
                                                 int nblk,
                                                 const float* __restrict__ gamma,
                                                 const float* __restrict__ beta,
                                                 float* __restrict__ stats,
                                                 float inv_n) {
    const int c = blockIdx.x;
    const int tid = threadIdx.x;
    float s = 0.f, ss = 0.f;
    for (int b = tid; b < nblk; b += 256) {
        s  += partial[b * 128 + c * 2 + 0];
        ss += partial[b * 128 + c * 2 + 1];
    }
    __shared__ float sh[8], sh2[8];
#pragma unroll
    for (int off = 32; off; off >>= 1) {
        s += __shfl_xor(s, off, 64);
        ss += __shfl_xor(ss, off, 64);
    }
    if ((tid & 63) == 0) { sh[tid >> 6] = s; sh2[tid >> 6] = ss; }
    __syncthreads();
    if (tid == 0) {
        s = sh[0] + sh[1] + sh[2] + sh[3];
        ss = sh2[0] + sh2[1] + sh2[2] + sh2[3];
        float mn = s * inv_n;
        float var = ss * inv_n - mn * mn;
        float a = gamma[c] * rsqrtf(var + 1e-5f);
        stats[c] = a;
        stats[64 + c] = beta[c] - mn * a;
    }
}

__global__ __launch_bounds__(256) void k_bn1stats(const float* __restrict__ c1,
                                                  const float* __restrict__ gamma,
                                                  const float* __restrict__ beta,
                                                  float* __restrict__ stats1) {
    const int c = blockIdx.x;
    const int tid = threadIdx.x;
    float s = 0.f, ss = 0.f;
    for (int e = tid; e < 7056; e += 256) {
        int n = e / 441, p = e - n * 441;
        float v = c1[(n * 64 + c) * 441 + p];
        s += v; ss += v * v;
    }
    __shared__ float sh[8], sh2[8];
#pragma unroll
    for (int off = 32; off; off >>= 1) {
        s += __shfl_xor(s, off, 64);
        ss += __shfl_xor(ss, off, 64);
    }
    if ((tid & 63) == 0) { sh[tid >> 6] = s; sh2[tid >> 6] = ss; }
    __syncthreads();
    if (tid == 0) {
        s = sh[0] + sh[1] + sh[2] + sh[3];
        ss = sh2[0] + sh2[1] + sh2[2] + sh2[3];
        const float inv_n = 1.f / 7056.f;
        float mn = s * inv_n;
        float var = ss * inv_n - mn * mn;
        float a = gamma[c] * rsqrtf(var + 1e-5f);
        stats1[c] = a;
        stats1[64 + c] = beta[c] - mn * a;
    }
}

// ===== K3: BN apply + relu + maxpool 3x3/s2/p1 — 8 outputs per thread ======
__global__ __launch_bounds__(256) void k_bnpool(const __hip_bfloat16* __restrict__ sin_,
                                                const float* __restrict__ stats,
                                                float* __restrict__ f) {
    const int idx = blockIdx.x * 256 + threadIdx.x;
    const int pwg = idx & 15;
    const int ph = (idx >> 4) & 127;
    const int c = (idx >> 11) & 63;
    const int n = idx >> 17;
    const int pw0 = pwg * 8;
    const float a = stats[c], b = stats[64 + c];
    const uint* base = (const uint*)((const ushort*)sin_ + (size_t)(n * 64 + c) * 65536);

    float colmax[17];
#pragma unroll
    for (int k = 0; k < 17; k++) colmax[k] = -1e30f;

    const int r0 = ph * 2 - 1;
#pragma unroll
    for (int dr = 0; dr < 3; dr++) {
        const int r = r0 + dr;
        const bool rv = (unsigned)r < 256u;
        uint d[9];
        const uint* rp = base + r * 128 + pw0 - 1;
#pragma unroll
        for (int j = 0; j < 9; j++)
            d[j] = (rv && (pw0 > 0 || j > 0)) ? rp[j] : 0u;
#pragma unroll
        for (int j = 0; j < 9; j++) {
            float vhi = a * bfbits2f((ushort)(d[j] >> 16)) + b;
            colmax[2 * j] = rv ? fmaxf(colmax[2 * j], vhi) : colmax[2 * j];
            if (j > 0) {
                float vlo = a * bfbits2f((ushort)(d[j] & 0xFFFFu)) + b;
                colmax[2 * j - 1] = rv ? fmaxf(colmax[2 * j - 1], vlo) : colmax[2 * j - 1];
            }
        }
    }
    if (pw0 == 0) colmax[0] = -1e30f;

    float o[8];
#pragma unroll
    for (int i = 0; i < 8; i++)
        o[i] = fmaxf(fmaxf(colmax[2 * i], fmaxf(colmax[2 * i + 1], colmax[2 * i + 2])), 0.f);
    float* fp = f + (size_t)(n * 64 + c) * 16384 + ph * 128 + pw0;
    *(float4*)fp       = (float4){o[0], o[1], o[2], o[3]};
    *(float4*)(fp + 4) = (float4){o[4], o[5], o[6], o[7]};
}

// ====== K4: grid_sample, both rotations, banded-LDS (bit-identical) ========
__device__ __forceinline__ float gs_tap(const float* band, int nrows, int ry0,
                                        float yy, float xx, float wt) {
    bool valid = (xx >= 0.f) & (xx < 128.f) & (yy >= 0.f) & (yy < 128.f);
    int xi = (int)fminf(fmaxf(xx, 0.f), 127.f);
    int yi = (int)fminf(fmaxf(yy, 0.f), 127.f);
    int r = min(max(yi - ry0, 0), nrows - 1);
    return valid ? band[r * 128 + xi] * wt : 0.f;
}

__device__ __forceinline__ float gs_band(const float* band, int nrows, int ry0,
                                         float ix, float iy) {
    float x0 = floorf(ix), y0 = floorf(iy);
    float lx = ix - x0, ly = iy - y0;
    float wa = (1.f - lx) * (1.f - ly);
    float wb = (1.f - lx) * ly;
    float wc = lx * (1.f - ly);
    float wd = lx * ly;
    return gs_tap(band, nrows, ry0, y0,       x0,       wa)
         + gs_tap(band, nrows, ry0, y0 + 1.f, x0,       wb)
         + gs_tap(band, nrows, ry0, y0,       x0 + 1.f, wc)
         + gs_tap(band, nrows, ry0, y0 + 1.f, x0 + 1.f, wd);
}

__global__ __launch_bounds__(256, 4) void k_gridsample2(const float* __restrict__ f,
                                                        float* __restrict__ xt1,
                                                        float* __restrict__ xt2) {
    __shared__ float band[78 * 128];
    const int bx = blockIdx.x;
    const int half = bx & 1;
    const int img_i = bx >> 1;          // n*64+c
    const int h0 = half * 64;
    const float gy0 = (2.f * h0 + 1.f) * (1.f / 128.f) - 1.f;
    const float gy1 = (2.f * (h0 + 63) + 1.f) * (1.f / 128.f) - 1.f;
    const float gxm = 255.f * (1.f / 128.f) - 1.f;
    const float iymin = 64.f * (C5 * gy0 - S5 * gxm) + 63.5f;
    const float iymax = 64.f * (C5 * gy1 + S5 * gxm) + 63.5f;
    const int ry0 = max(0, (int)floorf(iymin) - 1);
    const int ry1 = min(127, (int)floorf(iymax) + 2);
    const int nrows = ry1 - ry0 + 1;                 // <= 78
    const float* img = f + (size_t)img_i * 16384;
    const int tid = threadIdx.x;
    const float4* src4 = (const float4*)(img + ry0 * 128);
    for (int e = tid; e < nrows * 32; e += 256)
        ((float4*)band)[e] = src4[e];
    __syncthreads();

    float* o1 = xt1 + (size_t)img_i * 16384 + h0 * 128;
    float* o2 = xt2 + (size_t)img_i * 16384 + h0 * 128;
    for (int e = tid; e < 8192; e += 256) {
        const int h = h0 + (e >> 7);
        const int w = e & 127;
        float gx = (2 * w + 1) * (1.f / 128.f) - 1.f;
        float gy = (2 * h + 1) * (1.f / 128.f) - 1.f;
        float g0a = C5 * gx + S5 * gy,  g1a = -S5 * gx + C5 * gy;
        float g0b = C5 * gx - S5 * gy,  g1b =  S5 * gx + C5 * gy;
        o1[e] = gs_band(band, nrows, ry0, ((g0a + 1.f) * 128.f - 1.f) * 0.5f,
                                          ((g1a + 1.f) * 128.f - 1.f) * 0.5f);
        o2[e] = gs_band(band, nrows, ry0, ((g0b + 1.f) * 128.f - 1.f) * 0.5f,
                                          ((g1b + 1.f) * 128.f - 1.f) * 0.5f);
    }
}

// ========= K5: roialign into concat h (bf16), coords once per pp ==========
__global__ __launch_bounds__(256) void k_roialign(const float* __restrict__ f,
                                                  const float* __restrict__ xt1,
                                                  const float* __restrict__ xt2,
                                                  const float* __restrict__ box,
                                                  __hip_bfloat16* __restrict__ h) {
    const int bx = blockIdx.x;
    const int cg = bx & 7;
    const int job = (bx >> 3) % 11;
    const int n = bx / 88;
    int j, cbase;
    const float* src;
    if (job < 7)      { j = job;     cbase = job * 64;             src = f;   }
    else if (job < 9) { j = job - 7; cbase = 448 + (job - 7) * 64; src = xt1; }
    else              { j = job - 9; cbase = 576 + (job - 9) * 64; src = xt2; }
    const float* bp = box + n * 28 + j * 4;
    const float x1 = bp[0] * 0.25f, y1 = bp[1] * 0.25f;
    const float x2 = bp[2] * 0.25f, y2 = bp[3] * 0.25f;
    const float bw = fmaxf(x2 - x1, 1.f) * (1.f / 23.f);
    const float bh = fmaxf(y2 - y1, 1.f) * (1.f / 23.f);
    const float* imgb = src + (size_t)(n * 64 + cg * 8) * 16384;
    __hip_bfloat16* hb = h + (size_t)(n * 704 + cbase + cg * 8) * 529;

    for (int pp = threadIdx.x; pp < 529; pp += 256) {
        const int ph = pp / 23, pw = pp - ph * 23;
        int   off[4][4];
        float wt[4][4];
#pragma unroll
        for (int s = 0; s < 4; s++) {
            const int r1 = s >> 1, r2 = s & 1;
            const float yv = y1 + (ph + r1 * 0.5f + 0.25f) * bh;
            const float xv = x1 + (pw + r2 * 0.5f + 0.25f) * bw;
            const bool ok = !(yv < -1.f || yv > 128.f || xv < -1.f || xv > 128.f);
            float y = fminf(fmaxf(yv, 0.f), 127.f);
            float x = fminf(fmaxf(xv, 0.f), 127.f);
            float y0f = floorf(y), x0f = floorf(x);
            int y0 = (int)y0f, x0 = (int)x0f;
            int y1i = min(y0 + 1, 127), x1i = min(x0 + 1, 127);
            float ly = y - y0f, lx = x - x0f;
            float hy = 1.f - ly, hx = 1.f - lx;
            const float sc = ok ? 1.f : 0.f;
            off[s][0] = y0 * 128 + x0;   wt[s][0] = hy * hx * sc;
            off[s][1] = y0 * 128 + x1i;  wt[s][1] = hy * lx * sc;
            off[s][2] = y1i * 128 + x0;  wt[s][2] = ly * hx * sc;
            off[s][3] = y1i * 128 + x1i; wt[s][3] = ly * lx * sc;
        }
#pragma unroll
        for (int cl = 0; cl < 8; cl++) {
            const float* img = imgb + (size_t)cl * 16384;
            float sum = 0.f;
#pragma unroll
            for (int s = 0; s < 4; s++)
                sum += img[off[s][0]] * wt[s][0] + img[off[s][1]] * wt[s][1]
                     + img[off[s][2]] * wt[s][2] + img[off[s][3]] * wt[s][3];
            hb[(size_t)cl * 529 + pp] = __float2bfloat16(sum * 0.25f);
        }
    }
}

// ========= K6: conv1 MFMA bf16, split-K=3, double-buffered staging =========
__global__ __launch_bounds__(256) void k_conv1m(const ushort* __restrict__ hb,
                                                const ushort* __restrict__ w1b,
                                                float* __restrict__ c1p) {
    __shared__ __align__(16) ushort Bs[2][2][32][40];  // [buf][panel][pos][kk]
    const int bx = blockIdx.x;
    const int pt = bx % 17;
    const int n  = (bx / 17) & 15;
    const int s  = bx / 272;
    const int tid = threadIdx.x;
    const int w = tid >> 6, lane = tid & 63;
    const int quad = lane >> 4, m = lane & 15;
    const int kbase = s * 2112;
    const int posb = pt * 32;
    const size_t hb_n = (size_t)n * 704 * 529;
    f32x4 acc0 = {0.f, 0.f, 0.f, 0.f};
    f32x4 acc1 = {0.f, 0.f, 0.f, 0.f};
    const ushort* wrow = w1b + (size_t)(w * 16 + m) * 6336;

    int ep[8], ek[8], epos[8];
#pragma unroll
    for (int i = 0; i < 8; i++) {
        const int e = tid + 256 * i;
        ep[i] = e >> 10; ek[i] = (e >> 5) & 31; epos[i] = e & 31;
    }
    ushort rbuf[8];
#pragma unroll
    for (int i = 0; i < 8; i++) {          // preload it=0
        const int k = kbase + ep[i] * 32 + ek[i];
        const int ci = k / 9, tap = k - ci * 9;
        const int kh = tap / 3, kw = tap - kh * 3;
        rbuf[i] = hb[hb_n + (size_t)ci * 529 + kh * 23 + kw + posb + epos[i]];
    }
#pragma unroll
    for (int i = 0; i < 8; i++) Bs[0][ep[i]][epos[i]][ek[i]] = rbuf[i];

    for (int it = 0; it < 33; it++) {
        __syncthreads();                    // Bs[it&1] ready
        const int cur = it & 1;
        if (it < 32) {
            const int k0 = kbase + (it + 1) * 64;
#pragma unroll
            for (int i = 0; i < 8; i++) {
                const int k = k0 + ep[i] * 32 + ek[i];
                const int ci = k / 9, tap = k - ci * 9;
                const int kh = tap / 3, kw = tap - kh * 3;
                rbuf[i] = hb[hb_n + (size_t)ci * 529 + kh * 23 + kw + posb + epos[i]];
            }
        }
        const int k0 = kbase + it * 64;
        const short8 a0  = *(const short8*)(wrow + k0 + quad * 8);
        const short8 a1  = *(const short8*)(wrow + k0 + 32 + quad * 8);
        const short8 b00 = *(const short8*)&Bs[cur][0][m][quad * 8];
        const short8 b01 = *(const short8*)&Bs[cur][0][16 + m][quad * 8];
        const short8 b10 = *(const short8*)&Bs[cur][1][m][quad * 8];
        const short8 b11 = *(const short8*)&Bs[cur][1][16 + m][quad * 8];
        acc0 = __builtin_amdgcn_mfma_f32_16x16x32_bf16(a0, b00, acc0, 0, 0, 0);
        acc1 = __builtin_amdgcn_mfma_f32_16x16x32_bf16(a0, b01, acc1, 0, 0, 0);
        acc0 = __builtin_amdgcn_mfma_f32_16x16x32_bf16(a1, b10, acc0, 0, 0, 0);
        acc1 = __builtin_amdgcn_mfma_f32_16x16x32_bf16(a1, b11, acc1, 0, 0, 0);
        if (it < 32) {
#pragma unroll
            for (int i = 0; i < 8; i++) Bs[cur ^ 1][ep[i]][epos[i]][ek[i]] = rbuf[i];
        }
    }
    float* outp = c1p + ((size_t)(s * 16 + n) * 64) * 544;
#pragma unroll
    for (int r = 0; r < 4; r++) {
        const int oc = w * 16 + quad * 4 + r;
        outp[(size_t)oc * 544 + posb + m]      = acc0[r];
        outp[(size_t)oc * 544 + posb + 16 + m] = acc1[r];
    }
}

// =================== K6b: split-K reduce + bias ============================
__global__ __launch_bounds__(256) void k_c1red(const float* __restrict__ c1p,
                                               const float* __restrict__ b1,
                                               float* __restrict__ c1) {
    const int t = blockIdx.x * 256 + threadIdx.x;   // 451584 exact
    const int p = t % 441;
    const int oc = (t / 441) % 64;
    const int n = t / 28224;
    const int ph = p / 21, pw = p - ph * 21;
    const int p529 = ph * 23 + pw;
    const size_t base = ((size_t)n * 64 + oc) * 544 + p529;
    const size_t sstr = (size_t)16 * 64 * 544;
    c1[t] = c1p[base] + c1p[base + sstr] + c1p[base + 2 * sstr] + b1[oc];
}

// ================ K8: BN1 apply + relu + maxpool 2x2/s2 ====================
__global__ __launch_bounds__(256) void k_bnpool2(const float* __restrict__ c1,
                                                 const float* __restrict__ stats1,
                                                 float* __restrict__ p1) {
    const int t = blockIdx.x * 256 + threadIdx.x;   // 102400 exact
    const int pw = t % 10;
    const int ph = (t / 10) % 10;
    const int c = (t / 100) % 64;
    const int n = t / 6400;
    const float a = stats1[c], b = stats1[64 + c];
    const float* base = c1 + (size_t)(n * 64 + c) * 441;
    const int r = ph * 2, cc = pw * 2;
    float v0 = a * base[r * 21 + cc] + b;
    float v1 = a * base[r * 21 + cc + 1] + b;
    float v2 = a * base[(r + 1) * 21 + cc] + b;
    float v3 = a * base[(r + 1) * 21 + cc + 1] + b;
    p1[t] = fmaxf(fmaxf(fmaxf(v0, v1), fmaxf(v2, v3)), 0.f);
}

// ========== K9: conv2 3x3 (64->32) + bias + relu, LDS-staged ===============
__global__ __launch_bounds__(256) void k_conv2(const float* __restrict__ p1,
                                               const float* __restrict__ w2,
                                               const float* __restrict__ b2,
                                               float* __restrict__ c2) {
    __shared__ float ip[6400];      // 64 ci x 100
    __shared__ float wl[2304];      // 4 oc x 576
    const int bx = blockIdx.x;
    const int n = bx >> 3, ocq = bx & 7;
    const int tid = threadIdx.x;
    const float4* p14 = (const float4*)(p1 + (size_t)n * 6400);
    float4* ip4 = (float4*)ip;
    for (int e = tid; e < 1600; e += 256) ip4[e] = p14[e];
    for (int e = tid; e < 2304; e += 256) wl[e] = w2[ocq * 2304 + e];
    __syncthreads();

    const int ocl = tid >> 6, pos = tid & 63;
    const int ph = pos >> 3, pw = pos & 7;
    const int oc = ocq * 4 + ocl;
    float s = b2[oc];
    const float* wb = wl + ocl * 576;
    const float* ib = ip + ph * 10 + pw;
    for (int ci = 0; ci < 64; ci++) {
        const float* r = ib + ci * 100;
        const float* ww = wb + ci * 9;
        s += r[0] * ww[0] + r[1] * ww[1] + r[2] * ww[2]
           + r[10] * ww[3] + r[11] * ww[4] + r[12] * ww[5]
           + r[20] * ww[6] + r[21] * ww[7] + r[22] * ww[8];
    }
    c2[(size_t)(n * 32 + oc) * 64 + pos] = fmaxf(s, 0.f);
}

// ======================= K10: fc1 + relu ===================================
__global__ __launch_bounds__(64) void k_fc1(const float* __restrict__ c2,
                                            const float* __restrict__ fw,
                                            const float* __restrict__ fb,
                                            float* __restrict__ fo) {
    const int bx = blockIdx.x;
    const int oc = bx & 127, n = bx >> 7;
    const int lane = threadIdx.x;
    const float* a = c2 + (size_t)n * 2048;
    const float* w = fw + (size_t)oc * 2048;
    float s = 0.f;
    for (int k = lane; k < 2048; k += 64) s += a[k] * w[k];
#pragma unroll
    for (int off = 32; off; off >>= 1) s += __shfl_xor(s, off, 64);
    if (lane == 0) fo[n * 128 + oc] = fmaxf(s + fb[oc], 0.f);
}

// ======================= K11: head + tanh ==================================
__global__ __launch_bounds__(64) void k_head(const float* __restrict__ fo,
                                             const float* __restrict__ hw,
                                             const float* __restrict__ hb,
                                             float* __restrict__ out) {
    const int bx = blockIdx.x;
    const int oc = bx % 12, n = bx / 12;
    const int lane = threadIdx.x;
    float s = 0.f;
    for (int k = lane; k < 128; k += 64) s += fo[n * 128 + k] * hw[oc * 128 + k];
#pragma unroll
    for (int off = 32; off; off >>= 1) s += __shfl_xor(s, off, 64);
    if (lane == 0) out[bx] = tanhf(s + hb[oc]);
}

// ===========================================================================
extern "C" void kernel_launch(void* const* d_in, const int* in_sizes, int n_in,
                              void* d_out, int out_size, void* d_ws, size_t ws_size,
                              hipStream_t stream) {
    const float* x       = (const float*)d_in[0];
    const float* box     = (const float*)d_in[1];
    const float* stem_w  = (const float*)d_in[2];
    const float* stem_g  = (const float*)d_in[3];
    const float* stem_b  = (const float*)d_in[4];
    const float* conv1_w = (const float*)d_in[5];
    const float* conv1_b = (const float*)d_in[6];
    const float* bn1_g   = (const float*)d_in[7];
    const float* bn1_b   = (const float*)d_in[8];
    const float* conv2_w = (const float*)d_in[9];
    const float* conv2_b = (const float*)d_in[10];
    const float* fc1_w   = (const float*)d_in[11];
    const float* fc1_b   = (const float*)d_in[12];
    const float* head_w  = (const float*)d_in[13];
    const float* head_b  = (const float*)d_in[14];
    float* out = (float*)d_out;
    float* w = (float*)d_ws;

    const size_t F_SZ = 16777216;                         // 16*64*128*128
    float* f   = w;                                       // fp32
    __hip_bfloat16* stem = (__hip_bfloat16*)(w + F_SZ);   // bf16, spans 2*F_SZ floats
    float* xt1 = w + F_SZ;                                // aliases stem (dead after K3)
    float* xt2 = w + 2 * F_SZ;
    float* base3 = w + 3 * F_SZ;
    __hip_bfloat16* hbuf = (__hip_bfloat16*)base3;        // 5958656 els = 2979328+pad
    float* c1   = base3 + 2979392;                        // 451584
    float* c1p  = c1 + 451584;                            // 3*16*64*544 = 1671168
    float* p1   = c1p + 1671168;                          // 102400
    float* c2   = p1 + 102400;                            // 32768
    float* fo   = c2 + 32768;                             // 2048
    float* partial = fo + 2048;                           // 4096*128 used
    float* stats   = partial + 1048576;                   // 128
    float* stats1  = stats + 128;                         // 128
    __hip_bfloat16* w1b = (__hip_bfloat16*)(stats1 + 128); // 405504 els
    __hip_bfloat16* w2b = (__hip_bfloat16*)(stats1 + 128 + 202752); // 12288 els

    k_cvt<<<1632, 256, 0, stream>>>(conv1_w, w1b, stem_w, w2b);
    k_stem<<<4096, 256, 0, stream>>>(x, (const ushort*)w2b, stem, partial);
    k_bnstats<<<64, 256, 0, stream>>>(partial, 4096, stem_g, stem_b, stats,
                                      1.f / 1048576.f);
    k_bnpool<<<8192, 256, 0, stream>>>(stem, stats, f);
    k_gridsample2<<<2048, 256, 0, stream>>>(f, xt1, xt2);
    k_roialign<<<1408, 256, 0, stream>>>(f, xt1, xt2, box, hbuf);
    k_conv1m<<<816, 256, 0, stream>>>((const ushort*)hbuf, (const ushort*)w1b, c1p);
    k_c1red<<<1764, 256, 0, stream>>>(c1p, conv1_b, c1);
    k_bn1stats<<<64, 256, 0, stream>>>(c1, bn1_g, bn1_b, stats1);
    k_bnpool2<<<400, 256, 0, stream>>>(c1, stats1, p1);
    k_conv2<<<128, 256, 0, stream>>>(p1, conv2_w, conv2_b, c2);
    k_fc1<<<2048, 64, 0, stream>>>(c2, fc1_w, fc1_b, fo);
    k_head<<<192, 64, 0, stream>>>(fo, head_w, head_b, out);
}